// Round 7
// baseline (923.885 us; speedup 1.0000x reference)
//
#include <hip/hip_runtime.h>
#include <hip/hip_bf16.h>

#define BB 1024
#define NN 32
#define SUD 8
#define HD 64
#define NCD 4
#define ED 992      // NN*(NN-1)
#define NITER 5

// ---- fp32 weight workspace layout (element offsets into d_ws) ----
#define O_W2AT 0        // 18 x 64   W2aT[su][f] = W2a[f][su]
#define O_B2A  1152     // 64
#define O_W2B  1216     // 32 x 64
#define O_B2B  3264     // 32
#define O_W2CT 3296     // 32 x 8
#define O_B2C  3552     // 8
#define O_WIHT 3560     // 10 x 192  WihT[k][o]
#define O_BIH  5480     // 192
#define O_WHHT 5672     // 64 x 192  WhhT[k][o]
#define O_BHH  17960    // 192
#define O_W4T  18152    // 64 x 8    W4T[k][su]
#define O_B4   18664    // 8
#define O_W3AT 18672    // 8 x 64    W3aT[k][f]
#define O_B3A  19184    // 64
#define O_W3BT 19248    // 64 x 32   W3bT[k][f]
#define O_B3B  21296    // 32
#define O_W3CT 21328    // 32 x 4    W3cT[k][c]
#define O_B3C  21456    // 4
#define O_W1AT 21460    // 3 x 8     W1aT[c][su]
#define O_B1A  21484    // 8
#define W_TOTAL 21492   // floats

// ---- bf16 MFMA fragment region, at byte offset W_TOTAL*4 ----
#define FRAG_B2_HI 0
#define FRAG_B2_LO 2048
#define FRAG_C     4096
#define W_EXT (W_TOTAL + 2560)

typedef const float* fwp;
typedef __attribute__((ext_vector_type(8))) short short8;
typedef __attribute__((ext_vector_type(4))) float float4v;

__device__ __forceinline__ short bf16r(float x) {
  __hip_bfloat16 h = __float2bfloat16(x);
  return __builtin_bit_cast(short, h);
}
__device__ __forceinline__ float bf16tof(short s) {
  __hip_bfloat16 h = __builtin_bit_cast(__hip_bfloat16, s);
  return __bfloat162float(h);
}

__global__ void prep_weights(fwp W2a, fwp b2a, fwp W2b, fwp b2b, fwp W2c, fwp b2c,
                             fwp Wih, fwp bih, fwp Whh, fwp bhh,
                             fwp W3a, fwp b3a, fwp W3b, fwp b3b, fwp W3c, fwp b3c,
                             fwp W4, fwp b4, fwp W1a, fwp b1a, float* __restrict__ ws) {
  int idx = blockIdx.x * 256 + threadIdx.x;
  if (idx >= W_EXT) return;
  if (idx >= W_TOTAL) {
    __hip_bfloat16* wb = (__hip_bfloat16*)(ws + W_TOTAL);
    int e = idx - W_TOTAL;
    if (e < 2048) {
      int j = e & 7, L = (e >> 3) & 63, hs = e >> 9;
      int h = hs >> 1, s = hs & 1;
      float v = W2b[(h * 16 + (L & 15)) * 64 + s * 32 + ((L >> 4) & 3) * 8 + j];
      float hi = __bfloat162float(__float2bfloat16(v));
      wb[FRAG_B2_HI + e] = __float2bfloat16(v);
      wb[FRAG_B2_LO + e] = __float2bfloat16(v - hi);
    } else {
      int e2 = e - 2048;
      int j = e2 & 7, L = (e2 >> 3) & 63;
      int su = L & 15, q = L >> 4;
      float v = (su < 8) ? W2c[su * 32 + q * 8 + j] : 0.f;
      wb[FRAG_C + e2] = __float2bfloat16(v);
    }
    return;
  }
  float v;
  if (idx < O_B2A)       { int p = idx;          int su = p / 64, f = p % 64;   v = W2a[f * 18 + su]; }
  else if (idx < O_W2B)  { v = b2a[idx - O_B2A]; }
  else if (idx < O_B2B)  { v = W2b[idx - O_W2B]; }
  else if (idx < O_W2CT) { v = b2b[idx - O_B2B]; }
  else if (idx < O_B2C)  { int p = idx - O_W2CT; int o = p / 8, su = p % 8;     v = W2c[su * 32 + o]; }
  else if (idx < O_WIHT) { v = b2c[idx - O_B2C]; }
  else if (idx < O_BIH)  { int p = idx - O_WIHT; int k = p / 192, o = p % 192;  v = Wih[o * 10 + k]; }
  else if (idx < O_WHHT) { v = bih[idx - O_BIH]; }
  else if (idx < O_BHH)  { int p = idx - O_WHHT; int k = p / 192, o = p % 192;  v = Whh[o * 64 + k]; }
  else if (idx < O_W4T)  { v = bhh[idx - O_BHH]; }
  else if (idx < O_B4)   { int p = idx - O_W4T;  int k = p / 8, su = p % 8;     v = W4[su * 64 + k]; }
  else if (idx < O_W3AT) { v = b4[idx - O_B4]; }
  else if (idx < O_B3A)  { int p = idx - O_W3AT; int k = p / 64, f = p % 64;    v = W3a[f * 8 + k]; }
  else if (idx < O_W3BT) { v = b3a[idx - O_B3A]; }
  else if (idx < O_B3B)  { int p = idx - O_W3BT; int k = p / 32, f = p % 32;    v = W3b[f * 64 + k]; }
  else if (idx < O_W3CT) { v = b3b[idx - O_B3B]; }
  else if (idx < O_B3C)  { int p = idx - O_W3CT; int k = p / 4, c = p % 4;      v = W3c[c * 32 + k]; }
  else if (idx < O_W1AT) { v = b3c[idx - O_B3C]; }
  else if (idx < O_B1A)  { int p = idx - O_W1AT; int c = p / 8, su = p % 8;     v = W1a[su * 3 + c]; }
  else                   { v = b1a[idx - O_B1A]; }
  ws[idx] = v;
}

#define DO_STEP(KOFF, Y0, Y1, C0, C1, W0, W1, FH0, FL0, FH1, FL1)              \
  {                                                                            \
    float4v x0 = *(const float4v*)&sA1[a * 68 + (KOFF)];                       \
    float4v x1 = *(const float4v*)&sA1[a * 68 + (KOFF) + 4];                   \
    float t0 = fmaxf(x0.x + Y0.x + C0.x + ewv * W0.x, 0.f);                    \
    float t1 = fmaxf(x0.y + Y0.y + C0.y + ewv * W0.y, 0.f);                    \
    float t2 = fmaxf(x0.z + Y0.z + C0.z + ewv * W0.z, 0.f);                    \
    float t3 = fmaxf(x0.w + Y0.w + C0.w + ewv * W0.w, 0.f);                    \
    float t4 = fmaxf(x1.x + Y1.x + C1.x + ewv * W1.x, 0.f);                    \
    float t5 = fmaxf(x1.y + Y1.y + C1.y + ewv * W1.y, 0.f);                    \
    float t6 = fmaxf(x1.z + Y1.z + C1.z + ewv * W1.z, 0.f);                    \
    float t7 = fmaxf(x1.w + Y1.w + C1.w + ewv * W1.w, 0.f);                    \
    short8 ahi, alo;                                                           \
    ahi[0] = bf16r(t0); ahi[1] = bf16r(t1); ahi[2] = bf16r(t2);                \
    ahi[3] = bf16r(t3); ahi[4] = bf16r(t4); ahi[5] = bf16r(t5);                \
    ahi[6] = bf16r(t6); ahi[7] = bf16r(t7);                                    \
    alo[0] = bf16r(t0 - bf16tof(ahi[0])); alo[1] = bf16r(t1 - bf16tof(ahi[1]));\
    alo[2] = bf16r(t2 - bf16tof(ahi[2])); alo[3] = bf16r(t3 - bf16tof(ahi[3]));\
    alo[4] = bf16r(t4 - bf16tof(ahi[4])); alo[5] = bf16r(t5 - bf16tof(ahi[5]));\
    alo[6] = bf16r(t6 - bf16tof(ahi[6])); alo[7] = bf16r(t7 - bf16tof(ahi[7]));\
    accb0 = __builtin_amdgcn_mfma_f32_16x16x32_bf16(ahi, FH0, accb0, 0, 0, 0); \
    accb0 = __builtin_amdgcn_mfma_f32_16x16x32_bf16(alo, FH0, accb0, 0, 0, 0); \
    accb0 = __builtin_amdgcn_mfma_f32_16x16x32_bf16(ahi, FL0, accb0, 0, 0, 0); \
    accb1 = __builtin_amdgcn_mfma_f32_16x16x32_bf16(ahi, FH1, accb1, 0, 0, 0); \
    accb1 = __builtin_amdgcn_mfma_f32_16x16x32_bf16(alo, FH1, accb1, 0, 0, 0); \
    accb1 = __builtin_amdgcn_mfma_f32_16x16x32_bf16(ahi, FL1, accb1, 0, 0, 0); \
  }

__global__ __launch_bounds__(256, 2) void gnn_fused(
    const float* __restrict__ read_gru_in,
    const float* __restrict__ gru_init,
    const float* __restrict__ feat,
    const float* __restrict__ edge_w,
    const float* __restrict__ noise_in,
    const float* __restrict__ xhat,
    const float* __restrict__ vep,
    const int* __restrict__ gnn_iter_p,
    const float* __restrict__ ws,
    float* __restrict__ out)
{
  __shared__ __attribute__((aligned(16))) float sA1[NN * 68];
  __shared__ __attribute__((aligned(16))) float sA2[NN * 68];
  __shared__ __attribute__((aligned(16))) float sH [NN * 68];
  __shared__ __attribute__((aligned(16))) float sC1[64];
  __shared__ __attribute__((aligned(16))) float sWew[64];
  __shared__ __attribute__((aligned(16))) __hip_bfloat16 sM2[4 * 16 * 44];
  __shared__ __attribute__((aligned(16))) short sFrag[9 * 64 * 8];
  __shared__ float sNodes[NN * 9];
  __shared__ float sSum[NN * 8];
  __shared__ float sEw[ED];
  __shared__ float sX[NN];
  __shared__ float sV[NN];

  const int b = blockIdx.x;
  const int t = threadIdx.x;
  const int lane = t & 63;
  const int wv = t >> 6;
  const int quad = lane >> 4;
  const int lm = lane & 15;

  const __hip_bfloat16* wb = (const __hip_bfloat16*)(ws + W_TOTAL);

  // ---- stash MFMA B fragments into LDS ----
  if (t < 64) {
#pragma unroll
    for (int hs = 0; hs < 4; ++hs) {
      *(short8*)(sFrag + (hs * 64 + lane) * 8) =
          *(const short8*)(wb + FRAG_B2_HI + (hs * 64 + lane) * 8);
      *(short8*)(sFrag + ((4 + hs) * 64 + lane) * 8) =
          *(const short8*)(wb + FRAG_B2_LO + (hs * 64 + lane) * 8);
    }
    *(short8*)(sFrag + (8 * 64 + lane) * 8) = *(const short8*)(wb + FRAG_C + lane * 8);
  }

  // ---- per-sample inputs ----
  float noi = noise_in[b];
  for (int e = t; e < ED; e += 256) sEw[e] = edge_w[b * ED + e];
  if (t < NN) { sX[t] = xhat[b * NN + t]; sV[t] = vep[b * NN + t]; }
  if (t < 64) {
    sC1[t]  = ws[O_B2A + t] + noi * ws[O_W2AT + 17 * 64 + t];
    sWew[t] = ws[O_W2AT + 16 * 64 + t];
  }
#pragma unroll
  for (int i = 0; i < 8; ++i) {
    int p = t + 256 * i;
    sH[(p >> 6) * 68 + (p & 63)] = gru_init[b * (NN * HD) + p];
  }
  const int git = gnn_iter_p[0];

  for (int it = 0; it < NITER; ++it) {
    // ---- init_nodes ----
    if (it == 0) {
      int n = t >> 3, su = t & 7;
      float acc;
      if (git == 0) {
        acc = ws[O_B1A + su];
#pragma unroll
        for (int c = 0; c < 3; ++c)
          acc += ws[O_W1AT + c * 8 + su] * feat[b * (NN * 3) + n * 3 + c];
      } else {
        acc = read_gru_in[b * (NN * SUD) + t];
      }
      sNodes[n * 9 + su] = acc;
    }
    __syncthreads();

    // ---- A1/A2 node projections ----
#pragma unroll
    for (int i = 0; i < 8; ++i) {
      int p = t + 256 * i;
      int n = p >> 6, f = p & 63;
      float a1 = 0.f, a2 = 0.f;
#pragma unroll
      for (int su = 0; su < 8; ++su) {
        float nv = sNodes[n * 9 + su];
        a1 += ws[O_W2AT + su * 64 + f] * nv;
        a2 += ws[O_W2AT + (8 + su) * 64 + f] * nv;
      }
      sA1[n * 68 + f] = a1;
      sA2[n * 68 + f] = a2;
    }
    __syncthreads();

    // ---- edge MLP via MFMA ----
    {
      short8 fbh00 = *(const short8*)(sFrag + (0 * 64 + lane) * 8);
      short8 fbh01 = *(const short8*)(sFrag + (1 * 64 + lane) * 8);
      short8 fbh10 = *(const short8*)(sFrag + (2 * 64 + lane) * 8);
      short8 fbh11 = *(const short8*)(sFrag + (3 * 64 + lane) * 8);
      short8 fbl00 = *(const short8*)(sFrag + (4 * 64 + lane) * 8);
      short8 fbl01 = *(const short8*)(sFrag + (5 * 64 + lane) * 8);
      short8 fbl10 = *(const short8*)(sFrag + (6 * 64 + lane) * 8);
      short8 fbl11 = *(const short8*)(sFrag + (7 * 64 + lane) * 8);
      short8 fcf   = *(const short8*)(sFrag + (8 * 64 + lane) * 8);
      const float b2b0 = ws[O_B2B + lm];
      const float b2b1 = ws[O_B2B + 16 + lm];
      const float b2cl = ws[O_B2C + lm];

      __hip_bfloat16* m2w = sM2 + wv * (16 * 44);
      const int kq0 = quad * 8, kq1 = 32 + quad * 8;
      float4v c1A = *(const float4v*)&sC1[kq0];
      float4v c1B = *(const float4v*)&sC1[kq0 + 4];
      float4v c1C = *(const float4v*)&sC1[kq1];
      float4v c1D = *(const float4v*)&sC1[kq1 + 4];
      float4v wwA = *(const float4v*)&sWew[kq0];
      float4v wwB = *(const float4v*)&sWew[kq0 + 4];
      float4v wwC = *(const float4v*)&sWew[kq1];
      float4v wwD = *(const float4v*)&sWew[kq1 + 4];
      for (int ni = 0; ni < 8; ++ni) {
        const int jj = wv * 8 + ni;
        float4v yA = *(const float4v*)&sA2[jj * 68 + kq0];
        float4v yB = *(const float4v*)&sA2[jj * 68 + kq0 + 4];
        float4v yC = *(const float4v*)&sA2[jj * 68 + kq1];
        float4v yD = *(const float4v*)&sA2[jj * 68 + kq1 + 4];
        float psum = 0.f;
#pragma unroll
        for (int tile = 0; tile < 2; ++tile) {
          int kk = tile * 16 + lm;
          int kk2 = (kk < 31) ? kk : 0;
          int a = kk2 + (kk2 >= jj ? 1 : 0);
          float ewv = (kk < 31) ? sEw[jj * 31 + kk] : 0.f;
          float4v accb0 = {0.f, 0.f, 0.f, 0.f};
          float4v accb1 = {0.f, 0.f, 0.f, 0.f};
          DO_STEP(kq0, yA, yB, c1A, c1B, wwA, wwB, fbh00, fbl00, fbh10, fbl10);
          DO_STEP(kq1, yC, yD, c1C, c1D, wwC, wwD, fbh01, fbl01, fbh11, fbl11);
#pragma unroll
          for (int r = 0; r < 4; ++r) {
            float m20 = fmaxf(accb0[r] + b2b0, 0.f);
            float m21 = fmaxf(accb1[r] + b2b1, 0.f);
            m2w[(quad * 4 + r) * 44 + lm]      = __float2bfloat16(m20);
            m2w[(quad * 4 + r) * 44 + 16 + lm] = __float2bfloat16(m21);
          }
          __asm__ __volatile__("" ::: "memory");
          short8 ac = *(const short8*)(m2w + lm * 44 + quad * 8);
          float4v c3 = {0.f, 0.f, 0.f, 0.f};
          c3 = __builtin_amdgcn_mfma_f32_16x16x32_bf16(ac, fcf, c3, 0, 0, 0);
#pragma unroll
          for (int r = 0; r < 4; ++r) {
            float v = fmaxf(c3[r] + b2cl, 0.f);
            if (tile == 1 && r == 3) v = (quad == 3) ? 0.f : v;
            psum += v;
          }
          __asm__ __volatile__("" ::: "memory");
        }
        psum += __shfl_xor(psum, 16);
        psum += __shfl_xor(psum, 32);
        if (lane < 8) sSum[jj * 8 + lane] = psum;
      }
    }
    __syncthreads();

    // ---- GRU: lane owns gate-column oo; nodes split into 2 groups of 4 ----
    // (sH rows are wave-private here: wave wq touches only nodes == wq mod 4,
    //  and DS ops are in-order per wave -> no inner barrier needed. Group split
    //  keeps peak live accs at 16+4, not 40 -> no scratch spill at 128 VGPRs.)
    {
      int oo = t & 63, wq = t >> 6;
#pragma unroll 1
      for (int jg = 0; jg < 2; ++jg) {
        float ar[4], az[4], inx[4], hn[4];
        {
          float br  = ws[O_BIH + oo]        + ws[O_BHH + oo];
          float bz  = ws[O_BIH + 64 + oo]   + ws[O_BHH + 64 + oo];
          float bni = ws[O_BIH + 128 + oo];
          float bnh = ws[O_BHH + 128 + oo];
#pragma unroll
          for (int j = 0; j < 4; ++j) { ar[j] = br; az[j] = bz; inx[j] = bni; hn[j] = bnh; }
        }
#pragma unroll
        for (int k = 0; k < 8; ++k) {
          float wr = ws[O_WIHT + k * 192 + oo];
          float wz = ws[O_WIHT + k * 192 + 64 + oo];
          float wn = ws[O_WIHT + k * 192 + 128 + oo];
#pragma unroll
          for (int j = 0; j < 4; ++j) {
            float g = sSum[(wq + 16 * jg + 4 * j) * 8 + k];
            ar[j] += wr * g; az[j] += wz * g; inx[j] += wn * g;
          }
        }
        {
          float wr = ws[O_WIHT + 8 * 192 + oo];
          float wz = ws[O_WIHT + 8 * 192 + 64 + oo];
          float wn = ws[O_WIHT + 8 * 192 + 128 + oo];
#pragma unroll
          for (int j = 0; j < 4; ++j) {
            float g = sX[wq + 16 * jg + 4 * j];
            ar[j] += wr * g; az[j] += wz * g; inx[j] += wn * g;
          }
          wr = ws[O_WIHT + 9 * 192 + oo];
          wz = ws[O_WIHT + 9 * 192 + 64 + oo];
          wn = ws[O_WIHT + 9 * 192 + 128 + oo];
#pragma unroll
          for (int j = 0; j < 4; ++j) {
            float g = sV[wq + 16 * jg + 4 * j];
            ar[j] += wr * g; az[j] += wz * g; inx[j] += wn * g;
          }
        }
#pragma unroll 2
        for (int k = 0; k < 64; ++k) {
          float wr = ws[O_WHHT + k * 192 + oo];
          float wz = ws[O_WHHT + k * 192 + 64 + oo];
          float wn = ws[O_WHHT + k * 192 + 128 + oo];
#pragma unroll
          for (int j = 0; j < 4; ++j) {
            float hk = sH[(wq + 16 * jg + 4 * j) * 68 + k];
            ar[j] += wr * hk; az[j] += wz * hk; hn[j] += wn * hk;
          }
        }
#pragma unroll
        for (int j = 0; j < 4; ++j) {
          int n = wq + 16 * jg + 4 * j;
          float r = 1.f / (1.f + __expf(-ar[j]));
          float z = 1.f / (1.f + __expf(-az[j]));
          float cd = inx[j] + r * hn[j];
          float e2 = __expf(2.f * cd);
          float th = 1.f - 2.f / (e2 + 1.f);
          sH[n * 68 + oo] = (1.f - z) * th + z * sH[n * 68 + oo];
        }
      }
    }
    __syncthreads();

    // ---- read_gru = W4 @ h + b4 -> sNodes ----
    {
      int n = t >> 3, su = t & 7;
      float c0 = 0.f, c1v = 0.f, c2 = 0.f, c3v = 0.f;
#pragma unroll
      for (int k = 0; k < 64; k += 4) {
        c0  += ws[O_W4T + (k + 0) * 8 + su] * sH[n * 68 + k + 0];
        c1v += ws[O_W4T + (k + 1) * 8 + su] * sH[n * 68 + k + 1];
        c2  += ws[O_W4T + (k + 2) * 8 + su] * sH[n * 68 + k + 2];
        c3v += ws[O_W4T + (k + 3) * 8 + su] * sH[n * 68 + k + 3];
      }
      sNodes[n * 9 + su] = ws[O_B4 + su] + ((c0 + c1v) + (c2 + c3v));
    }
    __syncthreads();
  } // iterations

  // ---- head ----
#pragma unroll
  for (int i = 0; i < 8; ++i) {
    int p = t + 256 * i;
    int n = p >> 6, f = p & 63;
    float acc = ws[O_B3A + f];
#pragma unroll
    for (int k = 0; k < 8; ++k) acc += ws[O_W3AT + k * 64 + f] * sNodes[n * 9 + k];
    sA1[n * 68 + f] = acc;
  }
  __syncthreads();
#pragma unroll
  for (int i = 0; i < 4; ++i) {
    int p = t + 256 * i;
    int n = p >> 5, f = p & 31;
    float c0 = 0.f, c1v = 0.f, c2 = 0.f, c3v = 0.f;
#pragma unroll
    for (int k = 0; k < 64; k += 4) {
      c0  += ws[O_W3BT + (k + 0) * 32 + f] * sA1[n * 68 + k + 0];
      c1v += ws[O_W3BT + (k + 1) * 32 + f] * sA1[n * 68 + k + 1];
      c2  += ws[O_W3BT + (k + 2) * 32 + f] * sA1[n * 68 + k + 2];
      c3v += ws[O_W3BT + (k + 3) * 32 + f] * sA1[n * 68 + k + 3];
    }
    sA2[n * 33 + f] = ws[O_B3B + f] + ((c0 + c1v) + (c2 + c3v));
  }
  __syncthreads();
  if (t < 128) {
    int n = t >> 2, c = t & 3;
    float acc = ws[O_B3C + c];
#pragma unroll
    for (int k = 0; k < 32; ++k) acc += ws[O_W3CT + k * 4 + c] * sA2[n * 33 + k];
    out[b * (NN * NCD) + t] = acc;
  }
  out[BB * NN * NCD + b * (NN * SUD) + t] = sNodes[(t >> 3) * 9 + (t & 7)];
#pragma unroll
  for (int i = 0; i < 8; ++i) {
    int p = t + 256 * i;
    out[BB * NN * NCD + BB * NN * SUD + b * (NN * HD) + p] =
        sH[(p >> 6) * 68 + (p & 63)];
  }
}

extern "C" void kernel_launch(void* const* d_in, const int* in_sizes, int n_in,
                              void* d_out, int out_size, void* d_ws, size_t ws_size,
                              hipStream_t stream) {
  typedef const float* F32;
  F32 read_gru = (F32)d_in[0];
  F32 gru_init = (F32)d_in[1];
  F32 feat     = (F32)d_in[2];
  F32 edge_w   = (F32)d_in[3];
  F32 noise    = (F32)d_in[4];
  F32 xh       = (F32)d_in[5];
  F32 vp       = (F32)d_in[6];
  F32 W1a = (F32)d_in[7];  F32 b1a = (F32)d_in[8];
  F32 W2a = (F32)d_in[9];  F32 b2a = (F32)d_in[10];
  F32 W2b = (F32)d_in[11]; F32 b2b = (F32)d_in[12];
  F32 W2c = (F32)d_in[13]; F32 b2c = (F32)d_in[14];
  F32 Wih = (F32)d_in[15]; F32 bih = (F32)d_in[16];
  F32 Whh = (F32)d_in[17]; F32 bhh = (F32)d_in[18];
  F32 W3a = (F32)d_in[19]; F32 b3a = (F32)d_in[20];
  F32 W3b = (F32)d_in[21]; F32 b3b = (F32)d_in[22];
  F32 W3c = (F32)d_in[23]; F32 b3c = (F32)d_in[24];
  F32 W4  = (F32)d_in[25]; F32 b4  = (F32)d_in[26];
  const int* git = (const int*)d_in[27];
  float* ws = (float*)d_ws;   // needs 95,184 B

  prep_weights<<<(W_EXT + 255) / 256, 256, 0, stream>>>(
      W2a, b2a, W2b, b2b, W2c, b2c, Wih, bih, Whh, bhh,
      W3a, b3a, W3b, b3b, W3c, b3c, W4, b4, W1a, b1a, ws);

  gnn_fused<<<BB, 256, 0, stream>>>(read_gru, gru_init, feat, edge_w, noise,
                                    xh, vp, git, ws, (float*)d_out);
}

// Round 8
// 834.058 us; speedup vs baseline: 1.1077x; 1.1077x over previous
//
#include <hip/hip_runtime.h>
#include <hip/hip_bf16.h>

#define BB 1024
#define NN 32
#define SUD 8
#define HD 64
#define NCD 4
#define ED 992      // NN*(NN-1)
#define NITER 5

// ---- fp32 weight workspace layout (element offsets into d_ws) ----
#define O_W2AT 0        // 18 x 64   W2aT[su][f] = W2a[f][su]
#define O_B2A  1152     // 64
#define O_W2B  1216     // 32 x 64
#define O_B2B  3264     // 32
#define O_W2CT 3296     // 32 x 8
#define O_B2C  3552     // 8
#define O_WIHT 3560     // 10 x 192  WihT[k][o]
#define O_BIH  5480     // 192
#define O_WHHT 5672     // 64 x 192  WhhT[k][o]
#define O_BHH  17960    // 192
#define O_W4T  18152    // 64 x 8    W4T[k][su]
#define O_B4   18664    // 8
#define O_W3AT 18672    // 8 x 64    W3aT[k][f]
#define O_B3A  19184    // 64
#define O_W3BT 19248    // 64 x 32   W3bT[k][f]
#define O_B3B  21296    // 32
#define O_W3CT 21328    // 32 x 4    W3cT[k][c]
#define O_B3C  21456    // 4
#define O_W1AT 21460    // 3 x 8     W1aT[c][su]
#define O_B1A  21484    // 8
#define W_TOTAL 21492   // floats

// ---- bf16 MFMA fragment region, at byte offset W_TOTAL*4 ----
#define FRAG_B2_HI 0
#define FRAG_B2_LO 2048
#define FRAG_C     4096
#define W_EXT (W_TOTAL + 2560)

typedef const float* fwp;
typedef __attribute__((ext_vector_type(8))) short short8;
typedef __attribute__((ext_vector_type(4))) float float4v;

__device__ __forceinline__ short bf16r(float x) {
  __hip_bfloat16 h = __float2bfloat16(x);
  return __builtin_bit_cast(short, h);
}
__device__ __forceinline__ float bf16tof(short s) {
  __hip_bfloat16 h = __builtin_bit_cast(__hip_bfloat16, s);
  return __bfloat162float(h);
}

__global__ void prep_weights(fwp W2a, fwp b2a, fwp W2b, fwp b2b, fwp W2c, fwp b2c,
                             fwp Wih, fwp bih, fwp Whh, fwp bhh,
                             fwp W3a, fwp b3a, fwp W3b, fwp b3b, fwp W3c, fwp b3c,
                             fwp W4, fwp b4, fwp W1a, fwp b1a, float* __restrict__ ws) {
  int idx = blockIdx.x * 256 + threadIdx.x;
  if (idx >= W_EXT) return;
  if (idx >= W_TOTAL) {
    __hip_bfloat16* wb = (__hip_bfloat16*)(ws + W_TOTAL);
    int e = idx - W_TOTAL;
    if (e < 2048) {
      int j = e & 7, L = (e >> 3) & 63, hs = e >> 9;
      int h = hs >> 1, s = hs & 1;
      float v = W2b[(h * 16 + (L & 15)) * 64 + s * 32 + ((L >> 4) & 3) * 8 + j];
      float hi = __bfloat162float(__float2bfloat16(v));
      wb[FRAG_B2_HI + e] = __float2bfloat16(v);
      wb[FRAG_B2_LO + e] = __float2bfloat16(v - hi);
    } else {
      int e2 = e - 2048;
      int j = e2 & 7, L = (e2 >> 3) & 63;
      int su = L & 15, q = L >> 4;
      float v = (su < 8) ? W2c[su * 32 + q * 8 + j] : 0.f;
      wb[FRAG_C + e2] = __float2bfloat16(v);
    }
    return;
  }
  float v;
  if (idx < O_B2A)       { int p = idx;          int su = p / 64, f = p % 64;   v = W2a[f * 18 + su]; }
  else if (idx < O_W2B)  { v = b2a[idx - O_B2A]; }
  else if (idx < O_B2B)  { v = W2b[idx - O_W2B]; }
  else if (idx < O_W2CT) { v = b2b[idx - O_B2B]; }
  else if (idx < O_B2C)  { int p = idx - O_W2CT; int o = p / 8, su = p % 8;     v = W2c[su * 32 + o]; }
  else if (idx < O_WIHT) { v = b2c[idx - O_B2C]; }
  else if (idx < O_BIH)  { int p = idx - O_WIHT; int k = p / 192, o = p % 192;  v = Wih[o * 10 + k]; }
  else if (idx < O_WHHT) { v = bih[idx - O_BIH]; }
  else if (idx < O_BHH)  { int p = idx - O_WHHT; int k = p / 192, o = p % 192;  v = Whh[o * 64 + k]; }
  else if (idx < O_W4T)  { v = bhh[idx - O_BHH]; }
  else if (idx < O_B4)   { int p = idx - O_W4T;  int k = p / 8, su = p % 8;     v = W4[su * 64 + k]; }
  else if (idx < O_W3AT) { v = b4[idx - O_B4]; }
  else if (idx < O_B3A)  { int p = idx - O_W3AT; int k = p / 64, f = p % 64;    v = W3a[f * 8 + k]; }
  else if (idx < O_W3BT) { v = b3a[idx - O_B3A]; }
  else if (idx < O_B3B)  { int p = idx - O_W3BT; int k = p / 32, f = p % 32;    v = W3b[f * 64 + k]; }
  else if (idx < O_W3CT) { v = b3b[idx - O_B3B]; }
  else if (idx < O_B3C)  { int p = idx - O_W3CT; int k = p / 4, c = p % 4;      v = W3c[c * 32 + k]; }
  else if (idx < O_W1AT) { v = b3c[idx - O_B3C]; }
  else if (idx < O_B1A)  { int p = idx - O_W1AT; int c = p / 8, su = p % 8;     v = W1a[su * 3 + c]; }
  else                   { v = b1a[idx - O_B1A]; }
  ws[idx] = v;
}

// c1 is pre-folded into sA2 -> m1 = sA1[a] + sA2'[jj] + ewv*wew
#define DO_STEP(KOFF, Y0, Y1, W0, W1, FH0, FL0, FH1, FL1)                      \
  {                                                                            \
    float4v x0 = *(const float4v*)&sA1[a * 68 + (KOFF)];                       \
    float4v x1 = *(const float4v*)&sA1[a * 68 + (KOFF) + 4];                   \
    float t0 = fmaxf(x0.x + Y0.x + ewv * W0.x, 0.f);                           \
    float t1 = fmaxf(x0.y + Y0.y + ewv * W0.y, 0.f);                           \
    float t2 = fmaxf(x0.z + Y0.z + ewv * W0.z, 0.f);                           \
    float t3 = fmaxf(x0.w + Y0.w + ewv * W0.w, 0.f);                           \
    float t4 = fmaxf(x1.x + Y1.x + ewv * W1.x, 0.f);                           \
    float t5 = fmaxf(x1.y + Y1.y + ewv * W1.y, 0.f);                           \
    float t6 = fmaxf(x1.z + Y1.z + ewv * W1.z, 0.f);                           \
    float t7 = fmaxf(x1.w + Y1.w + ewv * W1.w, 0.f);                           \
    short8 ahi, alo;                                                           \
    ahi[0] = bf16r(t0); ahi[1] = bf16r(t1); ahi[2] = bf16r(t2);                \
    ahi[3] = bf16r(t3); ahi[4] = bf16r(t4); ahi[5] = bf16r(t5);                \
    ahi[6] = bf16r(t6); ahi[7] = bf16r(t7);                                    \
    alo[0] = bf16r(t0 - bf16tof(ahi[0])); alo[1] = bf16r(t1 - bf16tof(ahi[1]));\
    alo[2] = bf16r(t2 - bf16tof(ahi[2])); alo[3] = bf16r(t3 - bf16tof(ahi[3]));\
    alo[4] = bf16r(t4 - bf16tof(ahi[4])); alo[5] = bf16r(t5 - bf16tof(ahi[5]));\
    alo[6] = bf16r(t6 - bf16tof(ahi[6])); alo[7] = bf16r(t7 - bf16tof(ahi[7]));\
    accb0 = __builtin_amdgcn_mfma_f32_16x16x32_bf16(ahi, FH0, accb0, 0, 0, 0); \
    accb0 = __builtin_amdgcn_mfma_f32_16x16x32_bf16(alo, FH0, accb0, 0, 0, 0); \
    accb0 = __builtin_amdgcn_mfma_f32_16x16x32_bf16(ahi, FL0, accb0, 0, 0, 0); \
    accb1 = __builtin_amdgcn_mfma_f32_16x16x32_bf16(ahi, FH1, accb1, 0, 0, 0); \
    accb1 = __builtin_amdgcn_mfma_f32_16x16x32_bf16(alo, FH1, accb1, 0, 0, 0); \
    accb1 = __builtin_amdgcn_mfma_f32_16x16x32_bf16(ahi, FL1, accb1, 0, 0, 0); \
  }

__global__ __launch_bounds__(256, 2) void gnn_fused(
    const float* __restrict__ read_gru_in,
    const float* __restrict__ gru_init,
    const float* __restrict__ feat,
    const float* __restrict__ edge_w,
    const float* __restrict__ noise_in,
    const float* __restrict__ xhat,
    const float* __restrict__ vep,
    const int* __restrict__ gnn_iter_p,
    const float* __restrict__ ws,
    float* __restrict__ out)
{
  __shared__ __attribute__((aligned(16))) float sA1[NN * 68];
  __shared__ __attribute__((aligned(16))) float sA2[NN * 68];   // holds A2 + c1 (folded)
  __shared__ __attribute__((aligned(16))) float sH [NN * 68];
  __shared__ __attribute__((aligned(16))) float sC1[64];
  __shared__ __attribute__((aligned(16))) float sWew[64];
  __shared__ __attribute__((aligned(16))) __hip_bfloat16 sM2[4 * 16 * 44];
  __shared__ __attribute__((aligned(16))) short sFrag[9 * 64 * 8];
  __shared__ float sNodes[NN * 9];
  __shared__ float sSum[NN * 8];
  __shared__ float sEw[ED];
  __shared__ float sX[NN];
  __shared__ float sV[NN];

  const int b = blockIdx.x;
  const int t = threadIdx.x;
  const int lane = t & 63;
  const int wv = t >> 6;
  const int quad = lane >> 4;
  const int lm = lane & 15;

  const __hip_bfloat16* wb = (const __hip_bfloat16*)(ws + W_TOTAL);

  // ---- stash MFMA B fragments into LDS ----
  if (t < 64) {
#pragma unroll
    for (int hs = 0; hs < 4; ++hs) {
      *(short8*)(sFrag + (hs * 64 + lane) * 8) =
          *(const short8*)(wb + FRAG_B2_HI + (hs * 64 + lane) * 8);
      *(short8*)(sFrag + ((4 + hs) * 64 + lane) * 8) =
          *(const short8*)(wb + FRAG_B2_LO + (hs * 64 + lane) * 8);
    }
    *(short8*)(sFrag + (8 * 64 + lane) * 8) = *(const short8*)(wb + FRAG_C + lane * 8);
  }

  // ---- per-sample inputs ----
  float noi = noise_in[b];
  for (int e = t; e < ED; e += 256) sEw[e] = edge_w[b * ED + e];
  if (t < NN) { sX[t] = xhat[b * NN + t]; sV[t] = vep[b * NN + t]; }
  if (t < 64) {
    sC1[t]  = ws[O_B2A + t] + noi * ws[O_W2AT + 17 * 64 + t];
    sWew[t] = ws[O_W2AT + 16 * 64 + t];
  }
#pragma unroll
  for (int i = 0; i < 8; ++i) {
    int p = t + 256 * i;
    sH[(p >> 6) * 68 + (p & 63)] = gru_init[b * (NN * HD) + p];
  }
  const int git = gnn_iter_p[0];

  for (int it = 0; it < NITER; ++it) {
    // ---- init_nodes ----
    if (it == 0) {
      int n = t >> 3, su = t & 7;
      float acc;
      if (git == 0) {
        acc = ws[O_B1A + su];
#pragma unroll
        for (int c = 0; c < 3; ++c)
          acc += ws[O_W1AT + c * 8 + su] * feat[b * (NN * 3) + n * 3 + c];
      } else {
        acc = read_gru_in[b * (NN * SUD) + t];
      }
      sNodes[n * 9 + su] = acc;
    }
    __syncthreads();

    // ---- A1/A2 node projections (c1 folded into A2) ----
#pragma unroll
    for (int i = 0; i < 8; ++i) {
      int p = t + 256 * i;
      int n = p >> 6, f = p & 63;
      float a1 = 0.f, a2 = 0.f;
#pragma unroll
      for (int su = 0; su < 8; ++su) {
        float nv = sNodes[n * 9 + su];
        a1 += ws[O_W2AT + su * 64 + f] * nv;
        a2 += ws[O_W2AT + (8 + su) * 64 + f] * nv;
      }
      sA1[n * 68 + f] = a1;
      sA2[n * 68 + f] = a2 + sC1[f];
    }
    __syncthreads();

    // ---- edge MLP via MFMA; laundered LDS offsets keep frags phase-local ----
    {
      const float b2b0 = ws[O_B2B + lm];
      const float b2b1 = ws[O_B2B + 16 + lm];
      const float b2cl = ws[O_B2C + lm];
      __hip_bfloat16* m2w = sM2 + wv * (16 * 44);
      const int kq0 = quad * 8, kq1 = 32 + quad * 8;
      for (int ni = 0; ni < 8; ++ni) {
        const int jj = wv * 8 + ni;
        int wo = 0; __asm__ __volatile__("" : "+v"(wo));   // opaque: defeat LICM
        float4v wwA = *(const float4v*)&sWew[wo + kq0];
        float4v wwB = *(const float4v*)&sWew[wo + kq0 + 4];
        float4v wwC = *(const float4v*)&sWew[wo + kq1];
        float4v wwD = *(const float4v*)&sWew[wo + kq1 + 4];
        float4v yA = *(const float4v*)&sA2[jj * 68 + kq0];
        float4v yB = *(const float4v*)&sA2[jj * 68 + kq0 + 4];
        float4v yC = *(const float4v*)&sA2[jj * 68 + kq1];
        float4v yD = *(const float4v*)&sA2[jj * 68 + kq1 + 4];
        float psum = 0.f;
#pragma unroll
        for (int tile = 0; tile < 2; ++tile) {
          int kk = tile * 16 + lm;
          int kk2 = (kk < 31) ? kk : 0;
          int a = kk2 + (kk2 >= jj ? 1 : 0);
          float ewv = (kk < 31) ? sEw[jj * 31 + kk] : 0.f;
          float4v accb0 = {0.f, 0.f, 0.f, 0.f};
          float4v accb1 = {0.f, 0.f, 0.f, 0.f};
          int fo = 0; __asm__ __volatile__("" : "+v"(fo)); // opaque per tile
          {
            short8 fh0 = *(const short8*)(sFrag + fo + (0 * 64 + lane) * 8);
            short8 fl0 = *(const short8*)(sFrag + fo + (4 * 64 + lane) * 8);
            short8 fh1 = *(const short8*)(sFrag + fo + (2 * 64 + lane) * 8);
            short8 fl1 = *(const short8*)(sFrag + fo + (6 * 64 + lane) * 8);
            DO_STEP(kq0, yA, yB, wwA, wwB, fh0, fl0, fh1, fl1);
          }
          {
            short8 fh0 = *(const short8*)(sFrag + fo + (1 * 64 + lane) * 8);
            short8 fl0 = *(const short8*)(sFrag + fo + (5 * 64 + lane) * 8);
            short8 fh1 = *(const short8*)(sFrag + fo + (3 * 64 + lane) * 8);
            short8 fl1 = *(const short8*)(sFrag + fo + (7 * 64 + lane) * 8);
            DO_STEP(kq1, yC, yD, wwC, wwD, fh0, fl0, fh1, fl1);
          }
#pragma unroll
          for (int r = 0; r < 4; ++r) {
            float m20 = fmaxf(accb0[r] + b2b0, 0.f);
            float m21 = fmaxf(accb1[r] + b2b1, 0.f);
            m2w[(quad * 4 + r) * 44 + lm]      = __float2bfloat16(m20);
            m2w[(quad * 4 + r) * 44 + 16 + lm] = __float2bfloat16(m21);
          }
          __asm__ __volatile__("" ::: "memory");
          short8 ac  = *(const short8*)(m2w + lm * 44 + quad * 8);
          short8 fcf = *(const short8*)(sFrag + fo + (8 * 64 + lane) * 8);
          float4v c3 = {0.f, 0.f, 0.f, 0.f};
          c3 = __builtin_amdgcn_mfma_f32_16x16x32_bf16(ac, fcf, c3, 0, 0, 0);
#pragma unroll
          for (int r = 0; r < 4; ++r) {
            float v = fmaxf(c3[r] + b2cl, 0.f);
            if (tile == 1 && r == 3) v = (quad == 3) ? 0.f : v;
            psum += v;
          }
          __asm__ __volatile__("" ::: "memory");
        }
        psum += __shfl_xor(psum, 16);
        psum += __shfl_xor(psum, 32);
        if (lane < 8) sSum[jj * 8 + lane] = psum;
      }
    }
    __syncthreads();

    // ---- GRU: lane owns gate-column oo for 8 nodes; direct wave-private writes ----
    {
      int oo = t & 63, wq = t >> 6;
      float ar[8], az[8], inx[8], hn[8];
      {
        float br  = ws[O_BIH + oo]        + ws[O_BHH + oo];
        float bz  = ws[O_BIH + 64 + oo]   + ws[O_BHH + 64 + oo];
        float bni = ws[O_BIH + 128 + oo];
        float bnh = ws[O_BHH + 128 + oo];
#pragma unroll
        for (int j = 0; j < 8; ++j) { ar[j] = br; az[j] = bz; inx[j] = bni; hn[j] = bnh; }
      }
#pragma unroll
      for (int k = 0; k < 8; ++k) {
        float wr = ws[O_WIHT + k * 192 + oo];
        float wz = ws[O_WIHT + k * 192 + 64 + oo];
        float wn = ws[O_WIHT + k * 192 + 128 + oo];
#pragma unroll
        for (int j = 0; j < 8; ++j) {
          float g = sSum[(wq + 4 * j) * 8 + k];
          ar[j] += wr * g; az[j] += wz * g; inx[j] += wn * g;
        }
      }
      {
        float wr = ws[O_WIHT + 8 * 192 + oo];
        float wz = ws[O_WIHT + 8 * 192 + 64 + oo];
        float wn = ws[O_WIHT + 8 * 192 + 128 + oo];
#pragma unroll
        for (int j = 0; j < 8; ++j) {
          float g = sX[wq + 4 * j];
          ar[j] += wr * g; az[j] += wz * g; inx[j] += wn * g;
        }
        wr = ws[O_WIHT + 9 * 192 + oo];
        wz = ws[O_WIHT + 9 * 192 + 64 + oo];
        wn = ws[O_WIHT + 9 * 192 + 128 + oo];
#pragma unroll
        for (int j = 0; j < 8; ++j) {
          float g = sV[wq + 4 * j];
          ar[j] += wr * g; az[j] += wz * g; inx[j] += wn * g;
        }
      }
#pragma unroll 2
      for (int k = 0; k < 64; ++k) {
        float wr = ws[O_WHHT + k * 192 + oo];
        float wz = ws[O_WHHT + k * 192 + 64 + oo];
        float wn = ws[O_WHHT + k * 192 + 128 + oo];
#pragma unroll
        for (int j = 0; j < 8; ++j) {
          float hk = sH[(wq + 4 * j) * 68 + k];
          ar[j] += wr * hk; az[j] += wz * hk; hn[j] += wn * hk;
        }
      }
#pragma unroll
      for (int j = 0; j < 8; ++j) {
        int n = wq + 4 * j;                 // rows wave-private; DS in-order per wave
        float r = 1.f / (1.f + __expf(-ar[j]));
        float z = 1.f / (1.f + __expf(-az[j]));
        float cd = inx[j] + r * hn[j];
        float e2 = __expf(2.f * cd);
        float th = 1.f - 2.f / (e2 + 1.f);
        sH[n * 68 + oo] = (1.f - z) * th + z * sH[n * 68 + oo];
      }
    }
    __syncthreads();

    // ---- read_gru = W4 @ h + b4 -> sNodes ----
    {
      int n = t >> 3, su = t & 7;
      float c0 = 0.f, c1v = 0.f, c2 = 0.f, c3v = 0.f;
#pragma unroll
      for (int k = 0; k < 64; k += 4) {
        c0  += ws[O_W4T + (k + 0) * 8 + su] * sH[n * 68 + k + 0];
        c1v += ws[O_W4T + (k + 1) * 8 + su] * sH[n * 68 + k + 1];
        c2  += ws[O_W4T + (k + 2) * 8 + su] * sH[n * 68 + k + 2];
        c3v += ws[O_W4T + (k + 3) * 8 + su] * sH[n * 68 + k + 3];
      }
      sNodes[n * 9 + su] = ws[O_B4 + su] + ((c0 + c1v) + (c2 + c3v));
    }
    __syncthreads();
  } // iterations

  // ---- head ----
#pragma unroll
  for (int i = 0; i < 8; ++i) {
    int p = t + 256 * i;
    int n = p >> 6, f = p & 63;
    float acc = ws[O_B3A + f];
#pragma unroll
    for (int k = 0; k < 8; ++k) acc += ws[O_W3AT + k * 64 + f] * sNodes[n * 9 + k];
    sA1[n * 68 + f] = acc;
  }
  __syncthreads();
#pragma unroll
  for (int i = 0; i < 4; ++i) {
    int p = t + 256 * i;
    int n = p >> 5, f = p & 31;
    float c0 = 0.f, c1v = 0.f, c2 = 0.f, c3v = 0.f;
#pragma unroll
    for (int k = 0; k < 64; k += 4) {
      c0  += ws[O_W3BT + (k + 0) * 32 + f] * sA1[n * 68 + k + 0];
      c1v += ws[O_W3BT + (k + 1) * 32 + f] * sA1[n * 68 + k + 1];
      c2  += ws[O_W3BT + (k + 2) * 32 + f] * sA1[n * 68 + k + 2];
      c3v += ws[O_W3BT + (k + 3) * 32 + f] * sA1[n * 68 + k + 3];
    }
    sA2[n * 33 + f] = ws[O_B3B + f] + ((c0 + c1v) + (c2 + c3v));
  }
  __syncthreads();
  if (t < 128) {
    int n = t >> 2, c = t & 3;
    float acc = ws[O_B3C + c];
#pragma unroll
    for (int k = 0; k < 32; ++k) acc += ws[O_W3CT + k * 4 + c] * sA2[n * 33 + k];
    out[b * (NN * NCD) + t] = acc;
  }
  out[BB * NN * NCD + b * (NN * SUD) + t] = sNodes[(t >> 3) * 9 + (t & 7)];
#pragma unroll
  for (int i = 0; i < 8; ++i) {
    int p = t + 256 * i;
    out[BB * NN * NCD + BB * NN * SUD + b * (NN * HD) + p] =
        sH[(p >> 6) * 68 + (p & 63)];
  }
}

extern "C" void kernel_launch(void* const* d_in, const int* in_sizes, int n_in,
                              void* d_out, int out_size, void* d_ws, size_t ws_size,
                              hipStream_t stream) {
  typedef const float* F32;
  F32 read_gru = (F32)d_in[0];
  F32 gru_init = (F32)d_in[1];
  F32 feat     = (F32)d_in[2];
  F32 edge_w   = (F32)d_in[3];
  F32 noise    = (F32)d_in[4];
  F32 xh       = (F32)d_in[5];
  F32 vp       = (F32)d_in[6];
  F32 W1a = (F32)d_in[7];  F32 b1a = (F32)d_in[8];
  F32 W2a = (F32)d_in[9];  F32 b2a = (F32)d_in[10];
  F32 W2b = (F32)d_in[11]; F32 b2b = (F32)d_in[12];
  F32 W2c = (F32)d_in[13]; F32 b2c = (F32)d_in[14];
  F32 Wih = (F32)d_in[15]; F32 bih = (F32)d_in[16];
  F32 Whh = (F32)d_in[17]; F32 bhh = (F32)d_in[18];
  F32 W3a = (F32)d_in[19]; F32 b3a = (F32)d_in[20];
  F32 W3b = (F32)d_in[21]; F32 b3b = (F32)d_in[22];
  F32 W3c = (F32)d_in[23]; F32 b3c = (F32)d_in[24];
  F32 W4  = (F32)d_in[25]; F32 b4  = (F32)d_in[26];
  const int* git = (const int*)d_in[27];
  float* ws = (float*)d_ws;   // needs 95,184 B

  prep_weights<<<(W_EXT + 255) / 256, 256, 0, stream>>>(
      W2a, b2a, W2b, b2b, W2c, b2c, Wih, bih, Whh, bhh,
      W3a, b3a, W3b, b3b, W3c, b3c, W4, b4, W1a, b1a, ws);

  gnn_fused<<<BB, 256, 0, stream>>>(read_gru, gru_init, feat, edge_w, noise,
                                    xh, vp, git, ws, (float*)d_out);
}

// Round 9
// 667.117 us; speedup vs baseline: 1.3849x; 1.2502x over previous
//
#include <hip/hip_runtime.h>
#include <hip/hip_bf16.h>

#define BB 1024
#define NN 32
#define SUD 8
#define HD 64
#define NCD 4
#define ED 992      // NN*(NN-1)
#define NITER 5

// ---- fp32 weight workspace layout (element offsets into d_ws) ----
#define O_W2AT 0        // 18 x 64   W2aT[su][f] = W2a[f][su]
#define O_B2A  1152     // 64
#define O_W2B  1216     // 32 x 64
#define O_B2B  3264     // 32
#define O_W2CT 3296     // 32 x 8
#define O_B2C  3552     // 8
#define O_WIHT 3560     // 10 x 192  WihT[k][o]
#define O_BIH  5480     // 192
#define O_WHHT 5672     // 64 x 192  WhhT[k][o]
#define O_BHH  17960    // 192
#define O_W4T  18152    // 64 x 8    W4T[k][su]
#define O_B4   18664    // 8
#define O_W3AT 18672    // 8 x 64    W3aT[k][f]
#define O_B3A  19184    // 64
#define O_W3BT 19248    // 64 x 32   W3bT[k][f]
#define O_B3B  21296    // 32
#define O_W3CT 21328    // 32 x 4    W3cT[k][c]
#define O_B3C  21456    // 4
#define O_W1AT 21460    // 3 x 8     W1aT[c][su]
#define O_B1A  21484    // 8
#define W_TOTAL 21492   // floats

// ---- bf16 MFMA fragment region, at byte offset W_TOTAL*4 ----
#define FRAG_B2_HI 0
#define FRAG_B2_LO 2048
#define FRAG_C     4096
#define W_EXT (W_TOTAL + 2560)

typedef const float* fwp;
typedef __attribute__((ext_vector_type(8))) short short8;
typedef __attribute__((ext_vector_type(4))) float float4v;

__device__ __forceinline__ short bf16r(float x) {
  __hip_bfloat16 h = __float2bfloat16(x);
  return __builtin_bit_cast(short, h);
}
__device__ __forceinline__ float bf16tof(short s) {
  __hip_bfloat16 h = __builtin_bit_cast(__hip_bfloat16, s);
  return __bfloat162float(h);
}

__global__ void prep_weights(fwp W2a, fwp b2a, fwp W2b, fwp b2b, fwp W2c, fwp b2c,
                             fwp Wih, fwp bih, fwp Whh, fwp bhh,
                             fwp W3a, fwp b3a, fwp W3b, fwp b3b, fwp W3c, fwp b3c,
                             fwp W4, fwp b4, fwp W1a, fwp b1a, float* __restrict__ ws) {
  int idx = blockIdx.x * 256 + threadIdx.x;
  if (idx >= W_EXT) return;
  if (idx >= W_TOTAL) {
    __hip_bfloat16* wb = (__hip_bfloat16*)(ws + W_TOTAL);
    int e = idx - W_TOTAL;
    if (e < 2048) {
      int j = e & 7, L = (e >> 3) & 63, hs = e >> 9;
      int h = hs >> 1, s = hs & 1;
      float v = W2b[(h * 16 + (L & 15)) * 64 + s * 32 + ((L >> 4) & 3) * 8 + j];
      float hi = __bfloat162float(__float2bfloat16(v));
      wb[FRAG_B2_HI + e] = __float2bfloat16(v);
      wb[FRAG_B2_LO + e] = __float2bfloat16(v - hi);
    } else {
      int e2 = e - 2048;
      int j = e2 & 7, L = (e2 >> 3) & 63;
      int su = L & 15, q = L >> 4;
      float v = (su < 8) ? W2c[su * 32 + q * 8 + j] : 0.f;
      wb[FRAG_C + e2] = __float2bfloat16(v);
    }
    return;
  }
  float v;
  if (idx < O_B2A)       { int p = idx;          int su = p / 64, f = p % 64;   v = W2a[f * 18 + su]; }
  else if (idx < O_W2B)  { v = b2a[idx - O_B2A]; }
  else if (idx < O_B2B)  { v = W2b[idx - O_W2B]; }
  else if (idx < O_W2CT) { v = b2b[idx - O_B2B]; }
  else if (idx < O_B2C)  { int p = idx - O_W2CT; int o = p / 8, su = p % 8;     v = W2c[su * 32 + o]; }
  else if (idx < O_WIHT) { v = b2c[idx - O_B2C]; }
  else if (idx < O_BIH)  { int p = idx - O_WIHT; int k = p / 192, o = p % 192;  v = Wih[o * 10 + k]; }
  else if (idx < O_WHHT) { v = bih[idx - O_BIH]; }
  else if (idx < O_BHH)  { int p = idx - O_WHHT; int k = p / 192, o = p % 192;  v = Whh[o * 64 + k]; }
  else if (idx < O_W4T)  { v = bhh[idx - O_BHH]; }
  else if (idx < O_B4)   { int p = idx - O_W4T;  int k = p / 8, su = p % 8;     v = W4[su * 64 + k]; }
  else if (idx < O_W3AT) { v = b4[idx - O_B4]; }
  else if (idx < O_B3A)  { int p = idx - O_W3AT; int k = p / 64, f = p % 64;    v = W3a[f * 8 + k]; }
  else if (idx < O_W3BT) { v = b3a[idx - O_B3A]; }
  else if (idx < O_B3B)  { int p = idx - O_W3BT; int k = p / 32, f = p % 32;    v = W3b[f * 64 + k]; }
  else if (idx < O_W3CT) { v = b3b[idx - O_B3B]; }
  else if (idx < O_B3C)  { int p = idx - O_W3CT; int k = p / 4, c = p % 4;      v = W3c[c * 32 + k]; }
  else if (idx < O_W1AT) { v = b3c[idx - O_B3C]; }
  else if (idx < O_B1A)  { int p = idx - O_W1AT; int c = p / 8, su = p % 8;     v = W1a[su * 3 + c]; }
  else                   { v = b1a[idx - O_B1A]; }
  ws[idx] = v;
}

// c1 pre-folded into sA2 -> m1 = sA1[a] + sA2'[jj] + ewv*wew
#define DO_STEP(KOFF, Y0, Y1, W0, W1, FH0, FL0, FH1, FL1)                      \
  {                                                                            \
    float4v x0 = *(const float4v*)&sA1[a * 68 + (KOFF)];                       \
    float4v x1 = *(const float4v*)&sA1[a * 68 + (KOFF) + 4];                   \
    float t0 = fmaxf(x0.x + Y0.x + ewv * W0.x, 0.f);                           \
    float t1 = fmaxf(x0.y + Y0.y + ewv * W0.y, 0.f);                           \
    float t2 = fmaxf(x0.z + Y0.z + ewv * W0.z, 0.f);                           \
    float t3 = fmaxf(x0.w + Y0.w + ewv * W0.w, 0.f);                           \
    float t4 = fmaxf(x1.x + Y1.x + ewv * W1.x, 0.f);                           \
    float t5 = fmaxf(x1.y + Y1.y + ewv * W1.y, 0.f);                           \
    float t6 = fmaxf(x1.z + Y1.z + ewv * W1.z, 0.f);                           \
    float t7 = fmaxf(x1.w + Y1.w + ewv * W1.w, 0.f);                           \
    short8 ahi, alo;                                                           \
    ahi[0] = bf16r(t0); ahi[1] = bf16r(t1); ahi[2] = bf16r(t2);                \
    ahi[3] = bf16r(t3); ahi[4] = bf16r(t4); ahi[5] = bf16r(t5);                \
    ahi[6] = bf16r(t6); ahi[7] = bf16r(t7);                                    \
    alo[0] = bf16r(t0 - bf16tof(ahi[0])); alo[1] = bf16r(t1 - bf16tof(ahi[1]));\
    alo[2] = bf16r(t2 - bf16tof(ahi[2])); alo[3] = bf16r(t3 - bf16tof(ahi[3]));\
    alo[4] = bf16r(t4 - bf16tof(ahi[4])); alo[5] = bf16r(t5 - bf16tof(ahi[5]));\
    alo[6] = bf16r(t6 - bf16tof(ahi[6])); alo[7] = bf16r(t7 - bf16tof(ahi[7]));\
    accb0 = __builtin_amdgcn_mfma_f32_16x16x32_bf16(ahi, FH0, accb0, 0, 0, 0); \
    accb0 = __builtin_amdgcn_mfma_f32_16x16x32_bf16(alo, FH0, accb0, 0, 0, 0); \
    accb0 = __builtin_amdgcn_mfma_f32_16x16x32_bf16(ahi, FL0, accb0, 0, 0, 0); \
    accb1 = __builtin_amdgcn_mfma_f32_16x16x32_bf16(ahi, FH1, accb1, 0, 0, 0); \
    accb1 = __builtin_amdgcn_mfma_f32_16x16x32_bf16(alo, FH1, accb1, 0, 0, 0); \
    accb1 = __builtin_amdgcn_mfma_f32_16x16x32_bf16(ahi, FL1, accb1, 0, 0, 0); \
  }

// launch_bounds(256,1): min 1 wave/EU -> allocator may use the full register
// file. (256,2) pinned the arch-VGPR partition at 128 (AGPR split heuristic)
// and spilled ~40 arch regs/thread to scratch every round (R5-R8: WRITE~230MB).
__global__ __launch_bounds__(256, 1) void gnn_fused(
    const float* __restrict__ read_gru_in,
    const float* __restrict__ gru_init,
    const float* __restrict__ feat,
    const float* __restrict__ edge_w,
    const float* __restrict__ noise_in,
    const float* __restrict__ xhat,
    const float* __restrict__ vep,
    const int* __restrict__ gnn_iter_p,
    const float* __restrict__ ws,
    float* __restrict__ out)
{
  __shared__ __attribute__((aligned(16))) float sA1[NN * 68];
  __shared__ __attribute__((aligned(16))) float sA2[NN * 68];   // A2 + c1 (folded)
  __shared__ __attribute__((aligned(16))) float sH [NN * 68];
  __shared__ __attribute__((aligned(16))) float sC1[64];
  __shared__ __attribute__((aligned(16))) float sWew[64];
  __shared__ __attribute__((aligned(16))) __hip_bfloat16 sM2[4 * 16 * 44];
  __shared__ __attribute__((aligned(16))) short sFrag[9 * 64 * 8];
  __shared__ float sNodes[NN * 9];
  __shared__ float sSum[NN * 8];
  __shared__ float sEw[ED];
  __shared__ float sX[NN];
  __shared__ float sV[NN];

  const int b = blockIdx.x;
  const int t = threadIdx.x;
  const int lane = t & 63;
  const int wv = t >> 6;
  const int quad = lane >> 4;
  const int lm = lane & 15;

  const __hip_bfloat16* wb = (const __hip_bfloat16*)(ws + W_TOTAL);

  // ---- stash MFMA B fragments into LDS ----
  if (t < 64) {
#pragma unroll
    for (int hs = 0; hs < 4; ++hs) {
      *(short8*)(sFrag + (hs * 64 + lane) * 8) =
          *(const short8*)(wb + FRAG_B2_HI + (hs * 64 + lane) * 8);
      *(short8*)(sFrag + ((4 + hs) * 64 + lane) * 8) =
          *(const short8*)(wb + FRAG_B2_LO + (hs * 64 + lane) * 8);
    }
    *(short8*)(sFrag + (8 * 64 + lane) * 8) = *(const short8*)(wb + FRAG_C + lane * 8);
  }

  // ---- per-sample inputs ----
  float noi = noise_in[b];
  for (int e = t; e < ED; e += 256) sEw[e] = edge_w[b * ED + e];
  if (t < NN) { sX[t] = xhat[b * NN + t]; sV[t] = vep[b * NN + t]; }
  if (t < 64) {
    sC1[t]  = ws[O_B2A + t] + noi * ws[O_W2AT + 17 * 64 + t];
    sWew[t] = ws[O_W2AT + 16 * 64 + t];
  }
#pragma unroll
  for (int i = 0; i < 8; ++i) {
    int p = t + 256 * i;
    sH[(p >> 6) * 68 + (p & 63)] = gru_init[b * (NN * HD) + p];
  }
  const int git = gnn_iter_p[0];

  for (int it = 0; it < NITER; ++it) {
    // ---- init_nodes ----
    if (it == 0) {
      int n = t >> 3, su = t & 7;
      float acc;
      if (git == 0) {
        acc = ws[O_B1A + su];
#pragma unroll
        for (int c = 0; c < 3; ++c)
          acc += ws[O_W1AT + c * 8 + su] * feat[b * (NN * 3) + n * 3 + c];
      } else {
        acc = read_gru_in[b * (NN * SUD) + t];
      }
      sNodes[n * 9 + su] = acc;
    }
    __syncthreads();

    // ---- A1/A2 node projections (c1 folded into A2) ----
#pragma unroll
    for (int i = 0; i < 8; ++i) {
      int p = t + 256 * i;
      int n = p >> 6, f = p & 63;
      float a1 = 0.f, a2 = 0.f;
#pragma unroll
      for (int su = 0; su < 8; ++su) {
        float nv = sNodes[n * 9 + su];
        a1 += ws[O_W2AT + su * 64 + f] * nv;
        a2 += ws[O_W2AT + (8 + su) * 64 + f] * nv;
      }
      sA1[n * 68 + f] = a1;
      sA2[n * 68 + f] = a2 + sC1[f];
    }
    __syncthreads();

    // ---- edge MLP via MFMA ----
    {
      short8 fbh00 = *(const short8*)(sFrag + (0 * 64 + lane) * 8);
      short8 fbh01 = *(const short8*)(sFrag + (1 * 64 + lane) * 8);
      short8 fbh10 = *(const short8*)(sFrag + (2 * 64 + lane) * 8);
      short8 fbh11 = *(const short8*)(sFrag + (3 * 64 + lane) * 8);
      short8 fbl00 = *(const short8*)(sFrag + (4 * 64 + lane) * 8);
      short8 fbl01 = *(const short8*)(sFrag + (5 * 64 + lane) * 8);
      short8 fbl10 = *(const short8*)(sFrag + (6 * 64 + lane) * 8);
      short8 fbl11 = *(const short8*)(sFrag + (7 * 64 + lane) * 8);
      short8 fcf   = *(const short8*)(sFrag + (8 * 64 + lane) * 8);
      const float b2b0 = ws[O_B2B + lm];
      const float b2b1 = ws[O_B2B + 16 + lm];
      const float b2cl = ws[O_B2C + lm];

      __hip_bfloat16* m2w = sM2 + wv * (16 * 44);
      const int kq0 = quad * 8, kq1 = 32 + quad * 8;
      float4v wwA = *(const float4v*)&sWew[kq0];
      float4v wwB = *(const float4v*)&sWew[kq0 + 4];
      float4v wwC = *(const float4v*)&sWew[kq1];
      float4v wwD = *(const float4v*)&sWew[kq1 + 4];
      for (int ni = 0; ni < 8; ++ni) {
        const int jj = wv * 8 + ni;
        float4v yA = *(const float4v*)&sA2[jj * 68 + kq0];
        float4v yB = *(const float4v*)&sA2[jj * 68 + kq0 + 4];
        float4v yC = *(const float4v*)&sA2[jj * 68 + kq1];
        float4v yD = *(const float4v*)&sA2[jj * 68 + kq1 + 4];
        float psum = 0.f;
#pragma unroll
        for (int tile = 0; tile < 2; ++tile) {
          int kk = tile * 16 + lm;
          int kk2 = (kk < 31) ? kk : 0;
          int a = kk2 + (kk2 >= jj ? 1 : 0);
          float ewv = (kk < 31) ? sEw[jj * 31 + kk] : 0.f;
          float4v accb0 = {0.f, 0.f, 0.f, 0.f};
          float4v accb1 = {0.f, 0.f, 0.f, 0.f};
          DO_STEP(kq0, yA, yB, wwA, wwB, fbh00, fbl00, fbh10, fbl10);
          DO_STEP(kq1, yC, yD, wwC, wwD, fbh01, fbl01, fbh11, fbl11);
#pragma unroll
          for (int r = 0; r < 4; ++r) {
            float m20 = fmaxf(accb0[r] + b2b0, 0.f);
            float m21 = fmaxf(accb1[r] + b2b1, 0.f);
            m2w[(quad * 4 + r) * 44 + lm]      = __float2bfloat16(m20);
            m2w[(quad * 4 + r) * 44 + 16 + lm] = __float2bfloat16(m21);
          }
          __asm__ __volatile__("" ::: "memory");
          short8 ac = *(const short8*)(m2w + lm * 44 + quad * 8);
          float4v c3 = {0.f, 0.f, 0.f, 0.f};
          c3 = __builtin_amdgcn_mfma_f32_16x16x32_bf16(ac, fcf, c3, 0, 0, 0);
#pragma unroll
          for (int r = 0; r < 4; ++r) {
            float v = fmaxf(c3[r] + b2cl, 0.f);
            if (tile == 1 && r == 3) v = (quad == 3) ? 0.f : v;
            psum += v;
          }
          __asm__ __volatile__("" ::: "memory");
        }
        psum += __shfl_xor(psum, 16);
        psum += __shfl_xor(psum, 32);
        if (lane < 8) sSum[jj * 8 + lane] = psum;
      }
    }
    __syncthreads();

    // ---- GRU: lane owns gate-column oo for 8 nodes; direct wave-private writes ----
    {
      int oo = t & 63, wq = t >> 6;
      float ar[8], az[8], inx[8], hn[8];
      {
        float br  = ws[O_BIH + oo]        + ws[O_BHH + oo];
        float bz  = ws[O_BIH + 64 + oo]   + ws[O_BHH + 64 + oo];
        float bni = ws[O_BIH + 128 + oo];
        float bnh = ws[O_BHH + 128 + oo];
#pragma unroll
        for (int j = 0; j < 8; ++j) { ar[j] = br; az[j] = bz; inx[j] = bni; hn[j] = bnh; }
      }
#pragma unroll
      for (int k = 0; k < 8; ++k) {
        float wr = ws[O_WIHT + k * 192 + oo];
        float wz = ws[O_WIHT + k * 192 + 64 + oo];
        float wn = ws[O_WIHT + k * 192 + 128 + oo];
#pragma unroll
        for (int j = 0; j < 8; ++j) {
          float g = sSum[(wq + 4 * j) * 8 + k];
          ar[j] += wr * g; az[j] += wz * g; inx[j] += wn * g;
        }
      }
      {
        float wr = ws[O_WIHT + 8 * 192 + oo];
        float wz = ws[O_WIHT + 8 * 192 + 64 + oo];
        float wn = ws[O_WIHT + 8 * 192 + 128 + oo];
#pragma unroll
        for (int j = 0; j < 8; ++j) {
          float g = sX[wq + 4 * j];
          ar[j] += wr * g; az[j] += wz * g; inx[j] += wn * g;
        }
        wr = ws[O_WIHT + 9 * 192 + oo];
        wz = ws[O_WIHT + 9 * 192 + 64 + oo];
        wn = ws[O_WIHT + 9 * 192 + 128 + oo];
#pragma unroll
        for (int j = 0; j < 8; ++j) {
          float g = sV[wq + 4 * j];
          ar[j] += wr * g; az[j] += wz * g; inx[j] += wn * g;
        }
      }
#pragma unroll 2
      for (int k = 0; k < 64; ++k) {
        float wr = ws[O_WHHT + k * 192 + oo];
        float wz = ws[O_WHHT + k * 192 + 64 + oo];
        float wn = ws[O_WHHT + k * 192 + 128 + oo];
#pragma unroll
        for (int j = 0; j < 8; ++j) {
          float hk = sH[(wq + 4 * j) * 68 + k];
          ar[j] += wr * hk; az[j] += wz * hk; hn[j] += wn * hk;
        }
      }
#pragma unroll
      for (int j = 0; j < 8; ++j) {
        int n = wq + 4 * j;                 // rows wave-private; DS in-order per wave
        float r = 1.f / (1.f + __expf(-ar[j]));
        float z = 1.f / (1.f + __expf(-az[j]));
        float cd = inx[j] + r * hn[j];
        float e2 = __expf(2.f * cd);
        float th = 1.f - 2.f / (e2 + 1.f);
        sH[n * 68 + oo] = (1.f - z) * th + z * sH[n * 68 + oo];
      }
    }
    __syncthreads();

    // ---- read_gru = W4 @ h + b4 -> sNodes ----
    {
      int n = t >> 3, su = t & 7;
      float c0 = 0.f, c1v = 0.f, c2 = 0.f, c3v = 0.f;
#pragma unroll
      for (int k = 0; k < 64; k += 4) {
        c0  += ws[O_W4T + (k + 0) * 8 + su] * sH[n * 68 + k + 0];
        c1v += ws[O_W4T + (k + 1) * 8 + su] * sH[n * 68 + k + 1];
        c2  += ws[O_W4T + (k + 2) * 8 + su] * sH[n * 68 + k + 2];
        c3v += ws[O_W4T + (k + 3) * 8 + su] * sH[n * 68 + k + 3];
      }
      sNodes[n * 9 + su] = ws[O_B4 + su] + ((c0 + c1v) + (c2 + c3v));
    }
    __syncthreads();
  } // iterations

  // ---- head ----
#pragma unroll
  for (int i = 0; i < 8; ++i) {
    int p = t + 256 * i;
    int n = p >> 6, f = p & 63;
    float acc = ws[O_B3A + f];
#pragma unroll
    for (int k = 0; k < 8; ++k) acc += ws[O_W3AT + k * 64 + f] * sNodes[n * 9 + k];
    sA1[n * 68 + f] = acc;
  }
  __syncthreads();
#pragma unroll
  for (int i = 0; i < 4; ++i) {
    int p = t + 256 * i;
    int n = p >> 5, f = p & 31;
    float c0 = 0.f, c1v = 0.f, c2 = 0.f, c3v = 0.f;
#pragma unroll
    for (int k = 0; k < 64; k += 4) {
      c0  += ws[O_W3BT + (k + 0) * 32 + f] * sA1[n * 68 + k + 0];
      c1v += ws[O_W3BT + (k + 1) * 32 + f] * sA1[n * 68 + k + 1];
      c2  += ws[O_W3BT + (k + 2) * 32 + f] * sA1[n * 68 + k + 2];
      c3v += ws[O_W3BT + (k + 3) * 32 + f] * sA1[n * 68 + k + 3];
    }
    sA2[n * 33 + f] = ws[O_B3B + f] + ((c0 + c1v) + (c2 + c3v));
  }
  __syncthreads();
  if (t < 128) {
    int n = t >> 2, c = t & 3;
    float acc = ws[O_B3C + c];
#pragma unroll
    for (int k = 0; k < 32; ++k) acc += ws[O_W3CT + k * 4 + c] * sA2[n * 33 + k];
    out[b * (NN * NCD) + t] = acc;
  }
  out[BB * NN * NCD + b * (NN * SUD) + t] = sNodes[(t >> 3) * 9 + (t & 7)];
#pragma unroll
  for (int i = 0; i < 8; ++i) {
    int p = t + 256 * i;
    out[BB * NN * NCD + BB * NN * SUD + b * (NN * HD) + p] =
        sH[(p >> 6) * 68 + (p & 63)];
  }
}

extern "C" void kernel_launch(void* const* d_in, const int* in_sizes, int n_in,
                              void* d_out, int out_size, void* d_ws, size_t ws_size,
                              hipStream_t stream) {
  typedef const float* F32;
  F32 read_gru = (F32)d_in[0];
  F32 gru_init = (F32)d_in[1];
  F32 feat     = (F32)d_in[2];
  F32 edge_w   = (F32)d_in[3];
  F32 noise    = (F32)d_in[4];
  F32 xh       = (F32)d_in[5];
  F32 vp       = (F32)d_in[6];
  F32 W1a = (F32)d_in[7];  F32 b1a = (F32)d_in[8];
  F32 W2a = (F32)d_in[9];  F32 b2a = (F32)d_in[10];
  F32 W2b = (F32)d_in[11]; F32 b2b = (F32)d_in[12];
  F32 W2c = (F32)d_in[13]; F32 b2c = (F32)d_in[14];
  F32 Wih = (F32)d_in[15]; F32 bih = (F32)d_in[16];
  F32 Whh = (F32)d_in[17]; F32 bhh = (F32)d_in[18];
  F32 W3a = (F32)d_in[19]; F32 b3a = (F32)d_in[20];
  F32 W3b = (F32)d_in[21]; F32 b3b = (F32)d_in[22];
  F32 W3c = (F32)d_in[23]; F32 b3c = (F32)d_in[24];
  F32 W4  = (F32)d_in[25]; F32 b4  = (F32)d_in[26];
  const int* git = (const int*)d_in[27];
  float* ws = (float*)d_ws;   // needs 95,184 B

  prep_weights<<<(W_EXT + 255) / 256, 256, 0, stream>>>(
      W2a, b2a, W2b, b2b, W2c, b2c, Wih, bih, Whh, bhh,
      W3a, b3a, W3b, b3b, W3c, b3c, W4, b4, W1a, b1a, ws);

  gnn_fused<<<BB, 256, 0, stream>>>(read_gru, gru_init, feat, edge_w, noise,
                                    xh, vp, git, ws, (float*)d_out);
}

// Round 10
// 474.786 us; speedup vs baseline: 1.9459x; 1.4051x over previous
//
#include <hip/hip_runtime.h>
#include <hip/hip_bf16.h>

#define BB 1024
#define NN 32
#define SUD 8
#define HD 64
#define NCD 4
#define ED 992      // NN*(NN-1)
#define NITER 5

// ---- fp32 weight workspace layout (element offsets into d_ws) ----
#define O_W2AT 0        // 18 x 64   W2aT[su][f] = W2a[f][su]
#define O_B2A  1152     // 64
#define O_W2B  1216     // 32 x 64
#define O_B2B  3264     // 32
#define O_W2CT 3296     // 32 x 8
#define O_B2C  3552     // 8
#define O_WIHT 3560     // 10 x 192  WihT[k][o]
#define O_BIH  5480     // 192
#define O_WHHT 5672     // 64 x 192  WhhT[k][o]
#define O_BHH  17960    // 192
#define O_W4T  18152    // 64 x 8    W4T[k][su]
#define O_B4   18664    // 8
#define O_W3AT 18672    // 8 x 64    W3aT[k][f]
#define O_B3A  19184    // 64
#define O_W3BT 19248    // 64 x 32   W3bT[k][f]
#define O_B3B  21296    // 32
#define O_W3CT 21328    // 32 x 4    W3cT[k][c]
#define O_B3C  21456    // 4
#define O_W1AT 21460    // 3 x 8     W1aT[c][su]
#define O_B1A  21484    // 8
#define W_TOTAL 21492   // floats

// ---- bf16 MFMA fragment region, at byte offset W_TOTAL*4 (bf16 element offsets) ----
#define FRAG_B2_HI  0        // 2048
#define FRAG_B2_LO  2048     // 2048
#define FRAG_C      4096     // 512
#define FRAG_WHH_HI 4608     // 12288 : ((nt*2+s)*64+L)*8+j = Whh[nt*16+(L&15)][s*32+((L>>4)&3)*8+j]
#define FRAG_WHH_LO 16896    // 12288
#define W_EXT (W_TOTAL + 2560 + 12288)   // prep thread count; ws needs 144,336 B

typedef const float* fwp;
typedef __attribute__((ext_vector_type(8))) short short8;
typedef __attribute__((ext_vector_type(4))) float float4v;

__device__ __forceinline__ short bf16r(float x) {
  __hip_bfloat16 h = __float2bfloat16(x);
  return __builtin_bit_cast(short, h);
}

__global__ void prep_weights(fwp W2a, fwp b2a, fwp W2b, fwp b2b, fwp W2c, fwp b2c,
                             fwp Wih, fwp bih, fwp Whh, fwp bhh,
                             fwp W3a, fwp b3a, fwp W3b, fwp b3b, fwp W3c, fwp b3c,
                             fwp W4, fwp b4, fwp W1a, fwp b1a, float* __restrict__ ws) {
  int idx = blockIdx.x * 256 + threadIdx.x;
  if (idx >= W_EXT) return;
  if (idx >= W_TOTAL) {
    __hip_bfloat16* wb = (__hip_bfloat16*)(ws + W_TOTAL);
    int e = idx - W_TOTAL;
    if (e < 2048) {
      int j = e & 7, L = (e >> 3) & 63, hs = e >> 9;
      int h = hs >> 1, s = hs & 1;
      float v = W2b[(h * 16 + (L & 15)) * 64 + s * 32 + ((L >> 4) & 3) * 8 + j];
      float hi = __bfloat162float(__float2bfloat16(v));
      wb[FRAG_B2_HI + e] = __float2bfloat16(v);
      wb[FRAG_B2_LO + e] = __float2bfloat16(v - hi);
    } else if (e < 2560) {
      int e2 = e - 2048;
      int j = e2 & 7, L = (e2 >> 3) & 63;
      int su = L & 15, q = L >> 4;
      float v = (su < 8) ? W2c[su * 32 + q * 8 + j] : 0.f;
      wb[FRAG_C + e2] = __float2bfloat16(v);
    } else {
      int e2 = e - 2560;                 // [0, 12288)
      int j = e2 & 7, L = (e2 >> 3) & 63, nts = e2 >> 9;
      int nt = nts >> 1, s = nts & 1;
      float v = Whh[(nt * 16 + (L & 15)) * 64 + s * 32 + ((L >> 4) & 3) * 8 + j];
      float hi = __bfloat162float(__float2bfloat16(v));
      wb[FRAG_WHH_HI + e2] = __float2bfloat16(v);
      wb[FRAG_WHH_LO + e2] = __float2bfloat16(v - hi);
    }
    return;
  }
  float v;
  if (idx < O_B2A)       { int p = idx;          int su = p / 64, f = p % 64;   v = W2a[f * 18 + su]; }
  else if (idx < O_W2B)  { v = b2a[idx - O_B2A]; }
  else if (idx < O_B2B)  { v = W2b[idx - O_W2B]; }
  else if (idx < O_W2CT) { v = b2b[idx - O_B2B]; }
  else if (idx < O_B2C)  { int p = idx - O_W2CT; int o = p / 8, su = p % 8;     v = W2c[su * 32 + o]; }
  else if (idx < O_WIHT) { v = b2c[idx - O_B2C]; }
  else if (idx < O_BIH)  { int p = idx - O_WIHT; int k = p / 192, o = p % 192;  v = Wih[o * 10 + k]; }
  else if (idx < O_WHHT) { v = bih[idx - O_BIH]; }
  else if (idx < O_BHH)  { int p = idx - O_WHHT; int k = p / 192, o = p % 192;  v = Whh[o * 64 + k]; }
  else if (idx < O_W4T)  { v = bhh[idx - O_BHH]; }
  else if (idx < O_B4)   { int p = idx - O_W4T;  int k = p / 8, su = p % 8;     v = W4[su * 64 + k]; }
  else if (idx < O_W3AT) { v = b4[idx - O_B4]; }
  else if (idx < O_B3A)  { int p = idx - O_W3AT; int k = p / 64, f = p % 64;    v = W3a[f * 8 + k]; }
  else if (idx < O_W3BT) { v = b3a[idx - O_B3A]; }
  else if (idx < O_B3B)  { int p = idx - O_W3BT; int k = p / 32, f = p % 32;    v = W3b[f * 64 + k]; }
  else if (idx < O_W3CT) { v = b3b[idx - O_B3B]; }
  else if (idx < O_B3C)  { int p = idx - O_W3CT; int k = p / 4, c = p % 4;      v = W3c[c * 32 + k]; }
  else if (idx < O_W1AT) { v = b3c[idx - O_B3C]; }
  else if (idx < O_B1A)  { int p = idx - O_W1AT; int c = p / 8, su = p % 8;     v = W1a[su * 3 + c]; }
  else                   { v = b1a[idx - O_B1A]; }
  ws[idx] = v;
}

// Layer-b K-step: activations single-bf16, weights hi/lo (4 MFMAs, alo dropped).
#define DO_STEP(KOFF, Y0, Y1, W0, W1, FH0, FL0, FH1, FL1)                      \
  {                                                                            \
    float4v x0 = *(const float4v*)&sA1[a * 68 + (KOFF)];                       \
    float4v x1 = *(const float4v*)&sA1[a * 68 + (KOFF) + 4];                   \
    float t0 = fmaxf(x0.x + Y0.x + ewv * W0.x, 0.f);                           \
    float t1 = fmaxf(x0.y + Y0.y + ewv * W0.y, 0.f);                           \
    float t2 = fmaxf(x0.z + Y0.z + ewv * W0.z, 0.f);                           \
    float t3 = fmaxf(x0.w + Y0.w + ewv * W0.w, 0.f);                           \
    float t4 = fmaxf(x1.x + Y1.x + ewv * W1.x, 0.f);                           \
    float t5 = fmaxf(x1.y + Y1.y + ewv * W1.y, 0.f);                           \
    float t6 = fmaxf(x1.z + Y1.z + ewv * W1.z, 0.f);                           \
    float t7 = fmaxf(x1.w + Y1.w + ewv * W1.w, 0.f);                           \
    short8 ahi;                                                                \
    ahi[0] = bf16r(t0); ahi[1] = bf16r(t1); ahi[2] = bf16r(t2);                \
    ahi[3] = bf16r(t3); ahi[4] = bf16r(t4); ahi[5] = bf16r(t5);                \
    ahi[6] = bf16r(t6); ahi[7] = bf16r(t7);                                    \
    accb0 = __builtin_amdgcn_mfma_f32_16x16x32_bf16(ahi, FH0, accb0, 0, 0, 0); \
    accb0 = __builtin_amdgcn_mfma_f32_16x16x32_bf16(ahi, FL0, accb0, 0, 0, 0); \
    accb1 = __builtin_amdgcn_mfma_f32_16x16x32_bf16(ahi, FH1, accb1, 0, 0, 0); \
    accb1 = __builtin_amdgcn_mfma_f32_16x16x32_bf16(ahi, FL1, accb1, 0, 0, 0); \
  }

// launch_bounds(256,1): full register file; (256,2) pinned arch-VGPRs at 128
// (AGPR split) and spilled ~40 regs/thread to scratch (R5-R8: WRITE~230MB).
__global__ __launch_bounds__(256, 1) void gnn_fused(
    const float* __restrict__ read_gru_in,
    const float* __restrict__ gru_init,
    const float* __restrict__ feat,
    const float* __restrict__ edge_w,
    const float* __restrict__ noise_in,
    const float* __restrict__ xhat,
    const float* __restrict__ vep,
    const int* __restrict__ gnn_iter_p,
    const float* __restrict__ ws,
    float* __restrict__ out)
{
  __shared__ __attribute__((aligned(16))) float sA1[NN * 68];
  __shared__ __attribute__((aligned(16))) float sA2[NN * 68];   // A2 + c1 (folded)
  __shared__ __attribute__((aligned(16))) float sH [NN * 68];
  __shared__ __attribute__((aligned(16))) float sGH[NN * 196];  // gh = H @ Whh^T (GEMM out)
  __shared__ __attribute__((aligned(16))) float sC1[64];
  __shared__ __attribute__((aligned(16))) float sWew[64];
  __shared__ __attribute__((aligned(16))) __hip_bfloat16 sM2[4 * 16 * 44];
  __shared__ __attribute__((aligned(16))) short sFrag[9 * 64 * 8];
  __shared__ float sNodes[NN * 9];
  __shared__ float sSum[NN * 8];
  __shared__ float sEw[ED];
  __shared__ float sX[NN];
  __shared__ float sV[NN];

  const int b = blockIdx.x;
  const int t = threadIdx.x;
  const int lane = t & 63;
  const int wv = t >> 6;
  const int quad = lane >> 4;
  const int lm = lane & 15;

  const __hip_bfloat16* wb = (const __hip_bfloat16*)(ws + W_TOTAL);

  // ---- stash edge-MLP B fragments into LDS ----
  if (t < 64) {
#pragma unroll
    for (int hs = 0; hs < 4; ++hs) {
      *(short8*)(sFrag + (hs * 64 + lane) * 8) =
          *(const short8*)(wb + FRAG_B2_HI + (hs * 64 + lane) * 8);
      *(short8*)(sFrag + ((4 + hs) * 64 + lane) * 8) =
          *(const short8*)(wb + FRAG_B2_LO + (hs * 64 + lane) * 8);
    }
    *(short8*)(sFrag + (8 * 64 + lane) * 8) = *(const short8*)(wb + FRAG_C + lane * 8);
  }

  // ---- per-sample inputs ----
  float noi = noise_in[b];
  for (int e = t; e < ED; e += 256) sEw[e] = edge_w[b * ED + e];
  if (t < NN) { sX[t] = xhat[b * NN + t]; sV[t] = vep[b * NN + t]; }
  if (t < 64) {
    sC1[t]  = ws[O_B2A + t] + noi * ws[O_W2AT + 17 * 64 + t];
    sWew[t] = ws[O_W2AT + 16 * 64 + t];
  }
#pragma unroll
  for (int i = 0; i < 8; ++i) {
    int p = t + 256 * i;
    sH[(p >> 6) * 68 + (p & 63)] = gru_init[b * (NN * HD) + p];
  }
  const int git = gnn_iter_p[0];

  for (int it = 0; it < NITER; ++it) {
    // ---- init_nodes ----
    if (it == 0) {
      int n = t >> 3, su = t & 7;
      float acc;
      if (git == 0) {
        acc = ws[O_B1A + su];
#pragma unroll
        for (int c = 0; c < 3; ++c)
          acc += ws[O_W1AT + c * 8 + su] * feat[b * (NN * 3) + n * 3 + c];
      } else {
        acc = read_gru_in[b * (NN * SUD) + t];
      }
      sNodes[n * 9 + su] = acc;
    }
    __syncthreads();

    // ---- A1/A2 node projections (c1 folded into A2) ----
#pragma unroll
    for (int i = 0; i < 8; ++i) {
      int p = t + 256 * i;
      int n = p >> 6, f = p & 63;
      float a1 = 0.f, a2 = 0.f;
#pragma unroll
      for (int su = 0; su < 8; ++su) {
        float nv = sNodes[n * 9 + su];
        a1 += ws[O_W2AT + su * 64 + f] * nv;
        a2 += ws[O_W2AT + (8 + su) * 64 + f] * nv;
      }
      sA1[n * 68 + f] = a1;
      sA2[n * 68 + f] = a2 + sC1[f];
    }
    __syncthreads();

    // ---- edge MLP via MFMA ----
    {
      short8 fbh00 = *(const short8*)(sFrag + (0 * 64 + lane) * 8);
      short8 fbh01 = *(const short8*)(sFrag + (1 * 64 + lane) * 8);
      short8 fbh10 = *(const short8*)(sFrag + (2 * 64 + lane) * 8);
      short8 fbh11 = *(const short8*)(sFrag + (3 * 64 + lane) * 8);
      short8 fbl00 = *(const short8*)(sFrag + (4 * 64 + lane) * 8);
      short8 fbl01 = *(const short8*)(sFrag + (5 * 64 + lane) * 8);
      short8 fbl10 = *(const short8*)(sFrag + (6 * 64 + lane) * 8);
      short8 fbl11 = *(const short8*)(sFrag + (7 * 64 + lane) * 8);
      short8 fcf   = *(const short8*)(sFrag + (8 * 64 + lane) * 8);
      const float b2b0 = ws[O_B2B + lm];
      const float b2b1 = ws[O_B2B + 16 + lm];
      const float b2cl = ws[O_B2C + lm];

      __hip_bfloat16* m2w = sM2 + wv * (16 * 44);
      const int kq0 = quad * 8, kq1 = 32 + quad * 8;
      float4v wwA = *(const float4v*)&sWew[kq0];
      float4v wwB = *(const float4v*)&sWew[kq0 + 4];
      float4v wwC = *(const float4v*)&sWew[kq1];
      float4v wwD = *(const float4v*)&sWew[kq1 + 4];
      for (int ni = 0; ni < 8; ++ni) {
        const int jj = wv * 8 + ni;
        float4v yA = *(const float4v*)&sA2[jj * 68 + kq0];
        float4v yB = *(const float4v*)&sA2[jj * 68 + kq0 + 4];
        float4v yC = *(const float4v*)&sA2[jj * 68 + kq1];
        float4v yD = *(const float4v*)&sA2[jj * 68 + kq1 + 4];
        float psum = 0.f;
#pragma unroll
        for (int tile = 0; tile < 2; ++tile) {
          int kk = tile * 16 + lm;
          int kk2 = (kk < 31) ? kk : 0;
          int a = kk2 + (kk2 >= jj ? 1 : 0);
          float ewv = (kk < 31) ? sEw[jj * 31 + kk] : 0.f;
          float4v accb0 = {0.f, 0.f, 0.f, 0.f};
          float4v accb1 = {0.f, 0.f, 0.f, 0.f};
          DO_STEP(kq0, yA, yB, wwA, wwB, fbh00, fbl00, fbh10, fbl10);
          DO_STEP(kq1, yC, yD, wwC, wwD, fbh01, fbl01, fbh11, fbl11);
#pragma unroll
          for (int r = 0; r < 4; ++r) {
            float m20 = fmaxf(accb0[r] + b2b0, 0.f);
            float m21 = fmaxf(accb1[r] + b2b1, 0.f);
            m2w[(quad * 4 + r) * 44 + lm]      = __float2bfloat16(m20);
            m2w[(quad * 4 + r) * 44 + 16 + lm] = __float2bfloat16(m21);
          }
          __asm__ __volatile__("" ::: "memory");
          short8 ac = *(const short8*)(m2w + lm * 44 + quad * 8);
          float4v c3 = {0.f, 0.f, 0.f, 0.f};
          c3 = __builtin_amdgcn_mfma_f32_16x16x32_bf16(ac, fcf, c3, 0, 0, 0);
#pragma unroll
          for (int r = 0; r < 4; ++r) {
            float v = fmaxf(c3[r] + b2cl, 0.f);
            if (tile == 1 && r == 3) v = (quad == 3) ? 0.f : v;
            psum += v;
          }
          __asm__ __volatile__("" ::: "memory");
        }
        psum += __shfl_xor(psum, 16);
        psum += __shfl_xor(psum, 32);
        if (lane < 8) sSum[jj * 8 + lane] = psum;
      }
    }
    __syncthreads();

    // ---- GRU part 1: GH = H @ Whh^T via MFMA (wave wv: N-tiles wv*3..wv*3+2) ----
    {
      short8 aH[2][2];
#pragma unroll
      for (int mt = 0; mt < 2; ++mt) {
#pragma unroll
        for (int s = 0; s < 2; ++s) {
          const float* hp = &sH[(mt * 16 + lm) * 68 + s * 32 + quad * 8];
          float4v h0 = *(const float4v*)hp;
          float4v h1 = *(const float4v*)(hp + 4);
          short8 a;
          a[0] = bf16r(h0.x); a[1] = bf16r(h0.y); a[2] = bf16r(h0.z); a[3] = bf16r(h0.w);
          a[4] = bf16r(h1.x); a[5] = bf16r(h1.y); a[6] = bf16r(h1.z); a[7] = bf16r(h1.w);
          aH[mt][s] = a;
        }
      }
#pragma unroll
      for (int nt = 0; nt < 3; ++nt) {
        int gnt = wv * 3 + nt;
        short8 bh0 = *(const short8*)(wb + FRAG_WHH_HI + ((gnt * 2 + 0) * 64 + lane) * 8);
        short8 bl0 = *(const short8*)(wb + FRAG_WHH_LO + ((gnt * 2 + 0) * 64 + lane) * 8);
        short8 bh1 = *(const short8*)(wb + FRAG_WHH_HI + ((gnt * 2 + 1) * 64 + lane) * 8);
        short8 bl1 = *(const short8*)(wb + FRAG_WHH_LO + ((gnt * 2 + 1) * 64 + lane) * 8);
#pragma unroll
        for (int mt = 0; mt < 2; ++mt) {
          float4v acc = {0.f, 0.f, 0.f, 0.f};
          acc = __builtin_amdgcn_mfma_f32_16x16x32_bf16(aH[mt][0], bh0, acc, 0, 0, 0);
          acc = __builtin_amdgcn_mfma_f32_16x16x32_bf16(aH[mt][0], bl0, acc, 0, 0, 0);
          acc = __builtin_amdgcn_mfma_f32_16x16x32_bf16(aH[mt][1], bh1, acc, 0, 0, 0);
          acc = __builtin_amdgcn_mfma_f32_16x16x32_bf16(aH[mt][1], bl1, acc, 0, 0, 0);
#pragma unroll
          for (int r = 0; r < 4; ++r)
            sGH[(mt * 16 + quad * 4 + r) * 196 + gnt * 16 + lm] = acc[r];
        }
      }
    }
    __syncthreads();

    // ---- GRU part 2: gi (K=10 VALU) + gates + h update ----
    {
      int oo = t & 63, wq = t >> 6;
      float ar[8], az[8], inx[8];
      {
        float br  = ws[O_BIH + oo]      + ws[O_BHH + oo];
        float bz  = ws[O_BIH + 64 + oo] + ws[O_BHH + 64 + oo];
        float bni = ws[O_BIH + 128 + oo];
#pragma unroll
        for (int j = 0; j < 8; ++j) { ar[j] = br; az[j] = bz; inx[j] = bni; }
      }
#pragma unroll
      for (int k = 0; k < 8; ++k) {
        float wr = ws[O_WIHT + k * 192 + oo];
        float wz = ws[O_WIHT + k * 192 + 64 + oo];
        float wn = ws[O_WIHT + k * 192 + 128 + oo];
#pragma unroll
        for (int j = 0; j < 8; ++j) {
          float g = sSum[(wq + 4 * j) * 8 + k];
          ar[j] += wr * g; az[j] += wz * g; inx[j] += wn * g;
        }
      }
      {
        float wr = ws[O_WIHT + 8 * 192 + oo];
        float wz = ws[O_WIHT + 8 * 192 + 64 + oo];
        float wn = ws[O_WIHT + 8 * 192 + 128 + oo];
#pragma unroll
        for (int j = 0; j < 8; ++j) {
          float g = sX[wq + 4 * j];
          ar[j] += wr * g; az[j] += wz * g; inx[j] += wn * g;
        }
        wr = ws[O_WIHT + 9 * 192 + oo];
        wz = ws[O_WIHT + 9 * 192 + 64 + oo];
        wn = ws[O_WIHT + 9 * 192 + 128 + oo];
#pragma unroll
        for (int j = 0; j < 8; ++j) {
          float g = sV[wq + 4 * j];
          ar[j] += wr * g; az[j] += wz * g; inx[j] += wn * g;
        }
      }
      float bnh = ws[O_BHH + 128 + oo];
#pragma unroll
      for (int j = 0; j < 8; ++j) {
        int n = wq + 4 * j;                 // rows wave-private; DS in-order per wave
        float ghr = sGH[n * 196 + oo];
        float ghz = sGH[n * 196 + 64 + oo];
        float ghn = sGH[n * 196 + 128 + oo] + bnh;
        float r = 1.f / (1.f + __expf(-(ar[j] + ghr)));
        float z = 1.f / (1.f + __expf(-(az[j] + ghz)));
        float cd = inx[j] + r * ghn;
        float e2 = __expf(2.f * cd);
        float th = 1.f - 2.f / (e2 + 1.f);
        sH[n * 68 + oo] = (1.f - z) * th + z * sH[n * 68 + oo];
      }
    }
    __syncthreads();

    // ---- read_gru = W4 @ h + b4 -> sNodes ----
    {
      int n = t >> 3, su = t & 7;
      float c0 = 0.f, c1v = 0.f, c2 = 0.f, c3v = 0.f;
#pragma unroll
      for (int k = 0; k < 64; k += 4) {
        c0  += ws[O_W4T + (k + 0) * 8 + su] * sH[n * 68 + k + 0];
        c1v += ws[O_W4T + (k + 1) * 8 + su] * sH[n * 68 + k + 1];
        c2  += ws[O_W4T + (k + 2) * 8 + su] * sH[n * 68 + k + 2];
        c3v += ws[O_W4T + (k + 3) * 8 + su] * sH[n * 68 + k + 3];
      }
      sNodes[n * 9 + su] = ws[O_B4 + su] + ((c0 + c1v) + (c2 + c3v));
    }
    __syncthreads();
  } // iterations

  // ---- head ----
#pragma unroll
  for (int i = 0; i < 8; ++i) {
    int p = t + 256 * i;
    int n = p >> 6, f = p & 63;
    float acc = ws[O_B3A + f];
#pragma unroll
    for (int k = 0; k < 8; ++k) acc += ws[O_W3AT + k * 64 + f] * sNodes[n * 9 + k];
    sA1[n * 68 + f] = acc;
  }
  __syncthreads();
#pragma unroll
  for (int i = 0; i < 4; ++i) {
    int p = t + 256 * i;
    int n = p >> 5, f = p & 31;
    float c0 = 0.f, c1v = 0.f, c2 = 0.f, c3v = 0.f;
#pragma unroll
    for (int k = 0; k < 64; k += 4) {
      c0  += ws[O_W3BT + (k + 0) * 32 + f] * sA1[n * 68 + k + 0];
      c1v += ws[O_W3BT + (k + 1) * 32 + f] * sA1[n * 68 + k + 1];
      c2  += ws[O_W3BT + (k + 2) * 32 + f] * sA1[n * 68 + k + 2];
      c3v += ws[O_W3BT + (k + 3) * 32 + f] * sA1[n * 68 + k + 3];
    }
    sA2[n * 33 + f] = ws[O_B3B + f] + ((c0 + c1v) + (c2 + c3v));
  }
  __syncthreads();
  if (t < 128) {
    int n = t >> 2, c = t & 3;
    float acc = ws[O_B3C + c];
#pragma unroll
    for (int k = 0; k < 32; ++k) acc += ws[O_W3CT + k * 4 + c] * sA2[n * 33 + k];
    out[b * (NN * NCD) + t] = acc;
  }
  out[BB * NN * NCD + b * (NN * SUD) + t] = sNodes[(t >> 3) * 9 + (t & 7)];
#pragma unroll
  for (int i = 0; i < 8; ++i) {
    int p = t + 256 * i;
    out[BB * NN * NCD + BB * NN * SUD + b * (NN * HD) + p] =
        sH[(p >> 6) * 68 + (p & 63)];
  }
}

extern "C" void kernel_launch(void* const* d_in, const int* in_sizes, int n_in,
                              void* d_out, int out_size, void* d_ws, size_t ws_size,
                              hipStream_t stream) {
  typedef const float* F32;
  F32 read_gru = (F32)d_in[0];
  F32 gru_init = (F32)d_in[1];
  F32 feat     = (F32)d_in[2];
  F32 edge_w   = (F32)d_in[3];
  F32 noise    = (F32)d_in[4];
  F32 xh       = (F32)d_in[5];
  F32 vp       = (F32)d_in[6];
  F32 W1a = (F32)d_in[7];  F32 b1a = (F32)d_in[8];
  F32 W2a = (F32)d_in[9];  F32 b2a = (F32)d_in[10];
  F32 W2b = (F32)d_in[11]; F32 b2b = (F32)d_in[12];
  F32 W2c = (F32)d_in[13]; F32 b2c = (F32)d_in[14];
  F32 Wih = (F32)d_in[15]; F32 bih = (F32)d_in[16];
  F32 Whh = (F32)d_in[17]; F32 bhh = (F32)d_in[18];
  F32 W3a = (F32)d_in[19]; F32 b3a = (F32)d_in[20];
  F32 W3b = (F32)d_in[21]; F32 b3b = (F32)d_in[22];
  F32 W3c = (F32)d_in[23]; F32 b3c = (F32)d_in[24];
  F32 W4  = (F32)d_in[25]; F32 b4  = (F32)d_in[26];
  const int* git = (const int*)d_in[27];
  float* ws = (float*)d_ws;   // needs 144,336 B

  prep_weights<<<(W_EXT + 255) / 256, 256, 0, stream>>>(
      W2a, b2a, W2b, b2b, W2c, b2c, Wih, bih, Whh, bhh,
      W3a, b3a, W3b, b3b, W3c, b3c, W4, b4, W1a, b1a, ws);

  gnn_fused<<<BB, 256, 0, stream>>>(read_gru, gru_init, feat, edge_w, noise,
                                    xh, vp, git, ws, (float*)d_out);
}

// Round 11
// 313.113 us; speedup vs baseline: 2.9506x; 1.5163x over previous
//
#include <hip/hip_runtime.h>
#include <hip/hip_bf16.h>

#define BB 1024
#define NN 32
#define SUD 8
#define HD 64
#define NCD 4
#define ED 992      // NN*(NN-1)
#define NITER 5

// ---- fp32 weight workspace layout (element offsets into d_ws) ----
#define O_W2AT 0        // 18 x 64   W2aT[su][f] = W2a[f][su]
#define O_B2A  1152     // 64
#define O_W2B  1216     // 32 x 64
#define O_B2B  3264     // 32
#define O_W2CT 3296     // 32 x 8
#define O_B2C  3552     // 8
#define O_WIHT 3560     // 10 x 192  WihT[k][o]
#define O_BIH  5480     // 192
#define O_WHHT 5672     // 64 x 192  WhhT[k][o]
#define O_BHH  17960    // 192
#define O_W4T  18152    // 64 x 8    W4T[k][su]
#define O_B4   18664    // 8
#define O_W3AT 18672    // 8 x 64    W3aT[k][f]
#define O_B3A  19184    // 64
#define O_W3BT 19248    // 64 x 32   W3bT[k][f]
#define O_B3B  21296    // 32
#define O_W3CT 21328    // 32 x 4    W3cT[k][c]
#define O_B3C  21456    // 4
#define O_W1AT 21460    // 3 x 8     W1aT[c][su]
#define O_B1A  21484    // 8
#define W_TOTAL 21492   // floats

// ---- bf16 MFMA fragment region, at byte offset W_TOTAL*4 (bf16 element offsets) ----
#define FRAG_B2_HI  0        // 2048
#define FRAG_B2_LO  2048     // 2048
#define FRAG_C      4096     // 512
#define FRAG_WHH_HI 4608     // 12288 : ((nt*2+s)*64+L)*8+j = Whh[nt*16+(L&15)][s*32+((L>>4)&3)*8+j]
#define FRAG_WHH_LO 16896    // 12288
#define W_EXT (W_TOTAL + 2560 + 12288)   // ws needs 144,336 B

#define GHS 212   // sGH fp32 stride (2-way max bank aliasing on write/read)

typedef const float* fwp;
typedef __attribute__((ext_vector_type(8))) short short8;
typedef __attribute__((ext_vector_type(4))) float float4v;

__device__ __forceinline__ short bf16r(float x) {
  __hip_bfloat16 h = __float2bfloat16(x);
  return __builtin_bit_cast(short, h);
}

__global__ void prep_weights(fwp W2a, fwp b2a, fwp W2b, fwp b2b, fwp W2c, fwp b2c,
                             fwp Wih, fwp bih, fwp Whh, fwp bhh,
                             fwp W3a, fwp b3a, fwp W3b, fwp b3b, fwp W3c, fwp b3c,
                             fwp W4, fwp b4, fwp W1a, fwp b1a, float* __restrict__ ws) {
  int idx = blockIdx.x * 256 + threadIdx.x;
  if (idx >= W_EXT) return;
  if (idx >= W_TOTAL) {
    __hip_bfloat16* wb = (__hip_bfloat16*)(ws + W_TOTAL);
    int e = idx - W_TOTAL;
    if (e < 2048) {
      int j = e & 7, L = (e >> 3) & 63, hs = e >> 9;
      int h = hs >> 1, s = hs & 1;
      float v = W2b[(h * 16 + (L & 15)) * 64 + s * 32 + ((L >> 4) & 3) * 8 + j];
      float hi = __bfloat162float(__float2bfloat16(v));
      wb[FRAG_B2_HI + e] = __float2bfloat16(v);
      wb[FRAG_B2_LO + e] = __float2bfloat16(v - hi);
    } else if (e < 2560) {
      int e2 = e - 2048;
      int j = e2 & 7, L = (e2 >> 3) & 63;
      int su = L & 15, q = L >> 4;
      float v = (su < 8) ? W2c[su * 32 + q * 8 + j] : 0.f;
      wb[FRAG_C + e2] = __float2bfloat16(v);
    } else {
      int e2 = e - 2560;                 // [0, 12288)
      int j = e2 & 7, L = (e2 >> 3) & 63, nts = e2 >> 9;
      int nt = nts >> 1, s = nts & 1;
      float v = Whh[(nt * 16 + (L & 15)) * 64 + s * 32 + ((L >> 4) & 3) * 8 + j];
      float hi = __bfloat162float(__float2bfloat16(v));
      wb[FRAG_WHH_HI + e2] = __float2bfloat16(v);
      wb[FRAG_WHH_LO + e2] = __float2bfloat16(v - hi);
    }
    return;
  }
  float v;
  if (idx < O_B2A)       { int p = idx;          int su = p / 64, f = p % 64;   v = W2a[f * 18 + su]; }
  else if (idx < O_W2B)  { v = b2a[idx - O_B2A]; }
  else if (idx < O_B2B)  { v = W2b[idx - O_W2B]; }
  else if (idx < O_W2CT) { v = b2b[idx - O_B2B]; }
  else if (idx < O_B2C)  { int p = idx - O_W2CT; int o = p / 8, su = p % 8;     v = W2c[su * 32 + o]; }
  else if (idx < O_WIHT) { v = b2c[idx - O_B2C]; }
  else if (idx < O_BIH)  { int p = idx - O_WIHT; int k = p / 192, o = p % 192;  v = Wih[o * 10 + k]; }
  else if (idx < O_WHHT) { v = bih[idx - O_BIH]; }
  else if (idx < O_BHH)  { int p = idx - O_WHHT; int k = p / 192, o = p % 192;  v = Whh[o * 64 + k]; }
  else if (idx < O_W4T)  { v = bhh[idx - O_BHH]; }
  else if (idx < O_B4)   { int p = idx - O_W4T;  int k = p / 8, su = p % 8;     v = W4[su * 64 + k]; }
  else if (idx < O_W3AT) { v = b4[idx - O_B4]; }
  else if (idx < O_B3A)  { int p = idx - O_W3AT; int k = p / 64, f = p % 64;    v = W3a[f * 8 + k]; }
  else if (idx < O_W3BT) { v = b3a[idx - O_B3A]; }
  else if (idx < O_B3B)  { int p = idx - O_W3BT; int k = p / 32, f = p % 32;    v = W3b[f * 64 + k]; }
  else if (idx < O_W3CT) { v = b3b[idx - O_B3B]; }
  else if (idx < O_B3C)  { int p = idx - O_W3CT; int k = p / 4, c = p % 4;      v = W3c[c * 32 + k]; }
  else if (idx < O_W1AT) { v = b3c[idx - O_B3C]; }
  else if (idx < O_B1A)  { int p = idx - O_W1AT; int c = p / 8, su = p % 8;     v = W1a[su * 3 + c]; }
  else                   { v = b1a[idx - O_B1A]; }
  ws[idx] = v;
}

// Layer-b K-step: activations single-bf16, weights hi/lo (4 MFMAs).
#define DO_STEP(KOFF, Y0, Y1, W0, W1, FH0, FL0, FH1, FL1)                      \
  {                                                                            \
    float4v x0 = *(const float4v*)&sA1[a * 68 + (KOFF)];                       \
    float4v x1 = *(const float4v*)&sA1[a * 68 + (KOFF) + 4];                   \
    float t0 = fmaxf(x0.x + Y0.x + ewv * W0.x, 0.f);                           \
    float t1 = fmaxf(x0.y + Y0.y + ewv * W0.y, 0.f);                           \
    float t2 = fmaxf(x0.z + Y0.z + ewv * W0.z, 0.f);                           \
    float t3 = fmaxf(x0.w + Y0.w + ewv * W0.w, 0.f);                           \
    float t4 = fmaxf(x1.x + Y1.x + ewv * W1.x, 0.f);                           \
    float t5 = fmaxf(x1.y + Y1.y + ewv * W1.y, 0.f);                           \
    float t6 = fmaxf(x1.z + Y1.z + ewv * W1.z, 0.f);                           \
    float t7 = fmaxf(x1.w + Y1.w + ewv * W1.w, 0.f);                           \
    short8 ahi;                                                                \
    ahi[0] = bf16r(t0); ahi[1] = bf16r(t1); ahi[2] = bf16r(t2);                \
    ahi[3] = bf16r(t3); ahi[4] = bf16r(t4); ahi[5] = bf16r(t5);                \
    ahi[6] = bf16r(t6); ahi[7] = bf16r(t7);                                    \
    accb0 = __builtin_amdgcn_mfma_f32_16x16x32_bf16(ahi, FH0, accb0, 0, 0, 0); \
    accb0 = __builtin_amdgcn_mfma_f32_16x16x32_bf16(ahi, FL0, accb0, 0, 0, 0); \
    accb1 = __builtin_amdgcn_mfma_f32_16x16x32_bf16(ahi, FH1, accb1, 0, 0, 0); \
    accb1 = __builtin_amdgcn_mfma_f32_16x16x32_bf16(ahi, FL1, accb1, 0, 0, 0); \
  }

#define LAUNDER(v) __asm__ __volatile__("" : "+v"(v))

__global__ __launch_bounds__(256, 1) void gnn_fused(
    const float* __restrict__ read_gru_in,
    const float* __restrict__ gru_init,
    const float* __restrict__ feat,
    const float* __restrict__ edge_w,
    const float* __restrict__ noise_in,
    const float* __restrict__ xhat,
    const float* __restrict__ vep,
    const int* __restrict__ gnn_iter_p,
    const float* __restrict__ ws,
    float* __restrict__ out)
{
  // Overlay pool: edge-phase {sA1, sA2, sM2} aliases GRU-phase sGH (fp32 32x212).
  __shared__ __attribute__((aligned(16))) char spool[NN * GHS * 4];  // 27136 B
  __shared__ __attribute__((aligned(16))) float sH[NN * 68];
  __shared__ __attribute__((aligned(16))) short sFrag[9 * 64 * 8];
  __shared__ float sNodes[NN * 9];
  __shared__ float sSum[NN * 8];
  __shared__ float sEw[ED];
  __shared__ float sC1[64];
  __shared__ float sWew[64];
  __shared__ float sX[NN];
  __shared__ float sV[NN];

  float* const sA1 = (float*)spool;                          // 8704 B
  float* const sA2 = (float*)(spool + 8704);                 // 8704 B
  __hip_bfloat16* const sM2 = (__hip_bfloat16*)(spool + 17408); // 5632 B
  float* const sGH = (float*)spool;                          // 27136 B (aliases all three)

  const int b = blockIdx.x;
  const int t = threadIdx.x;
  const int lane = t & 63;
  const int wv = t >> 6;
  const int quad = lane >> 4;
  const int lm = lane & 15;

  const __hip_bfloat16* wb = (const __hip_bfloat16*)(ws + W_TOTAL);

  // ---- stash edge-MLP B fragments into LDS ----
  if (t < 64) {
#pragma unroll
    for (int hs = 0; hs < 4; ++hs) {
      *(short8*)(sFrag + (hs * 64 + lane) * 8) =
          *(const short8*)(wb + FRAG_B2_HI + (hs * 64 + lane) * 8);
      *(short8*)(sFrag + ((4 + hs) * 64 + lane) * 8) =
          *(const short8*)(wb + FRAG_B2_LO + (hs * 64 + lane) * 8);
    }
    *(short8*)(sFrag + (8 * 64 + lane) * 8) = *(const short8*)(wb + FRAG_C + lane * 8);
  }

  // ---- per-sample inputs ----
  float noi = noise_in[b];
  for (int e = t; e < ED; e += 256) sEw[e] = edge_w[b * ED + e];
  if (t < NN) { sX[t] = xhat[b * NN + t]; sV[t] = vep[b * NN + t]; }
  if (t < 64) {
    sC1[t]  = ws[O_B2A + t] + noi * ws[O_W2AT + 17 * 64 + t];
    sWew[t] = ws[O_W2AT + 16 * 64 + t];
  }
#pragma unroll
  for (int i = 0; i < 8; ++i) {
    int p = t + 256 * i;
    sH[(p >> 6) * 68 + (p & 63)] = gru_init[b * (NN * HD) + p];
  }
  // ---- init_nodes (iteration 0 only; later iters use W4 output) ----
  {
    const int git = gnn_iter_p[0];
    int n = t >> 3, su = t & 7;
    float acc;
    if (git == 0) {
      acc = ws[O_B1A + su];
#pragma unroll
      for (int c = 0; c < 3; ++c)
        acc += ws[O_W1AT + c * 8 + su] * feat[b * (NN * 3) + n * 3 + c];
    } else {
      acc = read_gru_in[b * (NN * SUD) + t];
    }
    sNodes[n * 9 + su] = acc;
  }
  __syncthreads();

  for (int it = 0; it < NITER; ++it) {
    // ---- A1/A2 node projections (c1 folded into A2); laundered invariants ----
    {
      int iva = 0; LAUNDER(iva);
      const float* wsl = ws + iva;
#pragma unroll
      for (int i = 0; i < 8; ++i) {
        int p = t + 256 * i;
        int n = p >> 6, f = p & 63;
        float a1 = 0.f, a2 = 0.f;
#pragma unroll
        for (int su = 0; su < 8; ++su) {
          float nv = sNodes[n * 9 + su];
          a1 += wsl[O_W2AT + su * 64 + f] * nv;
          a2 += wsl[O_W2AT + (8 + su) * 64 + f] * nv;
        }
        sA1[n * 68 + f] = a1;
        sA2[n * 68 + f] = a2 + sC1[iva + f];
      }
    }
    __syncthreads();

    // ---- edge MLP via MFMA; phase-local (laundered) frags/weights ----
    {
      int ive = 0; LAUNDER(ive);
      const float* wsl = ws + ive;
      const short* sFragL = sFrag + ive;
      short8 fbh00 = *(const short8*)(sFragL + (0 * 64 + lane) * 8);
      short8 fbh01 = *(const short8*)(sFragL + (1 * 64 + lane) * 8);
      short8 fbh10 = *(const short8*)(sFragL + (2 * 64 + lane) * 8);
      short8 fbh11 = *(const short8*)(sFragL + (3 * 64 + lane) * 8);
      short8 fbl00 = *(const short8*)(sFragL + (4 * 64 + lane) * 8);
      short8 fbl01 = *(const short8*)(sFragL + (5 * 64 + lane) * 8);
      short8 fbl10 = *(const short8*)(sFragL + (6 * 64 + lane) * 8);
      short8 fbl11 = *(const short8*)(sFragL + (7 * 64 + lane) * 8);
      short8 fcf   = *(const short8*)(sFragL + (8 * 64 + lane) * 8);
      const float b2b0 = wsl[O_B2B + lm];
      const float b2b1 = wsl[O_B2B + 16 + lm];
      const float b2cl = wsl[O_B2C + lm];

      __hip_bfloat16* m2w = sM2 + wv * (16 * 44);
      const int kq0 = quad * 8, kq1 = 32 + quad * 8;
      float4v wwA = *(const float4v*)&sWew[ive + kq0];
      float4v wwB = *(const float4v*)&sWew[ive + kq0 + 4];
      float4v wwC = *(const float4v*)&sWew[ive + kq1];
      float4v wwD = *(const float4v*)&sWew[ive + kq1 + 4];
      for (int ni = 0; ni < 8; ++ni) {
        const int jj = wv * 8 + ni;
        float4v yA = *(const float4v*)&sA2[jj * 68 + kq0];
        float4v yB = *(const float4v*)&sA2[jj * 68 + kq0 + 4];
        float4v yC = *(const float4v*)&sA2[jj * 68 + kq1];
        float4v yD = *(const float4v*)&sA2[jj * 68 + kq1 + 4];
        float psum = 0.f;
#pragma unroll
        for (int tile = 0; tile < 2; ++tile) {
          int kk = tile * 16 + lm;
          int kk2 = (kk < 31) ? kk : 0;
          int a = kk2 + (kk2 >= jj ? 1 : 0);
          float ewv = (kk < 31) ? sEw[ive + jj * 31 + kk] : 0.f;
          float4v accb0 = {0.f, 0.f, 0.f, 0.f};
          float4v accb1 = {0.f, 0.f, 0.f, 0.f};
          DO_STEP(kq0, yA, yB, wwA, wwB, fbh00, fbl00, fbh10, fbl10);
          DO_STEP(kq1, yC, yD, wwC, wwD, fbh01, fbl01, fbh11, fbl11);
#pragma unroll
          for (int r = 0; r < 4; ++r) {
            float m20 = fmaxf(accb0[r] + b2b0, 0.f);
            float m21 = fmaxf(accb1[r] + b2b1, 0.f);
            m2w[(quad * 4 + r) * 44 + lm]      = __float2bfloat16(m20);
            m2w[(quad * 4 + r) * 44 + 16 + lm] = __float2bfloat16(m21);
          }
          __asm__ __volatile__("" ::: "memory");
          short8 ac = *(const short8*)(m2w + lm * 44 + quad * 8);
          float4v c3 = {0.f, 0.f, 0.f, 0.f};
          c3 = __builtin_amdgcn_mfma_f32_16x16x32_bf16(ac, fcf, c3, 0, 0, 0);
#pragma unroll
          for (int r = 0; r < 4; ++r) {
            float v = fmaxf(c3[r] + b2cl, 0.f);
            if (tile == 1 && r == 3) v = (quad == 3) ? 0.f : v;
            psum += v;
          }
          __asm__ __volatile__("" ::: "memory");
        }
        psum += __shfl_xor(psum, 16);
        psum += __shfl_xor(psum, 32);
        if (lane < 8) sSum[jj * 8 + lane] = psum;
      }
    }
    __syncthreads();

    // ---- GRU part 1: GH = H @ Whh^T via MFMA. Wave wv owns N-tiles {wv,4+wv,8+wv}
    //      so GRU part 2 (cols wv*16+lm) reads only this wave's output: no barrier,
    //      just a wave-local compiler fence (DS is in-order per wave). ----
    {
      int ivg = 0; LAUNDER(ivg);
      const __hip_bfloat16* wbl = wb + ivg;
      short8 aH[2][2];
#pragma unroll
      for (int mt = 0; mt < 2; ++mt) {
#pragma unroll
        for (int s = 0; s < 2; ++s) {
          const float* hp = &sH[(mt * 16 + lm) * 68 + s * 32 + quad * 8];
          float4v h0 = *(const float4v*)hp;
          float4v h1 = *(const float4v*)(hp + 4);
          short8 a;
          a[0] = bf16r(h0.x); a[1] = bf16r(h0.y); a[2] = bf16r(h0.z); a[3] = bf16r(h0.w);
          a[4] = bf16r(h1.x); a[5] = bf16r(h1.y); a[6] = bf16r(h1.z); a[7] = bf16r(h1.w);
          aH[mt][s] = a;
        }
      }
#pragma unroll
      for (int nt = 0; nt < 3; ++nt) {
        int gnt = 4 * nt + wv;
        short8 bh0 = *(const short8*)(wbl + FRAG_WHH_HI + ((gnt * 2 + 0) * 64 + lane) * 8);
        short8 bl0 = *(const short8*)(wbl + FRAG_WHH_LO + ((gnt * 2 + 0) * 64 + lane) * 8);
        short8 bh1 = *(const short8*)(wbl + FRAG_WHH_HI + ((gnt * 2 + 1) * 64 + lane) * 8);
        short8 bl1 = *(const short8*)(wbl + FRAG_WHH_LO + ((gnt * 2 + 1) * 64 + lane) * 8);
#pragma unroll
        for (int mt = 0; mt < 2; ++mt) {
          float4v acc = {0.f, 0.f, 0.f, 0.f};
          acc = __builtin_amdgcn_mfma_f32_16x16x32_bf16(aH[mt][0], bh0, acc, 0, 0, 0);
          acc = __builtin_amdgcn_mfma_f32_16x16x32_bf16(aH[mt][0], bl0, acc, 0, 0, 0);
          acc = __builtin_amdgcn_mfma_f32_16x16x32_bf16(aH[mt][1], bh1, acc, 0, 0, 0);
          acc = __builtin_amdgcn_mfma_f32_16x16x32_bf16(aH[mt][1], bl1, acc, 0, 0, 0);
#pragma unroll
          for (int r = 0; r < 4; ++r)
            sGH[(mt * 16 + quad * 4 + r) * GHS + gnt * 16 + lm] = acc[r];
        }
      }
    }
    __asm__ __volatile__("" ::: "memory");   // order GH writes before same-wave reads

    // ---- GRU part 2: gates; wave-private cols c = wv*16+lm2; hnew staged in regs ----
    {
      int ivq = 0; LAUNDER(ivq);
      const float* wsl = ws + ivq;
      int lm2 = lane & 15, g = lane >> 4;
      int c = wv * 16 + lm2;
      float ar[8], az[8], inx[8];
      {
        float br  = wsl[O_BIH + c]       + wsl[O_BHH + c];
        float bz  = wsl[O_BIH + 64 + c]  + wsl[O_BHH + 64 + c];
        float bni = wsl[O_BIH + 128 + c];
#pragma unroll
        for (int j = 0; j < 8; ++j) { ar[j] = br; az[j] = bz; inx[j] = bni; }
      }
#pragma unroll
      for (int k = 0; k < 8; ++k) {
        float wr = wsl[O_WIHT + k * 192 + c];
        float wz = wsl[O_WIHT + k * 192 + 64 + c];
        float wn = wsl[O_WIHT + k * 192 + 128 + c];
#pragma unroll
        for (int j = 0; j < 8; ++j) {
          float gg = sSum[(g + 4 * j) * 8 + k];
          ar[j] += wr * gg; az[j] += wz * gg; inx[j] += wn * gg;
        }
      }
      {
        float wr = wsl[O_WIHT + 8 * 192 + c];
        float wz = wsl[O_WIHT + 8 * 192 + 64 + c];
        float wn = wsl[O_WIHT + 8 * 192 + 128 + c];
#pragma unroll
        for (int j = 0; j < 8; ++j) {
          float gg = sX[ivq + g + 4 * j];
          ar[j] += wr * gg; az[j] += wz * gg; inx[j] += wn * gg;
        }
        wr = wsl[O_WIHT + 9 * 192 + c];
        wz = wsl[O_WIHT + 9 * 192 + 64 + c];
        wn = wsl[O_WIHT + 9 * 192 + 128 + c];
#pragma unroll
        for (int j = 0; j < 8; ++j) {
          float gg = sV[ivq + g + 4 * j];
          ar[j] += wr * gg; az[j] += wz * gg; inx[j] += wn * gg;
        }
      }
      float bnh = wsl[O_BHH + 128 + c];
      float hnew[8];
#pragma unroll
      for (int j = 0; j < 8; ++j) {
        int n = g + 4 * j;
        float ghr = sGH[n * GHS + c];
        float ghz = sGH[n * GHS + 64 + c];
        float ghn = sGH[n * GHS + 128 + c] + bnh;
        float r = 1.f / (1.f + __expf(-(ar[j] + ghr)));
        float z = 1.f / (1.f + __expf(-(az[j] + ghz)));
        float cd = inx[j] + r * ghn;
        float e2 = __expf(2.f * cd);
        float th = 1.f - 2.f / (e2 + 1.f);
        hnew[j] = (1.f - z) * th + z * sH[n * 68 + c];
      }
      __syncthreads();   // other waves' GRU1 reads of all sH cols complete
#pragma unroll
      for (int j = 0; j < 8; ++j) sH[(g + 4 * j) * 68 + c] = hnew[j];
    }
    __syncthreads();

    // ---- read_gru = W4 @ h + b4 -> sNodes ----
    {
      int ivw = 0; LAUNDER(ivw);
      const float* wsl = ws + ivw;
      int n = t >> 3, su = t & 7;
      float c0 = 0.f, c1v = 0.f, c2 = 0.f, c3v = 0.f;
#pragma unroll
      for (int k = 0; k < 64; k += 4) {
        c0  += wsl[O_W4T + (k + 0) * 8 + su] * sH[n * 68 + k + 0];
        c1v += wsl[O_W4T + (k + 1) * 8 + su] * sH[n * 68 + k + 1];
        c2  += wsl[O_W4T + (k + 2) * 8 + su] * sH[n * 68 + k + 2];
        c3v += wsl[O_W4T + (k + 3) * 8 + su] * sH[n * 68 + k + 3];
      }
      sNodes[n * 9 + su] = wsl[O_B4 + su] + ((c0 + c1v) + (c2 + c3v));
    }
    __syncthreads();
  } // iterations

  // ---- head ----
#pragma unroll
  for (int i = 0; i < 8; ++i) {
    int p = t + 256 * i;
    int n = p >> 6, f = p & 63;
    float acc = ws[O_B3A + f];
#pragma unroll
    for (int k = 0; k < 8; ++k) acc += ws[O_W3AT + k * 64 + f] * sNodes[n * 9 + k];
    sA1[n * 68 + f] = acc;
  }
  __syncthreads();
#pragma unroll
  for (int i = 0; i < 4; ++i) {
    int p = t + 256 * i;
    int n = p >> 5, f = p & 31;
    float c0 = 0.f, c1v = 0.f, c2 = 0.f, c3v = 0.f;
#pragma unroll
    for (int k = 0; k < 64; k += 4) {
      c0  += ws[O_W3BT + (k + 0) * 32 + f] * sA1[n * 68 + k + 0];
      c1v += ws[O_W3BT + (k + 1) * 32 + f] * sA1[n * 68 + k + 1];
      c2  += ws[O_W3BT + (k + 2) * 32 + f] * sA1[n * 68 + k + 2];
      c3v += ws[O_W3BT + (k + 3) * 32 + f] * sA1[n * 68 + k + 3];
    }
    sA2[n * 33 + f] = ws[O_B3B + f] + ((c0 + c1v) + (c2 + c3v));
  }
  __syncthreads();
  if (t < 128) {
    int n = t >> 2, c = t & 3;
    float acc = ws[O_B3C + c];
#pragma unroll
    for (int k = 0; k < 32; ++k) acc += ws[O_W3CT + k * 4 + c] * sA2[n * 33 + k];
    out[b * (NN * NCD) + t] = acc;
  }
  out[BB * NN * NCD + b * (NN * SUD) + t] = sNodes[(t >> 3) * 9 + (t & 7)];
#pragma unroll
  for (int i = 0; i < 8; ++i) {
    int p = t + 256 * i;
    out[BB * NN * NCD + BB * NN * SUD + b * (NN * HD) + p] =
        sH[(p >> 6) * 68 + (p & 63)];
  }
}

extern "C" void kernel_launch(void* const* d_in, const int* in_sizes, int n_in,
                              void* d_out, int out_size, void* d_ws, size_t ws_size,
                              hipStream_t stream) {
  typedef const float* F32;
  F32 read_gru = (F32)d_in[0];
  F32 gru_init = (F32)d_in[1];
  F32 feat     = (F32)d_in[2];
  F32 edge_w   = (F32)d_in[3];
  F32 noise    = (F32)d_in[4];
  F32 xh       = (F32)d_in[5];
  F32 vp       = (F32)d_in[6];
  F32 W1a = (F32)d_in[7];  F32 b1a = (F32)d_in[8];
  F32 W2a = (F32)d_in[9];  F32 b2a = (F32)d_in[10];
  F32 W2b = (F32)d_in[11]; F32 b2b = (F32)d_in[12];
  F32 W2c = (F32)d_in[13]; F32 b2c = (F32)d_in[14];
  F32 Wih = (F32)d_in[15]; F32 bih = (F32)d_in[16];
  F32 Whh = (F32)d_in[17]; F32 bhh = (F32)d_in[18];
  F32 W3a = (F32)d_in[19]; F32 b3a = (F32)d_in[20];
  F32 W3b = (F32)d_in[21]; F32 b3b = (F32)d_in[22];
  F32 W3c = (F32)d_in[23]; F32 b3c = (F32)d_in[24];
  F32 W4  = (F32)d_in[25]; F32 b4  = (F32)d_in[26];
  const int* git = (const int*)d_in[27];
  float* ws = (float*)d_ws;   // needs 144,336 B

  prep_weights<<<(W_EXT + 255) / 256, 256, 0, stream>>>(
      W2a, b2a, W2b, b2b, W2c, b2c, Wih, bih, Whh, bhh,
      W3a, b3a, W3b, b3b, W3c, b3c, W4, b4, W1a, b1a, ws);

  gnn_fused<<<BB, 256, 0, stream>>>(read_gru, gru_init, feat, edge_w, noise,
                                    xh, vp, git, ws, (float*)d_out);
}

// Round 13
// 310.866 us; speedup vs baseline: 2.9720x; 1.0072x over previous
//
#include <hip/hip_runtime.h>
#include <hip/hip_bf16.h>

#define BB 1024
#define NN 32
#define SUD 8
#define HD 64
#define NCD 4
#define ED 992      // NN*(NN-1)
#define NITER 5

// ---- fp32 weight workspace layout (element offsets into d_ws) ----
#define O_W2AT 0        // 18 x 64   W2aT[su][f] = W2a[f][su]
#define O_B2A  1152     // 64
#define O_W2B  1216     // 32 x 64
#define O_B2B  3264     // 32
#define O_W2CT 3296     // 32 x 8
#define O_B2C  3552     // 8
#define O_WIHT 3560     // 10 x 192  WihT[k][o]
#define O_BIH  5480     // 192
#define O_WHHT 5672     // 64 x 192  WhhT[k][o]
#define O_BHH  17960    // 192
#define O_W4T  18152    // 64 x 8    W4T[k][su]
#define O_B4   18664    // 8
#define O_W3AT 18672    // 8 x 64    W3aT[k][f]
#define O_B3A  19184    // 64
#define O_W3BT 19248    // 64 x 32   W3bT[k][f]
#define O_B3B  21296    // 32
#define O_W3CT 21328    // 32 x 4    W3cT[k][c]
#define O_B3C  21456    // 4
#define O_W1AT 21460    // 3 x 8     W1aT[c][su]
#define O_B1A  21484    // 8
#define W_TOTAL 21492   // floats

// ---- bf16 MFMA fragment region, at byte offset W_TOTAL*4 (bf16 element offsets) ----
#define FRAG_B2_HI  0        // 2048
#define FRAG_B2_LO  2048     // 2048
#define FRAG_C      4096     // 512
#define FRAG_WHH_HI 4608     // 12288
#define FRAG_WHH_LO 16896    // 12288
#define W_EXT (W_TOTAL + 2560 + 12288)   // ws needs 144,336 B

#define GHS 196   // sGH fp32 stride

typedef const float* fwp;
typedef __attribute__((ext_vector_type(8))) short short8;
typedef __attribute__((ext_vector_type(4))) float float4v;

__device__ __forceinline__ short bf16r(float x) {
  __hip_bfloat16 h = __float2bfloat16(x);
  return __builtin_bit_cast(short, h);
}

__global__ void prep_weights(fwp W2a, fwp b2a, fwp W2b, fwp b2b, fwp W2c, fwp b2c,
                             fwp Wih, fwp bih, fwp Whh, fwp bhh,
                             fwp W3a, fwp b3a, fwp W3b, fwp b3b, fwp W3c, fwp b3c,
                             fwp W4, fwp b4, fwp W1a, fwp b1a, float* __restrict__ ws) {
  int idx = blockIdx.x * 256 + threadIdx.x;
  if (idx >= W_EXT) return;
  if (idx >= W_TOTAL) {
    __hip_bfloat16* wb = (__hip_bfloat16*)(ws + W_TOTAL);
    int e = idx - W_TOTAL;
    if (e < 2048) {
      int j = e & 7, L = (e >> 3) & 63, hs = e >> 9;
      int h = hs >> 1, s = hs & 1;
      float v = W2b[(h * 16 + (L & 15)) * 64 + s * 32 + ((L >> 4) & 3) * 8 + j];
      float hi = __bfloat162float(__float2bfloat16(v));
      wb[FRAG_B2_HI + e] = __float2bfloat16(v);
      wb[FRAG_B2_LO + e] = __float2bfloat16(v - hi);
    } else if (e < 2560) {
      int e2 = e - 2048;
      int j = e2 & 7, L = (e2 >> 3) & 63;
      int su = L & 15, q = L >> 4;
      float v = (su < 8) ? W2c[su * 32 + q * 8 + j] : 0.f;
      wb[FRAG_C + e2] = __float2bfloat16(v);
    } else {
      int e2 = e - 2560;                 // [0, 12288)
      int j = e2 & 7, L = (e2 >> 3) & 63, nts = e2 >> 9;
      int nt = nts >> 1, s = nts & 1;
      float v = Whh[(nt * 16 + (L & 15)) * 64 + s * 32 + ((L >> 4) & 3) * 8 + j];
      float hi = __bfloat162float(__float2bfloat16(v));
      wb[FRAG_WHH_HI + e2] = __float2bfloat16(v);
      wb[FRAG_WHH_LO + e2] = __float2bfloat16(v - hi);
    }
    return;
  }
  float v;
  if (idx < O_B2A)       { int p = idx;          int su = p / 64, f = p % 64;   v = W2a[f * 18 + su]; }
  else if (idx < O_W2B)  { v = b2a[idx - O_B2A]; }
  else if (idx < O_B2B)  { v = W2b[idx - O_W2B]; }
  else if (idx < O_W2CT) { v = b2b[idx - O_B2B]; }
  else if (idx < O_B2C)  { int p = idx - O_W2CT; int o = p / 8, su = p % 8;     v = W2c[su * 32 + o]; }
  else if (idx < O_WIHT) { v = b2c[idx - O_B2C]; }
  else if (idx < O_BIH)  { int p = idx - O_WIHT; int k = p / 192, o = p % 192;  v = Wih[o * 10 + k]; }
  else if (idx < O_WHHT) { v = bih[idx - O_BIH]; }
  else if (idx < O_BHH)  { int p = idx - O_WHHT; int k = p / 192, o = p % 192;  v = Whh[o * 64 + k]; }
  else if (idx < O_W4T)  { v = bhh[idx - O_BHH]; }
  else if (idx < O_B4)   { int p = idx - O_W4T;  int k = p / 8, su = p % 8;     v = W4[su * 64 + k]; }
  else if (idx < O_W3AT) { v = b4[idx - O_B4]; }
  else if (idx < O_B3A)  { int p = idx - O_W3AT; int k = p / 64, f = p % 64;    v = W3a[f * 8 + k]; }
  else if (idx < O_W3BT) { v = b3a[idx - O_B3A]; }
  else if (idx < O_B3B)  { int p = idx - O_W3BT; int k = p / 32, f = p % 32;    v = W3b[f * 64 + k]; }
  else if (idx < O_W3CT) { v = b3b[idx - O_B3B]; }
  else if (idx < O_B3C)  { int p = idx - O_W3CT; int k = p / 4, c = p % 4;      v = W3c[c * 32 + k]; }
  else if (idx < O_W1AT) { v = b3c[idx - O_B3C]; }
  else if (idx < O_B1A)  { int p = idx - O_W1AT; int c = p / 8, su = p % 8;     v = W1a[su * 3 + c]; }
  else                   { v = b1a[idx - O_B1A]; }
  ws[idx] = v;
}

// Layer-b K-step: vector fp32 math (v_pk_add/v_pk_fma), weights hi/lo (4 MFMAs).
#define DO_STEP(KOFF, Y0, Y1, W0, W1, FH0, FL0, FH1, FL1)                      \
  {                                                                            \
    float4v x0 = *(const float4v*)&sA1[a * 68 + (KOFF)];                       \
    float4v x1 = *(const float4v*)&sA1[a * 68 + (KOFF) + 4];                   \
    float4v z4 = {0.f, 0.f, 0.f, 0.f};                                         \
    float4v t0 = (x0 + Y0) + ewv * W0;                                         \
    float4v t1 = (x1 + Y1) + ewv * W1;                                         \
    t0 = __builtin_elementwise_max(t0, z4);                                    \
    t1 = __builtin_elementwise_max(t1, z4);                                    \
    short8 ahi;                                                                \
    ahi[0] = bf16r(t0.x); ahi[1] = bf16r(t0.y); ahi[2] = bf16r(t0.z);          \
    ahi[3] = bf16r(t0.w); ahi[4] = bf16r(t1.x); ahi[5] = bf16r(t1.y);          \
    ahi[6] = bf16r(t1.z); ahi[7] = bf16r(t1.w);                                \
    accb0 = __builtin_amdgcn_mfma_f32_16x16x32_bf16(ahi, FH0, accb0, 0, 0, 0); \
    accb0 = __builtin_amdgcn_mfma_f32_16x16x32_bf16(ahi, FL0, accb0, 0, 0, 0); \
    accb1 = __builtin_amdgcn_mfma_f32_16x16x32_bf16(ahi, FH1, accb1, 0, 0, 0); \
    accb1 = __builtin_amdgcn_mfma_f32_16x16x32_bf16(ahi, FL1, accb1, 0, 0, 0); \
  }

#define LAUNDER(v) __asm__ __volatile__("" : "+v"(v))

__global__ __launch_bounds__(256, 1) void gnn_fused(
    const float* __restrict__ read_gru_in,
    const float* __restrict__ gru_init,
    const float* __restrict__ feat,
    const float* __restrict__ edge_w,
    const float* __restrict__ noise_in,
    const float* __restrict__ xhat,
    const float* __restrict__ vep,
    const int* __restrict__ gnn_iter_p,
    const float* __restrict__ ws,
    float* __restrict__ out)
{
  // Overlay pool: edge-phase {sA1, sA2, sM2} aliases GRU-phase sGH (fp32 32x196).
  __shared__ __attribute__((aligned(16))) char spool[NN * GHS * 4];  // 25088 B
  __shared__ __attribute__((aligned(16))) float sH[NN * 68];
  __shared__ float sNodes[NN * 9];
  __shared__ float sSum[NN * 8];
  __shared__ float sEw[ED];
  __shared__ float sC1[64];
  __shared__ float sWew[64];
  __shared__ float sX[NN];
  __shared__ float sV[NN];

  float* const sA1 = (float*)spool;                             // 8704 B
  float* const sA2 = (float*)(spool + 8704);                    // 8704 B
  __hip_bfloat16* const sM2 = (__hip_bfloat16*)(spool + 17408); // 5632 B
  float* const sGH = (float*)spool;                             // 25088 B (aliases all)

  const int b = blockIdx.x;
  const int t = threadIdx.x;
  const int lane = t & 63;
  const int wv = t >> 6;
  const int quad = lane >> 4;
  const int lm = lane & 15;

  const __hip_bfloat16* wb = (const __hip_bfloat16*)(ws + W_TOTAL);

  // ---- per-sample inputs ----
  float noi = noise_in[b];
  for (int e = t; e < ED; e += 256) sEw[e] = edge_w[b * ED + e];
  if (t < NN) { sX[t] = xhat[b * NN + t]; sV[t] = vep[b * NN + t]; }
  if (t < 64) {
    sC1[t]  = ws[O_B2A + t] + noi * ws[O_W2AT + 17 * 64 + t];
    sWew[t] = ws[O_W2AT + 16 * 64 + t];
  }
#pragma unroll
  for (int i = 0; i < 8; ++i) {
    int p = t + 256 * i;
    sH[(p >> 6) * 68 + (p & 63)] = gru_init[b * (NN * HD) + p];
  }
  // ---- init_nodes (iteration 0 only) ----
  {
    const int git = gnn_iter_p[0];
    int n = t >> 3, su = t & 7;
    float acc;
    if (git == 0) {
      acc = ws[O_B1A + su];
#pragma unroll
      for (int c = 0; c < 3; ++c)
        acc += ws[O_W1AT + c * 8 + su] * feat[b * (NN * 3) + n * 3 + c];
    } else {
      acc = read_gru_in[b * (NN * SUD) + t];
    }
    sNodes[n * 9 + su] = acc;
  }
  __syncthreads();

  for (int it = 0; it < NITER; ++it) {
    // ---- A1/A2 node projections (c1 folded into A2) ----
    {
      int iva = 0; LAUNDER(iva);
      const float* wsl = ws + iva;
#pragma unroll
      for (int i = 0; i < 8; ++i) {
        int p = t + 256 * i;
        int n = p >> 6, f = p & 63;
        float a1 = 0.f, a2 = 0.f;
#pragma unroll
        for (int su = 0; su < 8; ++su) {
          float nv = sNodes[n * 9 + su];
          a1 += wsl[O_W2AT + su * 64 + f] * nv;
          a2 += wsl[O_W2AT + (8 + su) * 64 + f] * nv;
        }
        sA1[n * 68 + f] = a1;
        sA2[n * 68 + f] = a2 + sC1[iva + f];
      }
    }
    __syncthreads();

    // ---- edge MLP via MFMA; frags loaded from global (L2) each phase ----
    {
      int ive = 0; LAUNDER(ive);
      const float* wsl = ws + ive;
      const __hip_bfloat16* wbl = wb + ive;
      short8 fbh00 = *(const short8*)(wbl + FRAG_B2_HI + (0 * 64 + lane) * 8);
      short8 fbh01 = *(const short8*)(wbl + FRAG_B2_HI + (1 * 64 + lane) * 8);
      short8 fbh10 = *(const short8*)(wbl + FRAG_B2_HI + (2 * 64 + lane) * 8);
      short8 fbh11 = *(const short8*)(wbl + FRAG_B2_HI + (3 * 64 + lane) * 8);
      short8 fbl00 = *(const short8*)(wbl + FRAG_B2_LO + (0 * 64 + lane) * 8);
      short8 fbl01 = *(const short8*)(wbl + FRAG_B2_LO + (1 * 64 + lane) * 8);
      short8 fbl10 = *(const short8*)(wbl + FRAG_B2_LO + (2 * 64 + lane) * 8);
      short8 fbl11 = *(const short8*)(wbl + FRAG_B2_LO + (3 * 64 + lane) * 8);
      short8 fcf   = *(const short8*)(wbl + FRAG_C + lane * 8);
      const float b2b0 = wsl[O_B2B + lm];
      const float b2b1 = wsl[O_B2B + 16 + lm];
      const float b2cl = wsl[O_B2C + lm];

      __hip_bfloat16* m2w = sM2 + wv * (16 * 44);
      const int kq0 = quad * 8, kq1 = 32 + quad * 8;
      float4v wwA = *(const float4v*)&sWew[ive + kq0];
      float4v wwB = *(const float4v*)&sWew[ive + kq0 + 4];
      float4v wwC = *(const float4v*)&sWew[ive + kq1];
      float4v wwD = *(const float4v*)&sWew[ive + kq1 + 4];
      for (int ni = 0; ni < 8; ++ni) {
        const int jj = wv * 8 + ni;
        float4v yA = *(const float4v*)&sA2[jj * 68 + kq0];
        float4v yB = *(const float4v*)&sA2[jj * 68 + kq0 + 4];
        float4v yC = *(const float4v*)&sA2[jj * 68 + kq1];
        float4v yD = *(const float4v*)&sA2[jj * 68 + kq1 + 4];
        float psum = 0.f;
#pragma unroll
        for (int tile = 0; tile < 2; ++tile) {
          int kk = tile * 16 + lm;
          int kk2 = (kk < 31) ? kk : 0;
          int a = kk2 + (kk2 >= jj ? 1 : 0);
          float ewv = (kk < 31) ? sEw[ive + jj * 31 + kk] : 0.f;
          float4v accb0 = {0.f, 0.f, 0.f, 0.f};
          float4v accb1 = {0.f, 0.f, 0.f, 0.f};
          DO_STEP(kq0, yA, yB, wwA, wwB, fbh00, fbl00, fbh10, fbl10);
          DO_STEP(kq1, yC, yD, wwC, wwD, fbh01, fbl01, fbh11, fbl11);
#pragma unroll
          for (int r = 0; r < 4; ++r) {
            float m20 = fmaxf(accb0[r] + b2b0, 0.f);
            float m21 = fmaxf(accb1[r] + b2b1, 0.f);
            m2w[(quad * 4 + r) * 44 + lm]      = __float2bfloat16(m20);
            m2w[(quad * 4 + r) * 44 + 16 + lm] = __float2bfloat16(m21);
          }
          __asm__ __volatile__("" ::: "memory");
          short8 ac = *(const short8*)(m2w + lm * 44 + quad * 8);
          float4v c3 = {0.f, 0.f, 0.f, 0.f};
          c3 = __builtin_amdgcn_mfma_f32_16x16x32_bf16(ac, fcf, c3, 0, 0, 0);
#pragma unroll
          for (int r = 0; r < 4; ++r) {
            float v = fmaxf(c3[r] + b2cl, 0.f);
            if (tile == 1 && r == 3) v = (quad == 3) ? 0.f : v;
            psum += v;
          }
          __asm__ __volatile__("" ::: "memory");
        }
        psum += __shfl_xor(psum, 16);
        psum += __shfl_xor(psum, 32);
        if (lane < 8) sSum[jj * 8 + lane] = psum;
      }
    }
    __syncthreads();

    // ---- GRU part 1: GH = H @ Whh^T via MFMA. Wave wv owns N-tiles {wv,4+wv,8+wv}
    //      so GRU part 2 (cols wv*16+lm) reads only this wave's output. ----
    {
      int ivg = 0; LAUNDER(ivg);
      const __hip_bfloat16* wbl = wb + ivg;
      short8 aH[2][2];
#pragma unroll
      for (int mt = 0; mt < 2; ++mt) {
#pragma unroll
        for (int s = 0; s < 2; ++s) {
          const float* hp = &sH[(mt * 16 + lm) * 68 + s * 32 + quad * 8];
          float4v h0 = *(const float4v*)hp;
          float4v h1 = *(const float4v*)(hp + 4);
          short8 a;
          a[0] = bf16r(h0.x); a[1] = bf16r(h0.y); a[2] = bf16r(h0.z); a[3] = bf16r(h0.w);
          a[4] = bf16r(h1.x); a[5] = bf16r(h1.y); a[6] = bf16r(h1.z); a[7] = bf16r(h1.w);
          aH[mt][s] = a;
        }
      }
#pragma unroll
      for (int nt = 0; nt < 3; ++nt) {
        int gnt = 4 * nt + wv;
        short8 bh0 = *(const short8*)(wbl + FRAG_WHH_HI + ((gnt * 2 + 0) * 64 + lane) * 8);
        short8 bl0 = *(const short8*)(wbl + FRAG_WHH_LO + ((gnt * 2 + 0) * 64 + lane) * 8);
        short8 bh1 = *(const short8*)(wbl + FRAG_WHH_HI + ((gnt * 2 + 1) * 64 + lane) * 8);
        short8 bl1 = *(const short8*)(wbl + FRAG_WHH_LO + ((gnt * 2 + 1) * 64 + lane) * 8);
#pragma unroll
        for (int mt = 0; mt < 2; ++mt) {
          float4v acc = {0.f, 0.f, 0.f, 0.f};
          acc = __builtin_amdgcn_mfma_f32_16x16x32_bf16(aH[mt][0], bh0, acc, 0, 0, 0);
          acc = __builtin_amdgcn_mfma_f32_16x16x32_bf16(aH[mt][0], bl0, acc, 0, 0, 0);
          acc = __builtin_amdgcn_mfma_f32_16x16x32_bf16(aH[mt][1], bh1, acc, 0, 0, 0);
          acc = __builtin_amdgcn_mfma_f32_16x16x32_bf16(aH[mt][1], bl1, acc, 0, 0, 0);
#pragma unroll
          for (int r = 0; r < 4; ++r)
            sGH[(mt * 16 + quad * 4 + r) * GHS + gnt * 16 + lm] = acc[r];
        }
      }
    }
    __asm__ __volatile__("" ::: "memory");   // order GH writes before same-wave reads

    // ---- GRU part 2: gates; wave-private cols c = wv*16+lm2; hnew staged in regs ----
    {
      int ivq = 0; LAUNDER(ivq);
      const float* wsl = ws + ivq;
      int lm2 = lane & 15, g = lane >> 4;
      int c = wv * 16 + lm2;
      float ar[8], az[8], inx[8];
      {
        float br  = wsl[O_BIH + c]       + wsl[O_BHH + c];
        float bz  = wsl[O_BIH + 64 + c]  + wsl[O_BHH + 64 + c];
        float bni = wsl[O_BIH + 128 + c];
#pragma unroll
        for (int j = 0; j < 8; ++j) { ar[j] = br; az[j] = bz; inx[j] = bni; }
      }
#pragma unroll
      for (int k = 0; k < 8; ++k) {
        float wr = wsl[O_WIHT + k * 192 + c];
        float wz = wsl[O_WIHT + k * 192 + 64 + c];
        float wn = wsl[O_WIHT + k * 192 + 128 + c];
#pragma unroll
        for (int j = 0; j < 8; ++j) {
          float gg = sSum[(g + 4 * j) * 8 + k];
          ar[j] += wr * gg; az[j] += wz * gg; inx[j] += wn * gg;
        }
      }
      {
        float wr = wsl[O_WIHT + 8 * 192 + c];
        float wz = wsl[O_WIHT + 8 * 192 + 64 + c];
        float wn = wsl[O_WIHT + 8 * 192 + 128 + c];
#pragma unroll
        for (int j = 0; j < 8; ++j) {
          float gg = sX[ivq + g + 4 * j];
          ar[j] += wr * gg; az[j] += wz * gg; inx[j] += wn * gg;
        }
        wr = wsl[O_WIHT + 9 * 192 + c];
        wz = wsl[O_WIHT + 9 * 192 + 64 + c];
        wn = wsl[O_WIHT + 9 * 192 + 128 + c];
#pragma unroll
        for (int j = 0; j < 8; ++j) {
          float gg = sV[ivq + g + 4 * j];
          ar[j] += wr * gg; az[j] += wz * gg; inx[j] += wn * gg;
        }
      }
      float bnh = wsl[O_BHH + 128 + c];
      float hnew[8];
#pragma unroll
      for (int j = 0; j < 8; ++j) {
        int n = g + 4 * j;
        float ghr = sGH[n * GHS + c];
        float ghz = sGH[n * GHS + 64 + c];
        float ghn = sGH[n * GHS + 128 + c] + bnh;
        float r = 1.f / (1.f + __expf(-(ar[j] + ghr)));
        float z = 1.f / (1.f + __expf(-(az[j] + ghz)));
        float cd = inx[j] + r * ghn;
        float e2 = __expf(2.f * cd);
        float th = 1.f - 2.f / (e2 + 1.f);
        hnew[j] = (1.f - z) * th + z * sH[n * 68 + c];
      }
      __syncthreads();   // other waves' GRU1 reads of all sH cols complete
#pragma unroll
      for (int j = 0; j < 8; ++j) sH[(g + 4 * j) * 68 + c] = hnew[j];
    }
    __syncthreads();

    // ---- read_gru = W4 @ h + b4 -> sNodes ----
    {
      int ivw = 0; LAUNDER(ivw);
      const float* wsl = ws + ivw;
      int n = t >> 3, su = t & 7;
      float c0 = 0.f, c1v = 0.f, c2 = 0.f, c3v = 0.f;
#pragma unroll
      for (int k = 0; k < 64; k += 4) {
        c0  += wsl[O_W4T + (k + 0) * 8 + su] * sH[n * 68 + k + 0];
        c1v += wsl[O_W4T + (k + 1) * 8 + su] * sH[n * 68 + k + 1];
        c2  += wsl[O_W4T + (k + 2) * 8 + su] * sH[n * 68 + k + 2];
        c3v += wsl[O_W4T + (k + 3) * 8 + su] * sH[n * 68 + k + 3];
      }
      sNodes[n * 9 + su] = wsl[O_B4 + su] + ((c0 + c1v) + (c2 + c3v));
    }
    __syncthreads();
  } // iterations

  // ---- head ----
#pragma unroll
  for (int i = 0; i < 8; ++i) {
    int p = t + 256 * i;
    int n = p >> 6, f = p & 63;
    float acc = ws[O_B3A + f];
#pragma unroll
    for (int k = 0; k < 8; ++k) acc += ws[O_W3AT + k * 64 + f] * sNodes[n * 9 + k];
    sA1[n * 68 + f] = acc;
  }
  __syncthreads();
#pragma unroll
  for (int i = 0; i < 4; ++i) {
    int p = t + 256 * i;
    int n = p >> 5, f = p & 31;
    float c0 = 0.f, c1v = 0.f, c2 = 0.f, c3v = 0.f;
#pragma unroll
    for (int k = 0; k < 64; k += 4) {
      c0  += ws[O_W3BT + (k + 0) * 32 + f] * sA1[n * 68 + k + 0];
      c1v += ws[O_W3BT + (k + 1) * 32 + f] * sA1[n * 68 + k + 1];
      c2  += ws[O_W3BT + (k + 2) * 32 + f] * sA1[n * 68 + k + 2];
      c3v += ws[O_W3BT + (k + 3) * 32 + f] * sA1[n * 68 + k + 3];
    }
    sA2[n * 33 + f] = ws[O_B3B + f] + ((c0 + c1v) + (c2 + c3v));
  }
  __syncthreads();
  if (t < 128) {
    int n = t >> 2, c = t & 3;
    float acc = ws[O_B3C + c];
#pragma unroll
    for (int k = 0; k < 32; ++k) acc += ws[O_W3CT + k * 4 + c] * sA2[n * 33 + k];
    out[b * (NN * NCD) + t] = acc;
  }
  out[BB * NN * NCD + b * (NN * SUD) + t] = sNodes[(t >> 3) * 9 + (t & 7)];
#pragma unroll
  for (int i = 0; i < 8; ++i) {
    int p = t + 256 * i;
    out[BB * NN * NCD + BB * NN * SUD + b * (NN * HD) + p] =
        sH[(p >> 6) * 68 + (p & 63)];
  }
}

extern "C" void kernel_launch(void* const* d_in, const int* in_sizes, int n_in,
                              void* d_out, int out_size, void* d_ws, size_t ws_size,
                              hipStream_t stream) {
  typedef const float* F32;
  F32 read_gru = (F32)d_in[0];
  F32 gru_init = (F32)d_in[1];
  F32 feat     = (F32)d_in[2];
  F32 edge_w   = (F32)d_in[3];
  F32 noise    = (F32)d_in[4];
  F32 xh       = (F32)d_in[5];
  F32 vp       = (F32)d_in[6];
  F32 W1a = (F32)d_in[7];  F32 b1a = (F32)d_in[8];
  F32 W2a = (F32)d_in[9];  F32 b2a = (F32)d_in[10];
  F32 W2b = (F32)d_in[11]; F32 b2b = (F32)d_in[12];
  F32 W2c = (F32)d_in[13]; F32 b2c = (F32)d_in[14];
  F32 Wih = (F32)d_in[15]; F32 bih = (F32)d_in[16];
  F32 Whh = (F32)d_in[17]; F32 bhh = (F32)d_in[18];
  F32 W3a = (F32)d_in[19]; F32 b3a = (F32)d_in[20];
  F32 W3b = (F32)d_in[21]; F32 b3b = (F32)d_in[22];
  F32 W3c = (F32)d_in[23]; F32 b3c = (F32)d_in[24];
  F32 W4  = (F32)d_in[25]; F32 b4  = (F32)d_in[26];
  const int* git = (const int*)d_in[27];
  float* ws = (float*)d_ws;   // needs 144,336 B

  prep_weights<<<(W_EXT + 255) / 256, 256, 0, stream>>>(
      W2a, b2a, W2b, b2b, W2c, b2c, Wih, bih, Whh, bhh,
      W3a, b3a, W3b, b3b, W3c, b3c, W4, b4, W1a, b1a, ws);

  gnn_fused<<<BB, 256, 0, stream>>>(read_gru, gru_init, feat, edge_w, noise,
                                    xh, vp, git, ws, (float*)d_out);
}

// Round 14
// 287.983 us; speedup vs baseline: 3.2081x; 1.0795x over previous
//
#include <hip/hip_runtime.h>
#include <hip/hip_bf16.h>

#define BB 1024
#define NN 32
#define SUD 8
#define HD 64
#define NCD 4
#define ED 992      // NN*(NN-1)
#define NITER 5

// ---- fp32 weight workspace layout (element offsets into d_ws) ----
#define O_W2AT 0        // 18 x 64   W2aT[su][f] = W2a[f][su]
#define O_B2A  1152     // 64
#define O_W2B  1216     // 32 x 64
#define O_B2B  3264     // 32
#define O_W2CT 3296     // 32 x 8
#define O_B2C  3552     // 8
#define O_WIHT 3560     // 10 x 192  WihT[k][o]
#define O_BIH  5480     // 192
#define O_WHHT 5672     // 64 x 192  WhhT[k][o]
#define O_BHH  17960    // 192
#define O_W4T  18152    // 64 x 8    W4T[k][su]
#define O_B4   18664    // 8
#define O_W3AT 18672    // 8 x 64    W3aT[k][f]
#define O_B3A  19184    // 64
#define O_W3BT 19248    // 64 x 32   W3bT[k][f]
#define O_B3B  21296    // 32
#define O_W3CT 21328    // 32 x 4    W3cT[k][c]
#define O_B3C  21456    // 4
#define O_W1AT 21460    // 3 x 8     W1aT[c][su]
#define O_B1A  21484    // 8
#define W_TOTAL 21492   // floats

// ---- bf16 MFMA fragment region, at byte offset W_TOTAL*4 (bf16 element offsets) ----
#define FRAG_B2_HI  0        // 2048
#define FRAG_B2_LO  2048     // 2048 (written by prep; unused since R14 lo-drop)
#define FRAG_C      4096     // 512
#define FRAG_WHH_HI 4608     // 12288
#define FRAG_WHH_LO 16896    // 12288 (unused since R14)
#define W_EXT (W_TOTAL + 2560 + 12288)   // ws needs 144,336 B

#define GHS 196   // sGH fp32 stride

typedef const float* fwp;
typedef __attribute__((ext_vector_type(8))) short short8;
typedef __attribute__((ext_vector_type(4))) float float4v;

__device__ __forceinline__ short bf16r(float x) {
  __hip_bfloat16 h = __float2bfloat16(x);
  return __builtin_bit_cast(short, h);
}

__global__ void prep_weights(fwp W2a, fwp b2a, fwp W2b, fwp b2b, fwp W2c, fwp b2c,
                             fwp Wih, fwp bih, fwp Whh, fwp bhh,
                             fwp W3a, fwp b3a, fwp W3b, fwp b3b, fwp W3c, fwp b3c,
                             fwp W4, fwp b4, fwp W1a, fwp b1a, float* __restrict__ ws) {
  int idx = blockIdx.x * 256 + threadIdx.x;
  if (idx >= W_EXT) return;
  if (idx >= W_TOTAL) {
    __hip_bfloat16* wb = (__hip_bfloat16*)(ws + W_TOTAL);
    int e = idx - W_TOTAL;
    if (e < 2048) {
      int j = e & 7, L = (e >> 3) & 63, hs = e >> 9;
      int h = hs >> 1, s = hs & 1;
      float v = W2b[(h * 16 + (L & 15)) * 64 + s * 32 + ((L >> 4) & 3) * 8 + j];
      float hi = __bfloat162float(__float2bfloat16(v));
      wb[FRAG_B2_HI + e] = __float2bfloat16(v);
      wb[FRAG_B2_LO + e] = __float2bfloat16(v - hi);
    } else if (e < 2560) {
      int e2 = e - 2048;
      int j = e2 & 7, L = (e2 >> 3) & 63;
      int su = L & 15, q = L >> 4;
      float v = (su < 8) ? W2c[su * 32 + q * 8 + j] : 0.f;
      wb[FRAG_C + e2] = __float2bfloat16(v);
    } else {
      int e2 = e - 2560;                 // [0, 12288)
      int j = e2 & 7, L = (e2 >> 3) & 63, nts = e2 >> 9;
      int nt = nts >> 1, s = nts & 1;
      float v = Whh[(nt * 16 + (L & 15)) * 64 + s * 32 + ((L >> 4) & 3) * 8 + j];
      float hi = __bfloat162float(__float2bfloat16(v));
      wb[FRAG_WHH_HI + e2] = __float2bfloat16(v);
      wb[FRAG_WHH_LO + e2] = __float2bfloat16(v - hi);
    }
    return;
  }
  float v;
  if (idx < O_B2A)       { int p = idx;          int su = p / 64, f = p % 64;   v = W2a[f * 18 + su]; }
  else if (idx < O_W2B)  { v = b2a[idx - O_B2A]; }
  else if (idx < O_B2B)  { v = W2b[idx - O_W2B]; }
  else if (idx < O_W2CT) { v = b2b[idx - O_B2B]; }
  else if (idx < O_B2C)  { int p = idx - O_W2CT; int o = p / 8, su = p % 8;     v = W2c[su * 32 + o]; }
  else if (idx < O_WIHT) { v = b2c[idx - O_B2C]; }
  else if (idx < O_BIH)  { int p = idx - O_WIHT; int k = p / 192, o = p % 192;  v = Wih[o * 10 + k]; }
  else if (idx < O_WHHT) { v = bih[idx - O_BIH]; }
  else if (idx < O_BHH)  { int p = idx - O_WHHT; int k = p / 192, o = p % 192;  v = Whh[o * 64 + k]; }
  else if (idx < O_W4T)  { v = bhh[idx - O_BHH]; }
  else if (idx < O_B4)   { int p = idx - O_W4T;  int k = p / 8, su = p % 8;     v = W4[su * 64 + k]; }
  else if (idx < O_W3AT) { v = b4[idx - O_B4]; }
  else if (idx < O_B3A)  { int p = idx - O_W3AT; int k = p / 64, f = p % 64;    v = W3a[f * 8 + k]; }
  else if (idx < O_W3BT) { v = b3a[idx - O_B3A]; }
  else if (idx < O_B3B)  { int p = idx - O_W3BT; int k = p / 32, f = p % 32;    v = W3b[f * 64 + k]; }
  else if (idx < O_W3CT) { v = b3b[idx - O_B3B]; }
  else if (idx < O_B3C)  { int p = idx - O_W3CT; int k = p / 4, c = p % 4;      v = W3c[c * 32 + k]; }
  else if (idx < O_W1AT) { v = b3c[idx - O_B3C]; }
  else if (idx < O_B1A)  { int p = idx - O_W1AT; int c = p / 8, su = p % 8;     v = W1a[su * 3 + c]; }
  else                   { v = b1a[idx - O_B1A]; }
  ws[idx] = v;
}

// Layer-b K-step: packed fp32 math, single-bf16 weights (2 MFMAs; lo dropped R14).
#define DO_STEP(KOFF, Y0, Y1, W0, W1, FH0, FH1)                                \
  {                                                                            \
    float4v x0 = *(const float4v*)&sA1[a * 68 + (KOFF)];                       \
    float4v x1 = *(const float4v*)&sA1[a * 68 + (KOFF) + 4];                   \
    float4v z4 = {0.f, 0.f, 0.f, 0.f};                                         \
    float4v t0 = (x0 + Y0) + ewv * W0;                                         \
    float4v t1 = (x1 + Y1) + ewv * W1;                                         \
    t0 = __builtin_elementwise_max(t0, z4);                                    \
    t1 = __builtin_elementwise_max(t1, z4);                                    \
    short8 ahi;                                                                \
    ahi[0] = bf16r(t0.x); ahi[1] = bf16r(t0.y); ahi[2] = bf16r(t0.z);          \
    ahi[3] = bf16r(t0.w); ahi[4] = bf16r(t1.x); ahi[5] = bf16r(t1.y);          \
    ahi[6] = bf16r(t1.z); ahi[7] = bf16r(t1.w);                                \
    accb0 = __builtin_amdgcn_mfma_f32_16x16x32_bf16(ahi, FH0, accb0, 0, 0, 0); \
    accb1 = __builtin_amdgcn_mfma_f32_16x16x32_bf16(ahi, FH1, accb1, 0, 0, 0); \
  }

#define LAUNDER(v) __asm__ __volatile__("" : "+v"(v))

// (256,3): 3 waves/SIMD target (total reg budget ~170). Lo-drop + laundering
// shrank per-phase live sets so this should fit spill-free (watch WRITE_SIZE).
__global__ __launch_bounds__(256, 3) void gnn_fused(
    const float* __restrict__ read_gru_in,
    const float* __restrict__ gru_init,
    const float* __restrict__ feat,
    const float* __restrict__ edge_w,
    const float* __restrict__ noise_in,
    const float* __restrict__ xhat,
    const float* __restrict__ vep,
    const int* __restrict__ gnn_iter_p,
    const float* __restrict__ ws,
    float* __restrict__ out)
{
  // Overlay pool: edge-phase {sA1, sA2, sM2} aliases GRU-phase sGH (fp32 32x196).
  __shared__ __attribute__((aligned(16))) char spool[NN * GHS * 4];  // 25088 B
  __shared__ __attribute__((aligned(16))) float sH[NN * 68];
  __shared__ float sNodes[NN * 9];
  __shared__ float sSum[NN * 8];
  __shared__ float sEw[ED];
  __shared__ float sC1[64];
  __shared__ float sWew[64];
  __shared__ float sX[NN];
  __shared__ float sV[NN];

  float* const sA1 = (float*)spool;                             // 8704 B
  float* const sA2 = (float*)(spool + 8704);                    // 8704 B
  __hip_bfloat16* const sM2 = (__hip_bfloat16*)(spool + 17408); // 5632 B
  float* const sGH = (float*)spool;                             // 25088 B (aliases all)

  const int b = blockIdx.x;
  const int t = threadIdx.x;
  const int lane = t & 63;
  const int wv = t >> 6;
  const int quad = lane >> 4;
  const int lm = lane & 15;

  const __hip_bfloat16* wb = (const __hip_bfloat16*)(ws + W_TOTAL);

  // ---- per-sample inputs ----
  float noi = noise_in[b];
  for (int e = t; e < ED; e += 256) sEw[e] = edge_w[b * ED + e];
  if (t < NN) { sX[t] = xhat[b * NN + t]; sV[t] = vep[b * NN + t]; }
  if (t < 64) {
    sC1[t]  = ws[O_B2A + t] + noi * ws[O_W2AT + 17 * 64 + t];
    sWew[t] = ws[O_W2AT + 16 * 64 + t];
  }
#pragma unroll
  for (int i = 0; i < 8; ++i) {
    int p = t + 256 * i;
    sH[(p >> 6) * 68 + (p & 63)] = gru_init[b * (NN * HD) + p];
  }
  // ---- init_nodes (iteration 0 only) ----
  {
    const int git = gnn_iter_p[0];
    int n = t >> 3, su = t & 7;
    float acc;
    if (git == 0) {
      acc = ws[O_B1A + su];
#pragma unroll
      for (int c = 0; c < 3; ++c)
        acc += ws[O_W1AT + c * 8 + su] * feat[b * (NN * 3) + n * 3 + c];
    } else {
      acc = read_gru_in[b * (NN * SUD) + t];
    }
    sNodes[n * 9 + su] = acc;
  }
  __syncthreads();

  for (int it = 0; it < NITER; ++it) {
    // ---- A1/A2 node projections (c1 folded into A2) ----
    {
      int iva = 0; LAUNDER(iva);
      const float* wsl = ws + iva;
#pragma unroll
      for (int i = 0; i < 8; ++i) {
        int p = t + 256 * i;
        int n = p >> 6, f = p & 63;
        float a1 = 0.f, a2 = 0.f;
#pragma unroll
        for (int su = 0; su < 8; ++su) {
          float nv = sNodes[n * 9 + su];
          a1 += wsl[O_W2AT + su * 64 + f] * nv;
          a2 += wsl[O_W2AT + (8 + su) * 64 + f] * nv;
        }
        sA1[n * 68 + f] = a1;
        sA2[n * 68 + f] = a2 + sC1[iva + f];
      }
    }
    __syncthreads();

    // ---- edge MLP via MFMA; frags loaded from global (L2) each phase ----
    {
      int ive = 0; LAUNDER(ive);
      const float* wsl = ws + ive;
      const __hip_bfloat16* wbl = wb + ive;
      short8 fbh00 = *(const short8*)(wbl + FRAG_B2_HI + (0 * 64 + lane) * 8);
      short8 fbh01 = *(const short8*)(wbl + FRAG_B2_HI + (1 * 64 + lane) * 8);
      short8 fbh10 = *(const short8*)(wbl + FRAG_B2_HI + (2 * 64 + lane) * 8);
      short8 fbh11 = *(const short8*)(wbl + FRAG_B2_HI + (3 * 64 + lane) * 8);
      short8 fcf   = *(const short8*)(wbl + FRAG_C + lane * 8);
      const float b2b0 = wsl[O_B2B + lm];
      const float b2b1 = wsl[O_B2B + 16 + lm];
      const float b2cl = wsl[O_B2C + lm];

      __hip_bfloat16* m2w = sM2 + wv * (16 * 44);
      const int kq0 = quad * 8, kq1 = 32 + quad * 8;
      float4v wwA = *(const float4v*)&sWew[ive + kq0];
      float4v wwB = *(const float4v*)&sWew[ive + kq0 + 4];
      float4v wwC = *(const float4v*)&sWew[ive + kq1];
      float4v wwD = *(const float4v*)&sWew[ive + kq1 + 4];
      for (int ni = 0; ni < 8; ++ni) {
        const int jj = wv * 8 + ni;
        float4v yA = *(const float4v*)&sA2[jj * 68 + kq0];
        float4v yB = *(const float4v*)&sA2[jj * 68 + kq0 + 4];
        float4v yC = *(const float4v*)&sA2[jj * 68 + kq1];
        float4v yD = *(const float4v*)&sA2[jj * 68 + kq1 + 4];
        float psum = 0.f;
#pragma unroll
        for (int tile = 0; tile < 2; ++tile) {
          int kk = tile * 16 + lm;
          int kk2 = (kk < 31) ? kk : 0;
          int a = kk2 + (kk2 >= jj ? 1 : 0);
          float ewv = (kk < 31) ? sEw[ive + jj * 31 + kk] : 0.f;
          float4v accb0 = {0.f, 0.f, 0.f, 0.f};
          float4v accb1 = {0.f, 0.f, 0.f, 0.f};
          DO_STEP(kq0, yA, yB, wwA, wwB, fbh00, fbh10);
          DO_STEP(kq1, yC, yD, wwC, wwD, fbh01, fbh11);
#pragma unroll
          for (int r = 0; r < 4; ++r) {
            float m20 = fmaxf(accb0[r] + b2b0, 0.f);
            float m21 = fmaxf(accb1[r] + b2b1, 0.f);
            m2w[(quad * 4 + r) * 44 + lm]      = __float2bfloat16(m20);
            m2w[(quad * 4 + r) * 44 + 16 + lm] = __float2bfloat16(m21);
          }
          __asm__ __volatile__("" ::: "memory");
          short8 ac = *(const short8*)(m2w + lm * 44 + quad * 8);
          float4v c3 = {0.f, 0.f, 0.f, 0.f};
          c3 = __builtin_amdgcn_mfma_f32_16x16x32_bf16(ac, fcf, c3, 0, 0, 0);
#pragma unroll
          for (int r = 0; r < 4; ++r) {
            float v = fmaxf(c3[r] + b2cl, 0.f);
            if (tile == 1 && r == 3) v = (quad == 3) ? 0.f : v;
            psum += v;
          }
          __asm__ __volatile__("" ::: "memory");
        }
        psum += __shfl_xor(psum, 16);
        psum += __shfl_xor(psum, 32);
        if (lane < 8) sSum[jj * 8 + lane] = psum;
      }
    }
    __syncthreads();

    // ---- GRU part 1: GH = H @ Whh^T via MFMA. Wave wv owns N-tiles {wv,4+wv,8+wv}
    //      so GRU part 2 (cols wv*16+lm) reads only this wave's output. ----
    {
      int ivg = 0; LAUNDER(ivg);
      const __hip_bfloat16* wbl = wb + ivg;
      short8 aH[2][2];
#pragma unroll
      for (int mt = 0; mt < 2; ++mt) {
#pragma unroll
        for (int s = 0; s < 2; ++s) {
          const float* hp = &sH[(mt * 16 + lm) * 68 + s * 32 + quad * 8];
          float4v h0 = *(const float4v*)hp;
          float4v h1 = *(const float4v*)(hp + 4);
          short8 a;
          a[0] = bf16r(h0.x); a[1] = bf16r(h0.y); a[2] = bf16r(h0.z); a[3] = bf16r(h0.w);
          a[4] = bf16r(h1.x); a[5] = bf16r(h1.y); a[6] = bf16r(h1.z); a[7] = bf16r(h1.w);
          aH[mt][s] = a;
        }
      }
#pragma unroll
      for (int nt = 0; nt < 3; ++nt) {
        int gnt = 4 * nt + wv;
        short8 bh0 = *(const short8*)(wbl + FRAG_WHH_HI + ((gnt * 2 + 0) * 64 + lane) * 8);
        short8 bh1 = *(const short8*)(wbl + FRAG_WHH_HI + ((gnt * 2 + 1) * 64 + lane) * 8);
#pragma unroll
        for (int mt = 0; mt < 2; ++mt) {
          float4v acc = {0.f, 0.f, 0.f, 0.f};
          acc = __builtin_amdgcn_mfma_f32_16x16x32_bf16(aH[mt][0], bh0, acc, 0, 0, 0);
          acc = __builtin_amdgcn_mfma_f32_16x16x32_bf16(aH[mt][1], bh1, acc, 0, 0, 0);
#pragma unroll
          for (int r = 0; r < 4; ++r)
            sGH[(mt * 16 + quad * 4 + r) * GHS + gnt * 16 + lm] = acc[r];
        }
      }
    }
    __asm__ __volatile__("" ::: "memory");   // order GH writes before same-wave reads

    // ---- GRU part 2: gates; wave-private cols c = wv*16+lm2; hnew staged in regs ----
    {
      int ivq = 0; LAUNDER(ivq);
      const float* wsl = ws + ivq;
      int lm2 = lane & 15, g = lane >> 4;
      int c = wv * 16 + lm2;
      float ar[8], az[8], inx[8];
      {
        float br  = wsl[O_BIH + c]       + wsl[O_BHH + c];
        float bz  = wsl[O_BIH + 64 + c]  + wsl[O_BHH + 64 + c];
        float bni = wsl[O_BIH + 128 + c];
#pragma unroll
        for (int j = 0; j < 8; ++j) { ar[j] = br; az[j] = bz; inx[j] = bni; }
      }
#pragma unroll
      for (int k = 0; k < 8; ++k) {
        float wr = wsl[O_WIHT + k * 192 + c];
        float wz = wsl[O_WIHT + k * 192 + 64 + c];
        float wn = wsl[O_WIHT + k * 192 + 128 + c];
#pragma unroll
        for (int j = 0; j < 8; ++j) {
          float gg = sSum[(g + 4 * j) * 8 + k];
          ar[j] += wr * gg; az[j] += wz * gg; inx[j] += wn * gg;
        }
      }
      {
        float wr = wsl[O_WIHT + 8 * 192 + c];
        float wz = wsl[O_WIHT + 8 * 192 + 64 + c];
        float wn = wsl[O_WIHT + 8 * 192 + 128 + c];
#pragma unroll
        for (int j = 0; j < 8; ++j) {
          float gg = sX[ivq + g + 4 * j];
          ar[j] += wr * gg; az[j] += wz * gg; inx[j] += wn * gg;
        }
        wr = wsl[O_WIHT + 9 * 192 + c];
        wz = wsl[O_WIHT + 9 * 192 + 64 + c];
        wn = wsl[O_WIHT + 9 * 192 + 128 + c];
#pragma unroll
        for (int j = 0; j < 8; ++j) {
          float gg = sV[ivq + g + 4 * j];
          ar[j] += wr * gg; az[j] += wz * gg; inx[j] += wn * gg;
        }
      }
      float bnh = wsl[O_BHH + 128 + c];
      float hnew[8];
#pragma unroll
      for (int j = 0; j < 8; ++j) {
        int n = g + 4 * j;
        float ghr = sGH[n * GHS + c];
        float ghz = sGH[n * GHS + 64 + c];
        float ghn = sGH[n * GHS + 128 + c] + bnh;
        float r = 1.f / (1.f + __expf(-(ar[j] + ghr)));
        float z = 1.f / (1.f + __expf(-(az[j] + ghz)));
        float cd = inx[j] + r * ghn;
        float e2 = __expf(2.f * cd);
        float th = 1.f - 2.f / (e2 + 1.f);
        hnew[j] = (1.f - z) * th + z * sH[n * 68 + c];
      }
      __syncthreads();   // other waves' GRU1 reads of all sH cols complete
#pragma unroll
      for (int j = 0; j < 8; ++j) sH[(g + 4 * j) * 68 + c] = hnew[j];
    }
    __syncthreads();

    // ---- read_gru = W4 @ h + b4 -> sNodes ----
    {
      int ivw = 0; LAUNDER(ivw);
      const float* wsl = ws + ivw;
      int n = t >> 3, su = t & 7;
      float c0 = 0.f, c1v = 0.f, c2 = 0.f, c3v = 0.f;
#pragma unroll
      for (int k = 0; k < 64; k += 4) {
        c0  += wsl[O_W4T + (k + 0) * 8 + su] * sH[n * 68 + k + 0];
        c1v += wsl[O_W4T + (k + 1) * 8 + su] * sH[n * 68 + k + 1];
        c2  += wsl[O_W4T + (k + 2) * 8 + su] * sH[n * 68 + k + 2];
        c3v += wsl[O_W4T + (k + 3) * 8 + su] * sH[n * 68 + k + 3];
      }
      sNodes[n * 9 + su] = wsl[O_B4 + su] + ((c0 + c1v) + (c2 + c3v));
    }
    __syncthreads();
  } // iterations

  // ---- head ----
#pragma unroll
  for (int i = 0; i < 8; ++i) {
    int p = t + 256 * i;
    int n = p >> 6, f = p & 63;
    float acc = ws[O_B3A + f];
#pragma unroll
    for (int k = 0; k < 8; ++k) acc += ws[O_W3AT + k * 64 + f] * sNodes[n * 9 + k];
    sA1[n * 68 + f] = acc;
  }
  __syncthreads();
#pragma unroll
  for (int i = 0; i < 4; ++i) {
    int p = t + 256 * i;
    int n = p >> 5, f = p & 31;
    float c0 = 0.f, c1v = 0.f, c2 = 0.f, c3v = 0.f;
#pragma unroll
    for (int k = 0; k < 64; k += 4) {
      c0  += ws[O_W3BT + (k + 0) * 32 + f] * sA1[n * 68 + k + 0];
      c1v += ws[O_W3BT + (k + 1) * 32 + f] * sA1[n * 68 + k + 1];
      c2  += ws[O_W3BT + (k + 2) * 32 + f] * sA1[n * 68 + k + 2];
      c3v += ws[O_W3BT + (k + 3) * 32 + f] * sA1[n * 68 + k + 3];
    }
    sA2[n * 33 + f] = ws[O_B3B + f] + ((c0 + c1v) + (c2 + c3v));
  }
  __syncthreads();
  if (t < 128) {
    int n = t >> 2, c = t & 3;
    float acc = ws[O_B3C + c];
#pragma unroll
    for (int k = 0; k < 32; ++k) acc += ws[O_W3CT + k * 4 + c] * sA2[n * 33 + k];
    out[b * (NN * NCD) + t] = acc;
  }
  out[BB * NN * NCD + b * (NN * SUD) + t] = sNodes[(t >> 3) * 9 + (t & 7)];
#pragma unroll
  for (int i = 0; i < 8; ++i) {
    int p = t + 256 * i;
    out[BB * NN * NCD + BB * NN * SUD + b * (NN * HD) + p] =
        sH[(p >> 6) * 68 + (p & 63)];
  }
}

extern "C" void kernel_launch(void* const* d_in, const int* in_sizes, int n_in,
                              void* d_out, int out_size, void* d_ws, size_t ws_size,
                              hipStream_t stream) {
  typedef const float* F32;
  F32 read_gru = (F32)d_in[0];
  F32 gru_init = (F32)d_in[1];
  F32 feat     = (F32)d_in[2];
  F32 edge_w   = (F32)d_in[3];
  F32 noise    = (F32)d_in[4];
  F32 xh       = (F32)d_in[5];
  F32 vp       = (F32)d_in[6];
  F32 W1a = (F32)d_in[7];  F32 b1a = (F32)d_in[8];
  F32 W2a = (F32)d_in[9];  F32 b2a = (F32)d_in[10];
  F32 W2b = (F32)d_in[11]; F32 b2b = (F32)d_in[12];
  F32 W2c = (F32)d_in[13]; F32 b2c = (F32)d_in[14];
  F32 Wih = (F32)d_in[15]; F32 bih = (F32)d_in[16];
  F32 Whh = (F32)d_in[17]; F32 bhh = (F32)d_in[18];
  F32 W3a = (F32)d_in[19]; F32 b3a = (F32)d_in[20];
  F32 W3b = (F32)d_in[21]; F32 b3b = (F32)d_in[22];
  F32 W3c = (F32)d_in[23]; F32 b3c = (F32)d_in[24];
  F32 W4  = (F32)d_in[25]; F32 b4  = (F32)d_in[26];
  const int* git = (const int*)d_in[27];
  float* ws = (float*)d_ws;   // needs 144,336 B

  prep_weights<<<(W_EXT + 255) / 256, 256, 0, stream>>>(
      W2a, b2a, W2b, b2b, W2c, b2c, Wih, bih, Whh, bhh,
      W3a, b3a, W3b, b3b, W3c, b3c, W4, b4, W1a, b1a, ws);

  gnn_fused<<<BB, 256, 0, stream>>>(read_gru, gru_init, feat, edge_w, noise,
                                    xh, vp, git, ws, (float*)d_out);
}

// Round 15
// 268.421 us; speedup vs baseline: 3.4419x; 1.0729x over previous
//
#include <hip/hip_runtime.h>
#include <hip/hip_bf16.h>

#define BB 1024
#define NN 32
#define SUD 8
#define HD 64
#define NCD 4
#define ED 992      // NN*(NN-1)
#define NITER 5

// ---- fp32 weight workspace layout (element offsets into d_ws) ----
#define O_W2AT 0        // 18 x 64   W2aT[su][f] = W2a[f][su]
#define O_B2A  1152     // 64
#define O_W2B  1216     // 32 x 64
#define O_B2B  3264     // 32
#define O_W2CT 3296     // 32 x 8
#define O_B2C  3552     // 8
#define O_WIHT 3560     // 10 x 192  WihT[k][o]
#define O_BIH  5480     // 192
#define O_WHHT 5672     // 64 x 192  WhhT[k][o]
#define O_BHH  17960    // 192
#define O_W4T  18152    // 64 x 8    W4T[k][su]
#define O_B4   18664    // 8
#define O_W3AT 18672    // 8 x 64    W3aT[k][f]
#define O_B3A  19184    // 64
#define O_W3BT 19248    // 64 x 32   W3bT[k][f]
#define O_B3B  21296    // 32
#define O_W3CT 21328    // 32 x 4    W3cT[k][c]
#define O_B3C  21456    // 4
#define O_W1AT 21460    // 3 x 8     W1aT[c][su]
#define O_B1A  21484    // 8
#define W_TOTAL 21492   // floats

// ---- bf16 MFMA fragment region, at byte offset W_TOTAL*4 (bf16 element offsets) ----
#define FRAG_B2_HI  0        // 2048
#define FRAG_B2_LO  2048     // 2048 (written by prep; unused since R14 lo-drop)
#define FRAG_C      4096     // 512
#define FRAG_WHH_HI 4608     // 12288
#define FRAG_WHH_LO 16896    // 12288 (unused since R14)
#define W_EXT (W_TOTAL + 2560 + 12288)   // ws needs 144,336 B

#define GHS 196   // sGH fp32 stride

typedef const float* fwp;
typedef __attribute__((ext_vector_type(8))) short short8;
typedef __attribute__((ext_vector_type(4))) float float4v;

__device__ __forceinline__ short bf16r(float x) {
  __hip_bfloat16 h = __float2bfloat16(x);
  return __builtin_bit_cast(short, h);
}

__global__ void prep_weights(fwp W2a, fwp b2a, fwp W2b, fwp b2b, fwp W2c, fwp b2c,
                             fwp Wih, fwp bih, fwp Whh, fwp bhh,
                             fwp W3a, fwp b3a, fwp W3b, fwp b3b, fwp W3c, fwp b3c,
                             fwp W4, fwp b4, fwp W1a, fwp b1a, float* __restrict__ ws) {
  int idx = blockIdx.x * 256 + threadIdx.x;
  if (idx >= W_EXT) return;
  if (idx >= W_TOTAL) {
    __hip_bfloat16* wb = (__hip_bfloat16*)(ws + W_TOTAL);
    int e = idx - W_TOTAL;
    if (e < 2048) {
      int j = e & 7, L = (e >> 3) & 63, hs = e >> 9;
      int h = hs >> 1, s = hs & 1;
      float v = W2b[(h * 16 + (L & 15)) * 64 + s * 32 + ((L >> 4) & 3) * 8 + j];
      float hi = __bfloat162float(__float2bfloat16(v));
      wb[FRAG_B2_HI + e] = __float2bfloat16(v);
      wb[FRAG_B2_LO + e] = __float2bfloat16(v - hi);
    } else if (e < 2560) {
      int e2 = e - 2048;
      int j = e2 & 7, L = (e2 >> 3) & 63;
      int su = L & 15, q = L >> 4;
      float v = (su < 8) ? W2c[su * 32 + q * 8 + j] : 0.f;
      wb[FRAG_C + e2] = __float2bfloat16(v);
    } else {
      int e2 = e - 2560;                 // [0, 12288)
      int j = e2 & 7, L = (e2 >> 3) & 63, nts = e2 >> 9;
      int nt = nts >> 1, s = nts & 1;
      float v = Whh[(nt * 16 + (L & 15)) * 64 + s * 32 + ((L >> 4) & 3) * 8 + j];
      float hi = __bfloat162float(__float2bfloat16(v));
      wb[FRAG_WHH_HI + e2] = __float2bfloat16(v);
      wb[FRAG_WHH_LO + e2] = __float2bfloat16(v - hi);
    }
    return;
  }
  float v;
  if (idx < O_B2A)       { int p = idx;          int su = p / 64, f = p % 64;   v = W2a[f * 18 + su]; }
  else if (idx < O_W2B)  { v = b2a[idx - O_B2A]; }
  else if (idx < O_B2B)  { v = W2b[idx - O_W2B]; }
  else if (idx < O_W2CT) { v = b2b[idx - O_B2B]; }
  else if (idx < O_B2C)  { int p = idx - O_W2CT; int o = p / 8, su = p % 8;     v = W2c[su * 32 + o]; }
  else if (idx < O_WIHT) { v = b2c[idx - O_B2C]; }
  else if (idx < O_BIH)  { int p = idx - O_WIHT; int k = p / 192, o = p % 192;  v = Wih[o * 10 + k]; }
  else if (idx < O_WHHT) { v = bih[idx - O_BIH]; }
  else if (idx < O_BHH)  { int p = idx - O_WHHT; int k = p / 192, o = p % 192;  v = Whh[o * 64 + k]; }
  else if (idx < O_W4T)  { v = bhh[idx - O_BHH]; }
  else if (idx < O_B4)   { int p = idx - O_W4T;  int k = p / 8, su = p % 8;     v = W4[su * 64 + k]; }
  else if (idx < O_W3AT) { v = b4[idx - O_B4]; }
  else if (idx < O_B3A)  { int p = idx - O_W3AT; int k = p / 64, f = p % 64;    v = W3a[f * 8 + k]; }
  else if (idx < O_W3BT) { v = b3a[idx - O_B3A]; }
  else if (idx < O_B3B)  { int p = idx - O_W3BT; int k = p / 32, f = p % 32;    v = W3b[f * 64 + k]; }
  else if (idx < O_W3CT) { v = b3b[idx - O_B3B]; }
  else if (idx < O_B3C)  { int p = idx - O_W3CT; int k = p / 4, c = p % 4;      v = W3c[c * 32 + k]; }
  else if (idx < O_W1AT) { v = b3c[idx - O_B3C]; }
  else if (idx < O_B1A)  { int p = idx - O_W1AT; int c = p / 8, su = p % 8;     v = W1a[su * 3 + c]; }
  else                   { v = b1a[idx - O_B1A]; }
  ws[idx] = v;
}

// Layer-b K-step: packed fp32 math, single-bf16 weights (2 MFMAs).
#define DO_STEP(KOFF, Y0, Y1, W0, W1, FH0, FH1)                                \
  {                                                                            \
    float4v x0 = *(const float4v*)&sA1[a * 68 + (KOFF)];                       \
    float4v x1 = *(const float4v*)&sA1[a * 68 + (KOFF) + 4];                   \
    float4v z4 = {0.f, 0.f, 0.f, 0.f};                                         \
    float4v t0 = (x0 + Y0) + ewv * W0;                                         \
    float4v t1 = (x1 + Y1) + ewv * W1;                                         \
    t0 = __builtin_elementwise_max(t0, z4);                                    \
    t1 = __builtin_elementwise_max(t1, z4);                                    \
    short8 ahi;                                                                \
    ahi[0] = bf16r(t0.x); ahi[1] = bf16r(t0.y); ahi[2] = bf16r(t0.z);          \
    ahi[3] = bf16r(t0.w); ahi[4] = bf16r(t1.x); ahi[5] = bf16r(t1.y);          \
    ahi[6] = bf16r(t1.z); ahi[7] = bf16r(t1.w);                                \
    accb0 = __builtin_amdgcn_mfma_f32_16x16x32_bf16(ahi, FH0, accb0, 0, 0, 0); \
    accb1 = __builtin_amdgcn_mfma_f32_16x16x32_bf16(ahi, FH1, accb1, 0, 0, 0); \
  }

#define LAUNDER(v) __asm__ __volatile__("" : "+v"(v))

// (256,4): 4 waves/SIMD = 4 blocks/CU (LDS 40960 fits exactly 4). R14 live set
// ~84 arch + ~12 AGPR fits the 128 budget; watch WRITE_SIZE for re-spill.
__global__ __launch_bounds__(256, 4) void gnn_fused(
    const float* __restrict__ read_gru_in,
    const float* __restrict__ gru_init,
    const float* __restrict__ feat,
    const float* __restrict__ edge_w,
    const float* __restrict__ noise_in,
    const float* __restrict__ xhat,
    const float* __restrict__ vep,
    const int* __restrict__ gnn_iter_p,
    const float* __restrict__ ws,
    float* __restrict__ out)
{
  // Overlay pool: edge-phase {sA1, sA2, sM2} aliases GRU-phase sGH (fp32 32x196).
  __shared__ __attribute__((aligned(16))) char spool[NN * GHS * 4];  // 25088 B
  __shared__ __attribute__((aligned(16))) float sH[NN * 68];
  __shared__ float sNodes[NN * 9];
  __shared__ float sSum[NN * 8];
  __shared__ float sEw[ED];
  __shared__ float sC1[64];
  __shared__ float sWew[64];
  __shared__ float sX[NN];
  __shared__ float sV[NN];

  float* const sA1 = (float*)spool;                             // 8704 B
  float* const sA2 = (float*)(spool + 8704);                    // 8704 B
  __hip_bfloat16* const sM2 = (__hip_bfloat16*)(spool + 17408); // 5632 B
  float* const sGH = (float*)spool;                             // 25088 B (aliases all)

  const int b = blockIdx.x;
  const int t = threadIdx.x;
  const int lane = t & 63;
  const int wv = t >> 6;
  const int quad = lane >> 4;
  const int lm = lane & 15;

  const __hip_bfloat16* wb = (const __hip_bfloat16*)(ws + W_TOTAL);

  // ---- per-sample inputs ----
  float noi = noise_in[b];
  for (int e = t; e < ED; e += 256) sEw[e] = edge_w[b * ED + e];
  if (t < NN) { sX[t] = xhat[b * NN + t]; sV[t] = vep[b * NN + t]; }
  if (t < 64) {
    sC1[t]  = ws[O_B2A + t] + noi * ws[O_W2AT + 17 * 64 + t];
    sWew[t] = ws[O_W2AT + 16 * 64 + t];
  }
#pragma unroll
  for (int i = 0; i < 8; ++i) {
    int p = t + 256 * i;
    sH[(p >> 6) * 68 + (p & 63)] = gru_init[b * (NN * HD) + p];
  }
  // ---- init_nodes (iteration 0 only) ----
  {
    const int git = gnn_iter_p[0];
    int n = t >> 3, su = t & 7;
    float acc;
    if (git == 0) {
      acc = ws[O_B1A + su];
#pragma unroll
      for (int c = 0; c < 3; ++c)
        acc += ws[O_W1AT + c * 8 + su] * feat[b * (NN * 3) + n * 3 + c];
    } else {
      acc = read_gru_in[b * (NN * SUD) + t];
    }
    sNodes[n * 9 + su] = acc;
  }
  __syncthreads();

  for (int it = 0; it < NITER; ++it) {
    // ---- A1/A2 node projections (c1 folded into A2) ----
    {
      int iva = 0; LAUNDER(iva);
      const float* wsl = ws + iva;
#pragma unroll
      for (int i = 0; i < 8; ++i) {
        int p = t + 256 * i;
        int n = p >> 6, f = p & 63;
        float a1 = 0.f, a2 = 0.f;
#pragma unroll
        for (int su = 0; su < 8; ++su) {
          float nv = sNodes[n * 9 + su];
          a1 += wsl[O_W2AT + su * 64 + f] * nv;
          a2 += wsl[O_W2AT + (8 + su) * 64 + f] * nv;
        }
        sA1[n * 68 + f] = a1;
        sA2[n * 68 + f] = a2 + sC1[iva + f];
      }
    }
    __syncthreads();

    // ---- edge MLP via MFMA; frags loaded from global (L2) each phase ----
    {
      int ive = 0; LAUNDER(ive);
      const float* wsl = ws + ive;
      const __hip_bfloat16* wbl = wb + ive;
      short8 fbh00 = *(const short8*)(wbl + FRAG_B2_HI + (0 * 64 + lane) * 8);
      short8 fbh01 = *(const short8*)(wbl + FRAG_B2_HI + (1 * 64 + lane) * 8);
      short8 fbh10 = *(const short8*)(wbl + FRAG_B2_HI + (2 * 64 + lane) * 8);
      short8 fbh11 = *(const short8*)(wbl + FRAG_B2_HI + (3 * 64 + lane) * 8);
      short8 fcf   = *(const short8*)(wbl + FRAG_C + lane * 8);
      const float b2b0 = wsl[O_B2B + lm];
      const float b2b1 = wsl[O_B2B + 16 + lm];
      const float b2cl = wsl[O_B2C + lm];

      __hip_bfloat16* m2w = sM2 + wv * (16 * 44);
      const int kq0 = quad * 8, kq1 = 32 + quad * 8;
      float4v wwA = *(const float4v*)&sWew[ive + kq0];
      float4v wwB = *(const float4v*)&sWew[ive + kq0 + 4];
      float4v wwC = *(const float4v*)&sWew[ive + kq1];
      float4v wwD = *(const float4v*)&sWew[ive + kq1 + 4];
      for (int ni = 0; ni < 8; ++ni) {
        const int jj = wv * 8 + ni;
        float4v yA = *(const float4v*)&sA2[jj * 68 + kq0];
        float4v yB = *(const float4v*)&sA2[jj * 68 + kq0 + 4];
        float4v yC = *(const float4v*)&sA2[jj * 68 + kq1];
        float4v yD = *(const float4v*)&sA2[jj * 68 + kq1 + 4];
        float psum = 0.f;
#pragma unroll
        for (int tile = 0; tile < 2; ++tile) {
          int kk = tile * 16 + lm;
          int kk2 = (kk < 31) ? kk : 0;
          int a = kk2 + (kk2 >= jj ? 1 : 0);
          float ewv = (kk < 31) ? sEw[ive + jj * 31 + kk] : 0.f;
          float4v accb0 = {0.f, 0.f, 0.f, 0.f};
          float4v accb1 = {0.f, 0.f, 0.f, 0.f};
          DO_STEP(kq0, yA, yB, wwA, wwB, fbh00, fbh10);
          DO_STEP(kq1, yC, yD, wwC, wwD, fbh01, fbh11);
#pragma unroll
          for (int r = 0; r < 4; ++r) {
            float m20 = fmaxf(accb0[r] + b2b0, 0.f);
            float m21 = fmaxf(accb1[r] + b2b1, 0.f);
            m2w[(quad * 4 + r) * 44 + lm]      = __float2bfloat16(m20);
            m2w[(quad * 4 + r) * 44 + 16 + lm] = __float2bfloat16(m21);
          }
          __asm__ __volatile__("" ::: "memory");
          short8 ac = *(const short8*)(m2w + lm * 44 + quad * 8);
          float4v c3 = {0.f, 0.f, 0.f, 0.f};
          c3 = __builtin_amdgcn_mfma_f32_16x16x32_bf16(ac, fcf, c3, 0, 0, 0);
#pragma unroll
          for (int r = 0; r < 4; ++r) {
            float v = fmaxf(c3[r] + b2cl, 0.f);
            if (tile == 1 && r == 3) v = (quad == 3) ? 0.f : v;
            psum += v;
          }
          __asm__ __volatile__("" ::: "memory");
        }
        psum += __shfl_xor(psum, 16);
        psum += __shfl_xor(psum, 32);
        if (lane < 8) sSum[jj * 8 + lane] = psum;
      }
    }
    __syncthreads();

    // ---- GRU part 1: GH = H @ Whh^T via MFMA. Wave wv owns N-tiles {wv,4+wv,8+wv}
    //      so GRU part 2 (cols wv*16+lm) reads only this wave's output. ----
    {
      int ivg = 0; LAUNDER(ivg);
      const __hip_bfloat16* wbl = wb + ivg;
      short8 aH[2][2];
#pragma unroll
      for (int mt = 0; mt < 2; ++mt) {
#pragma unroll
        for (int s = 0; s < 2; ++s) {
          const float* hp = &sH[(mt * 16 + lm) * 68 + s * 32 + quad * 8];
          float4v h0 = *(const float4v*)hp;
          float4v h1 = *(const float4v*)(hp + 4);
          short8 a;
          a[0] = bf16r(h0.x); a[1] = bf16r(h0.y); a[2] = bf16r(h0.z); a[3] = bf16r(h0.w);
          a[4] = bf16r(h1.x); a[5] = bf16r(h1.y); a[6] = bf16r(h1.z); a[7] = bf16r(h1.w);
          aH[mt][s] = a;
        }
      }
#pragma unroll
      for (int nt = 0; nt < 3; ++nt) {
        int gnt = 4 * nt + wv;
        short8 bh0 = *(const short8*)(wbl + FRAG_WHH_HI + ((gnt * 2 + 0) * 64 + lane) * 8);
        short8 bh1 = *(const short8*)(wbl + FRAG_WHH_HI + ((gnt * 2 + 1) * 64 + lane) * 8);
#pragma unroll
        for (int mt = 0; mt < 2; ++mt) {
          float4v acc = {0.f, 0.f, 0.f, 0.f};
          acc = __builtin_amdgcn_mfma_f32_16x16x32_bf16(aH[mt][0], bh0, acc, 0, 0, 0);
          acc = __builtin_amdgcn_mfma_f32_16x16x32_bf16(aH[mt][1], bh1, acc, 0, 0, 0);
#pragma unroll
          for (int r = 0; r < 4; ++r)
            sGH[(mt * 16 + quad * 4 + r) * GHS + gnt * 16 + lm] = acc[r];
        }
      }
    }
    __asm__ __volatile__("" ::: "memory");   // order GH writes before same-wave reads

    // ---- GRU part 2: gates; wave-private cols c = wv*16+lm2; hnew staged in regs ----
    {
      int ivq = 0; LAUNDER(ivq);
      const float* wsl = ws + ivq;
      int lm2 = lane & 15, g = lane >> 4;
      int c = wv * 16 + lm2;
      float ar[8], az[8], inx[8];
      {
        float br  = wsl[O_BIH + c]       + wsl[O_BHH + c];
        float bz  = wsl[O_BIH + 64 + c]  + wsl[O_BHH + 64 + c];
        float bni = wsl[O_BIH + 128 + c];
#pragma unroll
        for (int j = 0; j < 8; ++j) { ar[j] = br; az[j] = bz; inx[j] = bni; }
      }
#pragma unroll
      for (int k = 0; k < 8; ++k) {
        float wr = wsl[O_WIHT + k * 192 + c];
        float wz = wsl[O_WIHT + k * 192 + 64 + c];
        float wn = wsl[O_WIHT + k * 192 + 128 + c];
#pragma unroll
        for (int j = 0; j < 8; ++j) {
          float gg = sSum[(g + 4 * j) * 8 + k];
          ar[j] += wr * gg; az[j] += wz * gg; inx[j] += wn * gg;
        }
      }
      {
        float wr = wsl[O_WIHT + 8 * 192 + c];
        float wz = wsl[O_WIHT + 8 * 192 + 64 + c];
        float wn = wsl[O_WIHT + 8 * 192 + 128 + c];
#pragma unroll
        for (int j = 0; j < 8; ++j) {
          float gg = sX[ivq + g + 4 * j];
          ar[j] += wr * gg; az[j] += wz * gg; inx[j] += wn * gg;
        }
        wr = wsl[O_WIHT + 9 * 192 + c];
        wz = wsl[O_WIHT + 9 * 192 + 64 + c];
        wn = wsl[O_WIHT + 9 * 192 + 128 + c];
#pragma unroll
        for (int j = 0; j < 8; ++j) {
          float gg = sV[ivq + g + 4 * j];
          ar[j] += wr * gg; az[j] += wz * gg; inx[j] += wn * gg;
        }
      }
      float bnh = wsl[O_BHH + 128 + c];
      float hnew[8];
#pragma unroll
      for (int j = 0; j < 8; ++j) {
        int n = g + 4 * j;
        float ghr = sGH[n * GHS + c];
        float ghz = sGH[n * GHS + 64 + c];
        float ghn = sGH[n * GHS + 128 + c] + bnh;
        float r = 1.f / (1.f + __expf(-(ar[j] + ghr)));
        float z = 1.f / (1.f + __expf(-(az[j] + ghz)));
        float cd = inx[j] + r * ghn;
        float e2 = __expf(2.f * cd);
        float th = 1.f - 2.f / (e2 + 1.f);
        hnew[j] = (1.f - z) * th + z * sH[n * 68 + c];
      }
      __syncthreads();   // other waves' GRU1 reads of all sH cols complete
#pragma unroll
      for (int j = 0; j < 8; ++j) sH[(g + 4 * j) * 68 + c] = hnew[j];
    }
    __syncthreads();

    // ---- read_gru = W4 @ h + b4 -> sNodes ----
    {
      int ivw = 0; LAUNDER(ivw);
      const float* wsl = ws + ivw;
      int n = t >> 3, su = t & 7;
      float c0 = 0.f, c1v = 0.f, c2 = 0.f, c3v = 0.f;
#pragma unroll
      for (int k = 0; k < 64; k += 4) {
        c0  += wsl[O_W4T + (k + 0) * 8 + su] * sH[n * 68 + k + 0];
        c1v += wsl[O_W4T + (k + 1) * 8 + su] * sH[n * 68 + k + 1];
        c2  += wsl[O_W4T + (k + 2) * 8 + su] * sH[n * 68 + k + 2];
        c3v += wsl[O_W4T + (k + 3) * 8 + su] * sH[n * 68 + k + 3];
      }
      sNodes[n * 9 + su] = wsl[O_B4 + su] + ((c0 + c1v) + (c2 + c3v));
    }
    __syncthreads();
  } // iterations

  // ---- head ----
#pragma unroll
  for (int i = 0; i < 8; ++i) {
    int p = t + 256 * i;
    int n = p >> 6, f = p & 63;
    float acc = ws[O_B3A + f];
#pragma unroll
    for (int k = 0; k < 8; ++k) acc += ws[O_W3AT + k * 64 + f] * sNodes[n * 9 + k];
    sA1[n * 68 + f] = acc;
  }
  __syncthreads();
#pragma unroll
  for (int i = 0; i < 4; ++i) {
    int p = t + 256 * i;
    int n = p >> 5, f = p & 31;
    float c0 = 0.f, c1v = 0.f, c2 = 0.f, c3v = 0.f;
#pragma unroll
    for (int k = 0; k < 64; k += 4) {
      c0  += ws[O_W3BT + (k + 0) * 32 + f] * sA1[n * 68 + k + 0];
      c1v += ws[O_W3BT + (k + 1) * 32 + f] * sA1[n * 68 + k + 1];
      c2  += ws[O_W3BT + (k + 2) * 32 + f] * sA1[n * 68 + k + 2];
      c3v += ws[O_W3BT + (k + 3) * 32 + f] * sA1[n * 68 + k + 3];
    }
    sA2[n * 33 + f] = ws[O_B3B + f] + ((c0 + c1v) + (c2 + c3v));
  }
  __syncthreads();
  if (t < 128) {
    int n = t >> 2, c = t & 3;
    float acc = ws[O_B3C + c];
#pragma unroll
    for (int k = 0; k < 32; ++k) acc += ws[O_W3CT + k * 4 + c] * sA2[n * 33 + k];
    out[b * (NN * NCD) + t] = acc;
  }
  out[BB * NN * NCD + b * (NN * SUD) + t] = sNodes[(t >> 3) * 9 + (t & 7)];
#pragma unroll
  for (int i = 0; i < 8; ++i) {
    int p = t + 256 * i;
    out[BB * NN * NCD + BB * NN * SUD + b * (NN * HD) + p] =
        sH[(p >> 6) * 68 + (p & 63)];
  }
}

extern "C" void kernel_launch(void* const* d_in, const int* in_sizes, int n_in,
                              void* d_out, int out_size, void* d_ws, size_t ws_size,
                              hipStream_t stream) {
  typedef const float* F32;
  F32 read_gru = (F32)d_in[0];
  F32 gru_init = (F32)d_in[1];
  F32 feat     = (F32)d_in[2];
  F32 edge_w   = (F32)d_in[3];
  F32 noise    = (F32)d_in[4];
  F32 xh       = (F32)d_in[5];
  F32 vp       = (F32)d_in[6];
  F32 W1a = (F32)d_in[7];  F32 b1a = (F32)d_in[8];
  F32 W2a = (F32)d_in[9];  F32 b2a = (F32)d_in[10];
  F32 W2b = (F32)d_in[11]; F32 b2b = (F32)d_in[12];
  F32 W2c = (F32)d_in[13]; F32 b2c = (F32)d_in[14];
  F32 Wih = (F32)d_in[15]; F32 bih = (F32)d_in[16];
  F32 Whh = (F32)d_in[17]; F32 bhh = (F32)d_in[18];
  F32 W3a = (F32)d_in[19]; F32 b3a = (F32)d_in[20];
  F32 W3b = (F32)d_in[21]; F32 b3b = (F32)d_in[22];
  F32 W3c = (F32)d_in[23]; F32 b3c = (F32)d_in[24];
  F32 W4  = (F32)d_in[25]; F32 b4  = (F32)d_in[26];
  const int* git = (const int*)d_in[27];
  float* ws = (float*)d_ws;   // needs 144,336 B

  prep_weights<<<(W_EXT + 255) / 256, 256, 0, stream>>>(
      W2a, b2a, W2b, b2b, W2c, b2c, Wih, bih, Whh, bhh,
      W3a, b3a, W3b, b3b, W3c, b3c, W4, b4, W1a, b1a, ws);

  gnn_fused<<<BB, 256, 0, stream>>>(read_gru, gru_init, feat, edge_w, noise,
                                    xh, vp, git, ws, (float*)d_out);
}